// Round 1
// baseline (2091.621 us; speedup 1.0000x reference)
//
#include <hip/hip_runtime.h>
#include <math.h>

#define LSL 0.01f

static __device__ __forceinline__ float lrelu_f(float x){ return x > 0.f ? x : LSL * x; }
static __device__ __forceinline__ void atomAddF(float* p, float v){ unsafeAtomicAdd(p, v); }

// monotone float <-> uint bijection so atomicMax(uint) == float max; 0 encodes < -inf
static __device__ __forceinline__ unsigned encF(float f){
  unsigned u = __float_as_uint(f);
  return (u & 0x80000000u) ? ~u : (u | 0x80000000u);
}
static __device__ __forceinline__ float decF(unsigned u){
  return (u & 0x80000000u) ? __uint_as_float(u & 0x7FFFFFFFu) : __uint_as_float(~u);
}

__global__ void k_count(const int* __restrict__ idx, float* __restrict__ deg, int E){
  int e = blockIdx.x * blockDim.x + threadIdx.x;
  if (e < E) atomAddF(deg + idx[e], 1.f);
}

__global__ void k_inv_sqrt(float* __restrict__ d, int N){
  int v = blockIdx.x * blockDim.x + threadIdx.x;
  if (v < N){ float x = d[v]; d[v] = x > 0.f ? rsqrtf(x) : 0.f; }
}

// agg[i] += dis[j]*dis[i] * x[j]   (block per edge)
__global__ void k_gcn_agg(const int* __restrict__ src, const int* __restrict__ dst,
                          const float* __restrict__ x, const float* __restrict__ dis,
                          float* __restrict__ agg, int F){
  int e = blockIdx.x;
  int j = src[e], i = dst[e];
  float nrm = dis[j] * dis[i];
  const float* xj = x + (size_t)j * F;
  float* ai = agg + (size_t)i * F;
  for (int c = threadIdx.x; c < F; c += blockDim.x)
    atomAddF(ai + c, nrm * xj[c]);
}

// O = sig(X@Wh + b) * (relu(Agg)@Wg) + (1-sig)*X    (64x64 tile, K=Nn=300)
__global__ __launch_bounds__(256)
void k_dualgemm_hw(const float* __restrict__ Agg, const float* __restrict__ X,
                   const float* __restrict__ Wg, const float* __restrict__ Wh,
                   const float* __restrict__ bias, float* __restrict__ O,
                   int M, int K, int Nn, long ldo){
  __shared__ float As1[16][65], As2[16][65], Bs1[16][65], Bs2[16][65];
  int tid = threadIdx.x;
  int tx = tid & 15, ty = tid >> 4;
  int bm = blockIdx.x * 64, bn = blockIdx.y * 64;
  float acc1[4][4] = {{0.f}}, acc2[4][4] = {{0.f}};
  for (int k0 = 0; k0 < K; k0 += 16){
    int ml = tid >> 2;
    int klb = (tid & 3) * 4;
    int gm = bm + ml;
    #pragma unroll
    for (int q = 0; q < 4; q++){
      int gk = k0 + klb + q;
      bool ok = (gm < M) && (gk < K);
      float v1 = ok ? Agg[(size_t)gm * K + gk] : 0.f;
      float v2 = ok ? X[(size_t)gm * K + gk] : 0.f;
      As1[klb + q][ml] = fmaxf(v1, 0.f);
      As2[klb + q][ml] = v2;
    }
    #pragma unroll
    for (int p = 0; p < 4; p++){
      int L = tid + p * 256;
      int kl = L >> 6, nl = L & 63;
      int gk = k0 + kl, gn = bn + nl;
      bool ok = (gk < K) && (gn < Nn);
      Bs1[kl][nl] = ok ? Wg[(size_t)gk * Nn + gn] : 0.f;
      Bs2[kl][nl] = ok ? Wh[(size_t)gk * Nn + gn] : 0.f;
    }
    __syncthreads();
    #pragma unroll
    for (int kk = 0; kk < 16; kk++){
      float a1[4], a2[4], b1[4], b2[4];
      #pragma unroll
      for (int q = 0; q < 4; q++){
        a1[q] = As1[kk][ty*4+q]; a2[q] = As2[kk][ty*4+q];
        b1[q] = Bs1[kk][tx*4+q]; b2[q] = Bs2[kk][tx*4+q];
      }
      #pragma unroll
      for (int qi = 0; qi < 4; qi++)
        #pragma unroll
        for (int qj = 0; qj < 4; qj++){
          acc1[qi][qj] += a1[qi]*b1[qj];
          acc2[qi][qj] += a2[qi]*b2[qj];
        }
    }
    __syncthreads();
  }
  #pragma unroll
  for (int qi = 0; qi < 4; qi++){
    int gm = bm + ty*4 + qi;
    if (gm >= M) continue;
    #pragma unroll
    for (int qj = 0; qj < 4; qj++){
      int gn = bn + tx*4 + qj;
      if (gn >= Nn) continue;
      float xv = X[(size_t)gm * K + gn];
      float g = 1.f / (1.f + expf(-(acc2[qi][qj] + bias[gn])));
      O[(size_t)gm * ldo + gn] = g * acc1[qi][qj] + (1.f - g) * xv;
    }
  }
}

// thread-per-row small dot(s), optional leaky-relu on X
__global__ void k_dot2_small(const float* __restrict__ X, int ld, int len,
                             const float* __restrict__ wA, const float* __restrict__ wB,
                             float* __restrict__ oA, float* __restrict__ oB,
                             int n, int applyL){
  int v = blockIdx.x * blockDim.x + threadIdx.x;
  if (v >= n) return;
  const float* row = X + (size_t)v * ld;
  float a = 0.f, b = 0.f;
  for (int c = 0; c < len; c++){
    float f = row[c];
    if (applyL) f = lrelu_f(f);
    a += f * wA[c];
    if (wB) b += f * wB[c];
  }
  oA[v] = a;
  if (oB) oB[v] = b;
}

// wave-per-row: two dots against wA/wB over len columns of X (row stride ld)
__global__ void k_wave_dot2(const float* __restrict__ X, long ld, int len,
                            const float* __restrict__ wA, const float* __restrict__ wB,
                            float* __restrict__ oA, float* __restrict__ oB,
                            int n, int applyL){
  int gw = (int)(((long)blockIdx.x * blockDim.x + threadIdx.x) >> 6);
  int lane = threadIdx.x & 63;
  if (gw >= n) return;
  const float* row = X + (size_t)gw * ld;
  float a = 0.f, b = 0.f;
  for (int c = lane; c < len; c += 64){
    float f = row[c];
    if (applyL) f = lrelu_f(f);
    a += f * wA[c];
    b += f * wB[c];
  }
  #pragma unroll
  for (int o = 32; o > 0; o >>= 1){
    a += __shfl_down(a, o);
    b += __shfl_down(b, o);
  }
  if (lane == 0){ oA[gw] = a; oB[gw] = b; }
}

// per-edge logit + segment max (into encoded uint)
__global__ void k_edge_logit(const int* __restrict__ segI, const int* __restrict__ othI,
                             const int* __restrict__ relI,
                             const float* __restrict__ sSeg, const float* __restrict__ sOth,
                             const float* __restrict__ sRel,
                             float* __restrict__ elog, unsigned* __restrict__ mEnc,
                             int E, int applyL){
  int e = blockIdx.x * blockDim.x + threadIdx.x;
  if (e >= E) return;
  int s = segI[e];
  float v = sSeg[s] + sOth[othI[e]];
  if (relI) v += sRel[relI[e]];
  if (applyL) v = lrelu_f(v);
  elog[e] = v;
  atomicMax(mEnc + s, encF(v));
}

__global__ void k_edge_exp(const int* __restrict__ segI, float* __restrict__ elog,
                           const unsigned* __restrict__ mEnc, float* __restrict__ segSum, int E){
  int e = blockIdx.x * blockDim.x + threadIdx.x;
  if (e >= E) return;
  int s = segI[e];
  float ex = expf(elog[e] - decF(mEnc[s]));
  elog[e] = ex;
  atomAddF(segSum + s, ex);
}

// gat_r: oagg[i] += alpha * xin[j], alpha = ex / (sum[j] + eps)   (softmax grouped by j!)
__global__ void k_gatr_scatter(const int* __restrict__ src, const int* __restrict__ dst,
                               const float* __restrict__ ex, const float* __restrict__ segSum,
                               const float* __restrict__ xin, float* __restrict__ oagg, int F){
  int e = blockIdx.x;
  int j = src[e], i = dst[e];
  float alpha = ex[e] / (segSum[j] + 1e-16f);
  const float* xj = xin + (size_t)j * F;
  float* oi = oagg + (size_t)i * F;
  for (int c = threadIdx.x; c < F; c += blockDim.x)
    atomAddF(oi + c, alpha * xj[c]);
}

// wjq scatter: out[i,600:700] += a*lrelu(relEmb[r]); out[i,700:1000] += a*lrelu(x2[j]); sumAlpha[i] += a
__global__ void k_wjq_scatter(const int* __restrict__ row0, const int* __restrict__ row1,
                              const int* __restrict__ relI, const float* __restrict__ ex,
                              const float* __restrict__ sumS, float* __restrict__ sumAlpha,
                              const float* __restrict__ relEmb, float* __restrict__ out){
  int e = blockIdx.x;
  int i = row0[e], j = row1[e], r = relI[e];
  float alpha = ex[e] / (sumS[i] + 1e-16f);
  if (threadIdx.x == 0) atomAddF(sumAlpha + i, alpha);
  float* oi = out + (size_t)i * 2000;
  const float* rr = relEmb + (size_t)r * 100;
  const float* xj = out + (size_t)j * 2000;  // x2 lives in cols 0:300
  for (int c = threadIdx.x; c < 400; c += blockDim.x){
    if (c < 100) atomAddF(oi + 600 + c, alpha * lrelu_f(rr[c]));
    else         atomAddF(oi + 700 + (c - 100), alpha * lrelu_f(xj[c - 100]));
  }
}

// out[v,300:600] = lrelu(x2[v]) * sumAlpha[v]
__global__ void k_wjq_head(const float* __restrict__ sumAlpha, float* __restrict__ out){
  int v = blockIdx.x;
  float sa = sumAlpha[v];
  float* o = out + (size_t)v * 2000;
  for (int c = threadIdx.x; c < 300; c += blockDim.x)
    o[300 + c] = lrelu_f(o[c]) * sa;
}

// gat scatter: out[i,1000:2000] += alpha * x_wjq[j] (cols 0:1000)
__global__ void k_gat_scatter(const int* __restrict__ row0, const int* __restrict__ row1,
                              const float* __restrict__ ex, const float* __restrict__ sumS,
                              float* __restrict__ out){
  int e = blockIdx.x;
  int j = row0[e], i = row1[e];
  float alpha = ex[e] / (sumS[i] + 1e-16f);
  float* oi = out + (size_t)i * 2000 + 1000;
  const float* xj = out + (size_t)j * 2000;
  for (int c = threadIdx.x; c < 1000; c += blockDim.x)
    atomAddF(oi + c, alpha * xj[c]);
}

__global__ void k_relu_lin(float* __restrict__ p, long n){
  long t = (long)blockIdx.x * blockDim.x + threadIdx.x;
  if (t < n) p[t] = fmaxf(p[t], 0.f);
}

__global__ void k_relu_cols(float* __restrict__ out){
  int v = blockIdx.x;
  float* p = out + (size_t)v * 2000 + 1000;
  for (int c = threadIdx.x; c < 1000; c += blockDim.x)
    p[c] = fmaxf(p[c], 0.f);
}

extern "C" void kernel_launch(void* const* d_in, const int* in_sizes, int n_in,
                              void* d_out, int out_size, void* d_ws, size_t ws_size,
                              hipStream_t stream){
  const float* x_e     = (const float*)d_in[0];
  const int*   eiA     = (const int*)  d_in[3];   // edge_index_all [2,E]
  const int*   relAll  = (const int*)  d_in[4];
  const int*   lgOut   = (const int*)  d_in[5];
  const int*   lgIn    = (const int*)  d_in[7];
  const float* gcn1_w  = (const float*)d_in[9];
  const float* gcn2_w  = (const float*)d_in[10];
  const float* hw1_w   = (const float*)d_in[11];
  const float* hw1_b   = (const float*)d_in[12];
  const float* hw2_w   = (const float*)d_in[13];
  const float* hw2_b   = (const float*)d_in[14];
  const float* ww1     = (const float*)d_in[15];
  const float* gat_ai  = (const float*)d_in[16];
  const float* gat_aj  = (const float*)d_in[17];
  const float* gat_ar  = (const float*)d_in[18];
  const float* gatr_ai = (const float*)d_in[19];
  const float* gatr_aj = (const float*)d_in[20];
  const float* relEmb1 = (const float*)d_in[21];

  const int EH = 300, RH = 100;
  const int N   = in_sizes[0] / EH;
  const int E   = in_sizes[3] / 2;
  const int ELG = in_sizes[5] / 2;
  const int R   = in_sizes[21] / RH;

  float* w = (float*)d_ws;
  float* dis    = w; w += N;
  float* bufA   = w; w += (size_t)N * EH;   // agg buffer
  float* bufB   = w; w += (size_t)N * EH;   // x1
  float* relEmb = w; w += (size_t)2 * R * RH;
  float* sxi    = w; w += N;
  float* sxj    = w; w += N;
  unsigned* mEncN = (unsigned*)w; w += N;
  float* sumN   = w; w += N;
  float* sumAl  = w; w += N;
  float* sR_i   = w; w += R;
  float* sR_j   = w; w += R;
  unsigned* mEncR = (unsigned*)w; w += R;
  float* sumR   = w; w += R;
  float* aRel   = w; w += 2 * R;
  float* srr    = w; w += 2 * R;
  float* eE     = w; w += E;

  float* out = (float*)d_out;
  const int* srcA = eiA;         // row0 (j in gcn/gat, i in wjq)
  const int* dstA = eiA + E;     // row1

  auto cdiv = [](int a, int b){ return (a + b - 1) / b; };

  hipMemsetAsync(d_out, 0, (size_t)out_size * sizeof(float), stream);

  // degree -> deg^-0.5 (in-degree over row1)
  hipMemsetAsync(dis, 0, (size_t)N * 4, stream);
  k_count<<<cdiv(E,256),256,0,stream>>>(dstA, dis, E);
  k_inv_sqrt<<<cdiv(N,256),256,0,stream>>>(dis, N);

  dim3 gg((unsigned)cdiv(N,64), (unsigned)cdiv(EH,64));

  // layer 1: x1 = highway(x_e, gcn(x_e))
  hipMemsetAsync(bufA, 0, (size_t)N*EH*4, stream);
  k_gcn_agg<<<E,256,0,stream>>>(srcA, dstA, x_e, dis, bufA, EH);
  k_dualgemm_hw<<<gg,256,0,stream>>>(bufA, x_e, gcn1_w, hw1_w, hw1_b, bufB, N, EH, EH, EH);

  // layer 2: x2 = highway(x1, gcn(x1)) -> out cols 0:300
  hipMemsetAsync(bufA, 0, (size_t)N*EH*4, stream);
  k_gcn_agg<<<E,256,0,stream>>>(srcA, dstA, bufB, dis, bufA, EH);
  k_dualgemm_hw<<<gg,256,0,stream>>>(bufA, bufB, gcn2_w, hw2_w, hw2_b, out, N, EH, EH, 2000);

  // gat_r x2 -> relEmb [2R,100]
  k_dot2_small<<<cdiv(R,256),256,0,stream>>>(relEmb1, RH, RH, gatr_ai, gatr_aj, sR_i, sR_j, R, 0);
  hipMemsetAsync(relEmb, 0, (size_t)2*R*RH*4, stream);
  for (int g = 0; g < 2; g++){
    const int* lg = (g == 0) ? lgOut : lgIn;
    float* part = relEmb + (size_t)g * R * RH;
    hipMemsetAsync(mEncR, 0, (size_t)2*R*4, stream);   // mEncR + sumR contiguous
    // e = si[i] + sj[j], lrelu, softmax grouped by j (=row0)
    k_edge_logit<<<cdiv(ELG,256),256,0,stream>>>(lg, lg + ELG, nullptr, sR_j, sR_i, nullptr,
                                                 eE, mEncR, ELG, 1);
    k_edge_exp<<<cdiv(ELG,256),256,0,stream>>>(lg, eE, mEncR, sumR, ELG);
    k_gatr_scatter<<<ELG,128,0,stream>>>(lg, lg + ELG, eE, sumR, relEmb1, part, RH);
  }
  k_relu_lin<<<cdiv(2*R*RH,256),256,0,stream>>>(relEmb, (long)2*R*RH);

  // wjq: softmax grouped by row0, feat = [ef[i] | re[rel] | ef[j]]
  k_dot2_small<<<cdiv(2*R,256),256,0,stream>>>(relEmb, RH, RH, ww1 + EH, nullptr, aRel, nullptr, 2*R, 1);
  k_wave_dot2<<<cdiv(N,4),256,0,stream>>>(out, 2000, EH, ww1, ww1 + EH + RH, sxi, sxj, N, 1);
  hipMemsetAsync(mEncN, 0, (size_t)3*N*4, stream);     // mEncN + sumN + sumAl
  k_edge_logit<<<cdiv(E,256),256,0,stream>>>(srcA, dstA, relAll, sxi, sxj, aRel, eE, mEncN, E, 0);
  k_edge_exp<<<cdiv(E,256),256,0,stream>>>(srcA, eE, mEncN, sumN, E);
  k_wjq_scatter<<<E,256,0,stream>>>(srcA, dstA, relAll, eE, sumN, sumAl, relEmb, out);
  k_wjq_head<<<N,256,0,stream>>>(sumAl, out);

  // gat over x_wjq (out cols 0:1000), softmax grouped by row1
  k_wave_dot2<<<cdiv(N,4),256,0,stream>>>(out, 2000, 1000, gat_ai, gat_aj, sxi, sxj, N, 0);
  k_dot2_small<<<cdiv(2*R,256),256,0,stream>>>(relEmb, RH, RH, gat_ar, nullptr, srr, nullptr, 2*R, 0);
  hipMemsetAsync(mEncN, 0, (size_t)2*N*4, stream);     // mEncN + sumN
  k_edge_logit<<<cdiv(E,256),256,0,stream>>>(dstA, srcA, relAll, sxi, sxj, srr, eE, mEncN, E, 1);
  k_edge_exp<<<cdiv(E,256),256,0,stream>>>(dstA, eE, mEncN, sumN, E);
  k_gat_scatter<<<E,256,0,stream>>>(srcA, dstA, eE, sumN, out);
  k_relu_cols<<<N,256,0,stream>>>(out);
}

// Round 2
// 1337.477 us; speedup vs baseline: 1.5639x; 1.5639x over previous
//
#include <hip/hip_runtime.h>
#include <math.h>

#define LSL 0.01f

static __device__ __forceinline__ float lrelu_f(float x){ return x > 0.f ? x : LSL * x; }
static __device__ __forceinline__ void atomAddF(float* p, float v){ unsafeAtomicAdd(p, v); }

// monotone float <-> uint bijection so atomicMax(uint) == float max; 0 encodes < -inf
static __device__ __forceinline__ unsigned encF(float f){
  unsigned u = __float_as_uint(f);
  return (u & 0x80000000u) ? ~u : (u | 0x80000000u);
}
static __device__ __forceinline__ float decF(unsigned u){
  return (u & 0x80000000u) ? __uint_as_float(u & 0x7FFFFFFFu) : __uint_as_float(~u);
}

// ---------------- CSR build ----------------
__global__ void k_count_int(const int* __restrict__ idx, int* __restrict__ deg, int E){
  int e = blockIdx.x * blockDim.x + threadIdx.x;
  if (e < E) atomicAdd(deg + idx[e], 1);
}

// single-block exclusive scan (n up to ~20k)
__global__ void k_scan_excl(const int* __restrict__ cnt, int* __restrict__ off, int n){
  __shared__ int buf[256];
  __shared__ int carry;
  if (threadIdx.x == 0) carry = 0;
  __syncthreads();
  for (int base = 0; base < n; base += 256){
    int idx = base + threadIdx.x;
    int v = (idx < n) ? cnt[idx] : 0;
    buf[threadIdx.x] = v;
    __syncthreads();
    for (int o = 1; o < 256; o <<= 1){
      int t = (threadIdx.x >= o) ? buf[threadIdx.x - o] : 0;
      __syncthreads();
      buf[threadIdx.x] += t;
      __syncthreads();
    }
    if (idx < n) off[idx] = carry + buf[threadIdx.x] - v;
    __syncthreads();
    if (threadIdx.x == 255) carry += buf[255];
    __syncthreads();
  }
  if (threadIdx.x == 0) off[n] = carry;
}

__global__ void k_fill_csr(const int* __restrict__ idx, const int* __restrict__ off,
                           int* __restrict__ cursor, int* __restrict__ perm, int E){
  int e = blockIdx.x * blockDim.x + threadIdx.x;
  if (e >= E) return;
  int i = idx[e];
  int p = off[i] + atomicAdd(cursor + i, 1);
  perm[p] = e;
}

__global__ void k_inv_sqrt_int(const int* __restrict__ deg, float* __restrict__ dis, int N){
  int v = blockIdx.x * blockDim.x + threadIdx.x;
  if (v < N){ int d = deg[v]; dis[v] = d > 0 ? rsqrtf((float)d) : 0.f; }
}

// ---------------- CSR gathers (no atomics) ----------------
// agg[i] = sum_e dis[i]*dis[j] * x[j], F=300, block=256
__global__ __launch_bounds__(256)
void k_gcn_gather(const int* __restrict__ off, const int* __restrict__ perm,
                  const int* __restrict__ src, const float* __restrict__ x,
                  const float* __restrict__ dis, float* __restrict__ agg){
  int i = blockIdx.x, t = threadIdx.x;
  int p0 = off[i], p1 = off[i+1];
  float di = dis[i];
  __shared__ int sjv[64]; __shared__ float sw[64];
  float a0 = 0.f, a1 = 0.f;
  for (int pb = p0; pb < p1; pb += 64){
    int m = min(64, p1 - pb);
    if (t < m){ int e = perm[pb + t]; int j = src[e]; sjv[t] = j; sw[t] = di * dis[j]; }
    __syncthreads();
    for (int q = 0; q < m; q++){
      const float* xj = x + (size_t)sjv[q] * 300;
      a0 += sw[q] * xj[t];
      if (t < 44) a1 += sw[q] * xj[t + 256];
    }
    __syncthreads();
  }
  float* o = agg + (size_t)i * 300;
  o[t] = a0;
  if (t < 44) o[t + 256] = a1;
}

// wjq (grouped by i=row0): out[i,600:700] = sum a*lrelu(re[r]); out[i,700:1000] = sum a*lrelu(x2[j]);
// out[i,300:600] = lrelu(x2[i]) * sum(a)
__global__ __launch_bounds__(256)
void k_wjq_gather(const int* __restrict__ off, const int* __restrict__ perm,
                  const int* __restrict__ row1, const int* __restrict__ relI,
                  const float* __restrict__ ex, const float* __restrict__ sums,
                  const float* __restrict__ relEmb, float* __restrict__ out){
  int i = blockIdx.x, t = threadIdx.x;
  int p0 = off[i], p1 = off[i+1];
  float inv = 1.f / (sums[i] + 1e-16f);
  __shared__ int sjv[64], srv[64]; __shared__ float sal[64];
  float a0 = 0.f, a1 = 0.f, sa = 0.f;
  for (int pb = p0; pb < p1; pb += 64){
    int m = min(64, p1 - pb);
    if (t < m){ int e = perm[pb + t]; sjv[t] = row1[e]; srv[t] = relI[e]; sal[t] = ex[e] * inv; }
    __syncthreads();
    for (int q = 0; q < m; q++){
      float al = sal[q]; sa += al;
      const float* rr = relEmb + (size_t)srv[q] * 100;
      const float* xj = out + (size_t)sjv[q] * 2000;   // x2 in cols 0:300
      float v0 = (t < 100) ? rr[t] : xj[t - 100];
      a0 += al * lrelu_f(v0);
      if (t < 144) a1 += al * lrelu_f(xj[t + 156]);
    }
    __syncthreads();
  }
  float* oi = out + (size_t)i * 2000;
  if (t < 100) oi[600 + t] = a0;
  else         oi[700 + (t - 100)] = a0;
  if (t < 144) oi[856 + t] = a1;
  // head: out[i,300:600] = lrelu(x2) * sumAlpha
  oi[300 + t] = lrelu_f(oi[t]) * sa;                  // t in 0..255
  if (t < 44) oi[556 + t] = lrelu_f(oi[256 + t]) * sa;
}

// gat (grouped by i=row1): out[i,1000:2000] = relu(sum a * x_wjq[j,0:1000])
__global__ __launch_bounds__(256)
void k_gat_gather(const int* __restrict__ off, const int* __restrict__ perm,
                  const int* __restrict__ src, const float* __restrict__ ex,
                  const float* __restrict__ sums, float* __restrict__ out){
  int i = blockIdx.x, t = threadIdx.x;
  int p0 = off[i], p1 = off[i+1];
  float inv = 1.f / (sums[i] + 1e-16f);
  __shared__ int sjv[64]; __shared__ float sal[64];
  float acc[4] = {0.f, 0.f, 0.f, 0.f};
  for (int pb = p0; pb < p1; pb += 64){
    int m = min(64, p1 - pb);
    if (t < m){ int e = perm[pb + t]; sjv[t] = src[e]; sal[t] = ex[e] * inv; }
    __syncthreads();
    for (int q = 0; q < m; q++){
      const float* xj = out + (size_t)sjv[q] * 2000;
      float al = sal[q];
      #pragma unroll
      for (int k = 0; k < 4; k++){
        int c = t + k * 256;
        if (c < 1000) acc[k] += al * xj[c];
      }
    }
    __syncthreads();
  }
  float* oi = out + (size_t)i * 2000 + 1000;
  #pragma unroll
  for (int k = 0; k < 4; k++){
    int c = t + k * 256;
    if (c < 1000) oi[c] = fmaxf(acc[k], 0.f);
  }
}

// ---------------- dense / small kernels ----------------
// O = sig(X@Wh + b) * (relu(Agg)@Wg) + (1-sig)*X    (64x64 tile, K=Nn=300)
__global__ __launch_bounds__(256)
void k_dualgemm_hw(const float* __restrict__ Agg, const float* __restrict__ X,
                   const float* __restrict__ Wg, const float* __restrict__ Wh,
                   const float* __restrict__ bias, float* __restrict__ O,
                   int M, int K, int Nn, long ldo){
  __shared__ float As1[16][65], As2[16][65], Bs1[16][65], Bs2[16][65];
  int tid = threadIdx.x;
  int tx = tid & 15, ty = tid >> 4;
  int bm = blockIdx.x * 64, bn = blockIdx.y * 64;
  float acc1[4][4] = {{0.f}}, acc2[4][4] = {{0.f}};
  for (int k0 = 0; k0 < K; k0 += 16){
    int ml = tid >> 2;
    int klb = (tid & 3) * 4;
    int gm = bm + ml;
    #pragma unroll
    for (int q = 0; q < 4; q++){
      int gk = k0 + klb + q;
      bool ok = (gm < M) && (gk < K);
      float v1 = ok ? Agg[(size_t)gm * K + gk] : 0.f;
      float v2 = ok ? X[(size_t)gm * K + gk] : 0.f;
      As1[klb + q][ml] = fmaxf(v1, 0.f);
      As2[klb + q][ml] = v2;
    }
    #pragma unroll
    for (int p = 0; p < 4; p++){
      int L = tid + p * 256;
      int kl = L >> 6, nl = L & 63;
      int gk = k0 + kl, gn = bn + nl;
      bool ok = (gk < K) && (gn < Nn);
      Bs1[kl][nl] = ok ? Wg[(size_t)gk * Nn + gn] : 0.f;
      Bs2[kl][nl] = ok ? Wh[(size_t)gk * Nn + gn] : 0.f;
    }
    __syncthreads();
    #pragma unroll
    for (int kk = 0; kk < 16; kk++){
      float a1[4], a2[4], b1[4], b2[4];
      #pragma unroll
      for (int q = 0; q < 4; q++){
        a1[q] = As1[kk][ty*4+q]; a2[q] = As2[kk][ty*4+q];
        b1[q] = Bs1[kk][tx*4+q]; b2[q] = Bs2[kk][tx*4+q];
      }
      #pragma unroll
      for (int qi = 0; qi < 4; qi++)
        #pragma unroll
        for (int qj = 0; qj < 4; qj++){
          acc1[qi][qj] += a1[qi]*b1[qj];
          acc2[qi][qj] += a2[qi]*b2[qj];
        }
    }
    __syncthreads();
  }
  #pragma unroll
  for (int qi = 0; qi < 4; qi++){
    int gm = bm + ty*4 + qi;
    if (gm >= M) continue;
    #pragma unroll
    for (int qj = 0; qj < 4; qj++){
      int gn = bn + tx*4 + qj;
      if (gn >= Nn) continue;
      float xv = X[(size_t)gm * K + gn];
      float g = 1.f / (1.f + expf(-(acc2[qi][qj] + bias[gn])));
      O[(size_t)gm * ldo + gn] = g * acc1[qi][qj] + (1.f - g) * xv;
    }
  }
}

__global__ void k_dot2_small(const float* __restrict__ X, int ld, int len,
                             const float* __restrict__ wA, const float* __restrict__ wB,
                             float* __restrict__ oA, float* __restrict__ oB,
                             int n, int applyL){
  int v = blockIdx.x * blockDim.x + threadIdx.x;
  if (v >= n) return;
  const float* row = X + (size_t)v * ld;
  float a = 0.f, b = 0.f;
  for (int c = 0; c < len; c++){
    float f = row[c];
    if (applyL) f = lrelu_f(f);
    a += f * wA[c];
    if (wB) b += f * wB[c];
  }
  oA[v] = a;
  if (oB) oB[v] = b;
}

__global__ void k_wave_dot2(const float* __restrict__ X, long ld, int len,
                            const float* __restrict__ wA, const float* __restrict__ wB,
                            float* __restrict__ oA, float* __restrict__ oB,
                            int n, int applyL){
  int gw = (int)(((long)blockIdx.x * blockDim.x + threadIdx.x) >> 6);
  int lane = threadIdx.x & 63;
  if (gw >= n) return;
  const float* row = X + (size_t)gw * ld;
  float a = 0.f, b = 0.f;
  for (int c = lane; c < len; c += 64){
    float f = row[c];
    if (applyL) f = lrelu_f(f);
    a += f * wA[c];
    b += f * wB[c];
  }
  #pragma unroll
  for (int o = 32; o > 0; o >>= 1){
    a += __shfl_down(a, o);
    b += __shfl_down(b, o);
  }
  if (lane == 0){ oA[gw] = a; oB[gw] = b; }
}

__global__ void k_edge_logit(const int* __restrict__ segI, const int* __restrict__ othI,
                             const int* __restrict__ relI,
                             const float* __restrict__ sSeg, const float* __restrict__ sOth,
                             const float* __restrict__ sRel,
                             float* __restrict__ elog, unsigned* __restrict__ mEnc,
                             int E, int applyL){
  int e = blockIdx.x * blockDim.x + threadIdx.x;
  if (e >= E) return;
  int s = segI[e];
  float v = sSeg[s] + sOth[othI[e]];
  if (relI) v += sRel[relI[e]];
  if (applyL) v = lrelu_f(v);
  elog[e] = v;
  atomicMax(mEnc + s, encF(v));
}

__global__ void k_edge_exp(const int* __restrict__ segI, float* __restrict__ elog,
                           const unsigned* __restrict__ mEnc, float* __restrict__ segSum, int E){
  int e = blockIdx.x * blockDim.x + threadIdx.x;
  if (e >= E) return;
  int s = segI[e];
  float ex = expf(elog[e] - decF(mEnc[s]));
  elog[e] = ex;
  atomAddF(segSum + s, ex);
}

// gat_r: oagg[i] += alpha * xin[j], alpha = ex / (sum[j] + eps)  (small: keep atomics)
__global__ void k_gatr_scatter(const int* __restrict__ src, const int* __restrict__ dst,
                               const float* __restrict__ ex, const float* __restrict__ segSum,
                               const float* __restrict__ xin, float* __restrict__ oagg, int F){
  int e = blockIdx.x;
  int j = src[e], i = dst[e];
  float alpha = ex[e] / (segSum[j] + 1e-16f);
  const float* xj = xin + (size_t)j * F;
  float* oi = oagg + (size_t)i * F;
  for (int c = threadIdx.x; c < F; c += blockDim.x)
    atomAddF(oi + c, alpha * xj[c]);
}

__global__ void k_relu_lin(float* __restrict__ p, long n){
  long t = (long)blockIdx.x * blockDim.x + threadIdx.x;
  if (t < n) p[t] = fmaxf(p[t], 0.f);
}

extern "C" void kernel_launch(void* const* d_in, const int* in_sizes, int n_in,
                              void* d_out, int out_size, void* d_ws, size_t ws_size,
                              hipStream_t stream){
  const float* x_e     = (const float*)d_in[0];
  const int*   eiA     = (const int*)  d_in[3];   // edge_index_all [2,E]
  const int*   relAll  = (const int*)  d_in[4];
  const int*   lgOut   = (const int*)  d_in[5];
  const int*   lgIn    = (const int*)  d_in[7];
  const float* gcn1_w  = (const float*)d_in[9];
  const float* gcn2_w  = (const float*)d_in[10];
  const float* hw1_w   = (const float*)d_in[11];
  const float* hw1_b   = (const float*)d_in[12];
  const float* hw2_w   = (const float*)d_in[13];
  const float* hw2_b   = (const float*)d_in[14];
  const float* ww1     = (const float*)d_in[15];
  const float* gat_ai  = (const float*)d_in[16];
  const float* gat_aj  = (const float*)d_in[17];
  const float* gat_ar  = (const float*)d_in[18];
  const float* gatr_ai = (const float*)d_in[19];
  const float* gatr_aj = (const float*)d_in[20];
  const float* relEmb1 = (const float*)d_in[21];

  const int EH = 300, RH = 100;
  const int N   = in_sizes[0] / EH;
  const int E   = in_sizes[3] / 2;
  const int ELG = in_sizes[5] / 2;
  const int R   = in_sizes[21] / RH;

  float* w = (float*)d_ws;
  float* dis    = w; w += N;
  float* bufA   = w; w += (size_t)N * EH;   // agg buffer
  float* bufB   = w; w += (size_t)N * EH;   // x1
  float* relEmb = w; w += (size_t)2 * R * RH;
  float* sxi    = w; w += N;
  float* sxj    = w; w += N;
  unsigned* mEncN = (unsigned*)w; w += N;
  float* sumN   = w; w += N;
  float* sR_i   = w; w += R;
  float* sR_j   = w; w += R;
  unsigned* mEncR = (unsigned*)w; w += R;
  float* sumR   = w; w += R;
  float* aRel   = w; w += 2 * R;
  float* srr    = w; w += 2 * R;
  float* eE     = w; w += E;
  int* degI   = (int*)w; w += N;
  int* cursor = (int*)w; w += N;
  int* offD   = (int*)w; w += N + 1;
  int* offS   = (int*)w; w += N + 1;
  int* permD  = (int*)w; w += E;
  int* permS  = (int*)w; w += E;

  float* out = (float*)d_out;
  const int* srcA = eiA;         // row0 (j in gcn/gat, i in wjq)
  const int* dstA = eiA + E;     // row1

  auto cdiv = [](int a, int b){ return (a + b - 1) / b; };

  // ---- CSR by dst (gcn agg + gat agg) ; dis = in-degree^-0.5 ----
  hipMemsetAsync(degI, 0, (size_t)N * 4, stream);
  hipMemsetAsync(cursor, 0, (size_t)N * 4, stream);
  k_count_int<<<cdiv(E,256),256,0,stream>>>(dstA, degI, E);
  k_scan_excl<<<1,256,0,stream>>>(degI, offD, N);
  k_fill_csr<<<cdiv(E,256),256,0,stream>>>(dstA, offD, cursor, permD, E);
  k_inv_sqrt_int<<<cdiv(N,256),256,0,stream>>>(degI, dis, N);

  // ---- CSR by src (wjq grouping) ----
  hipMemsetAsync(degI, 0, (size_t)N * 4, stream);
  hipMemsetAsync(cursor, 0, (size_t)N * 4, stream);
  k_count_int<<<cdiv(E,256),256,0,stream>>>(srcA, degI, E);
  k_scan_excl<<<1,256,0,stream>>>(degI, offS, N);
  k_fill_csr<<<cdiv(E,256),256,0,stream>>>(srcA, offS, cursor, permS, E);

  dim3 gg((unsigned)cdiv(N,64), (unsigned)cdiv(EH,64));

  // layer 1: x1 = highway(x_e, gcn(x_e))
  k_gcn_gather<<<N,256,0,stream>>>(offD, permD, srcA, x_e, dis, bufA);
  k_dualgemm_hw<<<gg,256,0,stream>>>(bufA, x_e, gcn1_w, hw1_w, hw1_b, bufB, N, EH, EH, EH);

  // layer 2: x2 = highway(x1, gcn(x1)) -> out cols 0:300
  k_gcn_gather<<<N,256,0,stream>>>(offD, permD, srcA, bufB, dis, bufA);
  k_dualgemm_hw<<<gg,256,0,stream>>>(bufA, bufB, gcn2_w, hw2_w, hw2_b, out, N, EH, EH, 2000);

  // gat_r -> relEmb [2R,100]
  k_dot2_small<<<cdiv(R,256),256,0,stream>>>(relEmb1, RH, RH, gatr_ai, gatr_aj, sR_i, sR_j, R, 0);
  hipMemsetAsync(relEmb, 0, (size_t)2*R*RH*4, stream);
  for (int g = 0; g < 2; g++){
    const int* lg = (g == 0) ? lgOut : lgIn;
    float* part = relEmb + (size_t)g * R * RH;
    hipMemsetAsync(mEncR, 0, (size_t)2*R*4, stream);   // mEncR + sumR contiguous
    k_edge_logit<<<cdiv(ELG,256),256,0,stream>>>(lg, lg + ELG, nullptr, sR_j, sR_i, nullptr,
                                                 eE, mEncR, ELG, 1);
    k_edge_exp<<<cdiv(ELG,256),256,0,stream>>>(lg, eE, mEncR, sumR, ELG);
    k_gatr_scatter<<<ELG,128,0,stream>>>(lg, lg + ELG, eE, sumR, relEmb1, part, RH);
  }
  k_relu_lin<<<cdiv(2*R*RH,256),256,0,stream>>>(relEmb, (long)2*R*RH);

  // wjq: softmax grouped by row0 (=i), feat = [ef[i] | re[rel] | ef[j]]
  k_dot2_small<<<cdiv(2*R,256),256,0,stream>>>(relEmb, RH, RH, ww1 + EH, nullptr, aRel, nullptr, 2*R, 1);
  k_wave_dot2<<<cdiv(N,4),256,0,stream>>>(out, 2000, EH, ww1, ww1 + EH + RH, sxi, sxj, N, 1);
  hipMemsetAsync(mEncN, 0, (size_t)2*N*4, stream);     // mEncN + sumN contiguous
  k_edge_logit<<<cdiv(E,256),256,0,stream>>>(srcA, dstA, relAll, sxi, sxj, aRel, eE, mEncN, E, 0);
  k_edge_exp<<<cdiv(E,256),256,0,stream>>>(srcA, eE, mEncN, sumN, E);
  k_wjq_gather<<<N,256,0,stream>>>(offS, permS, dstA, relAll, eE, sumN, relEmb, out);

  // gat over x_wjq (out cols 0:1000), softmax grouped by row1 (=i)
  k_wave_dot2<<<cdiv(N,4),256,0,stream>>>(out, 2000, 1000, gat_ai, gat_aj, sxi, sxj, N, 0);
  k_dot2_small<<<cdiv(2*R,256),256,0,stream>>>(relEmb, RH, RH, gat_ar, nullptr, srr, nullptr, 2*R, 0);
  hipMemsetAsync(mEncN, 0, (size_t)2*N*4, stream);
  k_edge_logit<<<cdiv(E,256),256,0,stream>>>(dstA, srcA, relAll, sxi, sxj, srr, eE, mEncN, E, 1);
  k_edge_exp<<<cdiv(E,256),256,0,stream>>>(dstA, eE, mEncN, sumN, E);
  k_gat_gather<<<N,256,0,stream>>>(offD, permD, srcA, eE, sumN, out);
}

// Round 3
// 857.197 us; speedup vs baseline: 2.4401x; 1.5603x over previous
//
#include <hip/hip_runtime.h>
#include <math.h>

#define LSL 0.01f

typedef _Float16 half8 __attribute__((ext_vector_type(8)));
typedef float floatx4 __attribute__((ext_vector_type(4)));

static __device__ __forceinline__ float lrelu_f(float x){ return x > 0.f ? x : LSL * x; }
static __device__ __forceinline__ void atomAddF(float* p, float v){ unsafeAtomicAdd(p, v); }

// monotone float <-> uint bijection so atomicMax(uint) == float max; 0 encodes < -inf
static __device__ __forceinline__ unsigned encF(float f){
  unsigned u = __float_as_uint(f);
  return (u & 0x80000000u) ? ~u : (u | 0x80000000u);
}
static __device__ __forceinline__ float decF(unsigned u){
  return (u & 0x80000000u) ? __uint_as_float(u & 0x7FFFFFFFu) : __uint_as_float(~u);
}

// ---------------- CSR build ----------------
__global__ void k_count_int(const int* __restrict__ idx, int* __restrict__ deg, int E){
  int e = blockIdx.x * blockDim.x + threadIdx.x;
  if (e < E) atomicAdd(deg + idx[e], 1);
}

__global__ void k_scan_excl(const int* __restrict__ cnt, int* __restrict__ off, int n){
  __shared__ int buf[256];
  __shared__ int carry;
  if (threadIdx.x == 0) carry = 0;
  __syncthreads();
  for (int base = 0; base < n; base += 256){
    int idx = base + threadIdx.x;
    int v = (idx < n) ? cnt[idx] : 0;
    buf[threadIdx.x] = v;
    __syncthreads();
    for (int o = 1; o < 256; o <<= 1){
      int t = (threadIdx.x >= o) ? buf[threadIdx.x - o] : 0;
      __syncthreads();
      buf[threadIdx.x] += t;
      __syncthreads();
    }
    if (idx < n) off[idx] = carry + buf[threadIdx.x] - v;
    __syncthreads();
    if (threadIdx.x == 255) carry += buf[255];
    __syncthreads();
  }
  if (threadIdx.x == 0) off[n] = carry;
}

__global__ void k_fill_csr(const int* __restrict__ idx, const int* __restrict__ off,
                           int* __restrict__ cursor, int* __restrict__ perm, int E){
  int e = blockIdx.x * blockDim.x + threadIdx.x;
  if (e >= E) return;
  int i = idx[e];
  int p = off[i] + atomicAdd(cursor + i, 1);
  perm[p] = e;
}

__global__ void k_inv_sqrt_int(const int* __restrict__ deg, float* __restrict__ dis, int N){
  int v = blockIdx.x * blockDim.x + threadIdx.x;
  if (v < N){ int d = deg[v]; dis[v] = d > 0 ? rsqrtf((float)d) : 0.f; }
}

// ---------------- CSR gathers (no atomics) ----------------
// agg_f16[i][0:320] = relu(sum_e dis[i]*dis[j] * x[j]) zero-padded, F=300
__global__ __launch_bounds__(256)
void k_gcn_gather(const int* __restrict__ off, const int* __restrict__ perm,
                  const int* __restrict__ src, const float* __restrict__ x,
                  const float* __restrict__ dis, _Float16* __restrict__ agg){
  int i = blockIdx.x, t = threadIdx.x;
  int p0 = off[i], p1 = off[i+1];
  float di = dis[i];
  __shared__ int sjv[64]; __shared__ float sw[64];
  float a0 = 0.f, a1 = 0.f;
  for (int pb = p0; pb < p1; pb += 64){
    int m = min(64, p1 - pb);
    if (t < m){ int e = perm[pb + t]; int j = src[e]; sjv[t] = j; sw[t] = di * dis[j]; }
    __syncthreads();
    for (int q = 0; q < m; q++){
      const float* xj = x + (size_t)sjv[q] * 300;
      a0 += sw[q] * xj[t];
      if (t < 44) a1 += sw[q] * xj[t + 256];
    }
    __syncthreads();
  }
  _Float16* o = agg + (size_t)i * 320;
  o[t] = (_Float16)fmaxf(a0, 0.f);
  if (t < 44) o[t + 256] = (_Float16)fmaxf(a1, 0.f);
  else if (t < 64) o[t + 256] = (_Float16)0.f;   // pad cols 300..319
}

// ---------------- MFMA dual-GEMM + highway ----------------
// pack W [K x Nn] f32 into fragment-ready f16: Bf[((ks*5+nt)*4+nf)*64+lane][8]
__global__ void k_prep_B(const float* __restrict__ W, _Float16* __restrict__ Bf,
                         int K, int Nn){
  int idx = blockIdx.x * 256 + threadIdx.x;
  if (idx >= 10*5*4*64) return;
  int lane = idx & 63;
  int rem = idx >> 6;
  int nf = rem & 3; rem >>= 2;
  int nt = rem % 5;
  int ks = rem / 5;
  int n = nt*64 + nf*16 + (lane & 15);
  int kb = ks*32 + (lane >> 4) * 8;
  _Float16* o = Bf + (size_t)idx * 8;
  #pragma unroll
  for (int e = 0; e < 8; e++){
    int k = kb + e;
    float v = (k < K && n < Nn) ? W[(size_t)k * Nn + n] : 0.f;
    o[e] = (_Float16)v;
  }
}

// O = sig(X@Wh + b) * (A1@Wg) + (1-sig)*X ; A1 = relu(agg) f16 [Mpad][320]
__global__ __launch_bounds__(256)
void k_dual_mfma(const _Float16* __restrict__ A1, const float* __restrict__ X,
                 const _Float16* __restrict__ Bf1, const _Float16* __restrict__ Bf2,
                 const float* __restrict__ bias, float* __restrict__ O,
                 int M, long ldo){
  int tid = threadIdx.x;
  int w = tid >> 6, lane = tid & 63;
  int l15 = lane & 15, lg = lane >> 4;
  int nt = blockIdx.x;
  int rowBase = blockIdx.y * 128 + w * 32;
  int colBase = nt * 64;

  floatx4 acc1[2][4], acc2[2][4];
  #pragma unroll
  for (int a = 0; a < 2; a++)
    #pragma unroll
    for (int b = 0; b < 4; b++){
      acc1[a][b] = (floatx4){0.f,0.f,0.f,0.f};
      acc2[a][b] = (floatx4){0.f,0.f,0.f,0.f};
    }

  int row0 = rowBase + l15, row1 = rowBase + 16 + l15;
  int rX0 = min(row0, M-1), rX1 = min(row1, M-1);
  const _Float16* a1p0 = A1 + (size_t)row0 * 320;
  const _Float16* a1p1 = A1 + (size_t)row1 * 320;
  const float* xp0 = X + (size_t)rX0 * 300;
  const float* xp1 = X + (size_t)rX1 * 300;

  for (int ks = 0; ks < 10; ks++){
    int kA = ks*32 + lg*8;
    half8 a1f0 = *(const half8*)(a1p0 + kA);
    half8 a1f1 = *(const half8*)(a1p1 + kA);
    // X (f32) -> f16 frag; clamped addrs keep loads in-row, k>=300 pairs with B=0
    int lo = min(kA, 296), hi = min(kA + 4, 292);
    floatx4 x0l = *(const floatx4*)(xp0 + lo);
    floatx4 x0h = *(const floatx4*)(xp0 + hi);
    floatx4 x1l = *(const floatx4*)(xp1 + lo);
    floatx4 x1h = *(const floatx4*)(xp1 + hi);
    half8 a2f0, a2f1;
    #pragma unroll
    for (int e = 0; e < 4; e++){
      a2f0[e] = (_Float16)x0l[e]; a2f0[e+4] = (_Float16)x0h[e];
      a2f1[e] = (_Float16)x1l[e]; a2f1[e+4] = (_Float16)x1h[e];
    }
    const half8* b1p = (const half8*)Bf1 + ((size_t)(ks*5 + nt) * 4 * 64 + lane);
    const half8* b2p = (const half8*)Bf2 + ((size_t)(ks*5 + nt) * 4 * 64 + lane);
    #pragma unroll
    for (int nf = 0; nf < 4; nf++){
      half8 b1 = b1p[nf*64];
      half8 b2 = b2p[nf*64];
      acc1[0][nf] = __builtin_amdgcn_mfma_f32_16x16x32_f16(a1f0, b1, acc1[0][nf], 0,0,0);
      acc1[1][nf] = __builtin_amdgcn_mfma_f32_16x16x32_f16(a1f1, b1, acc1[1][nf], 0,0,0);
      acc2[0][nf] = __builtin_amdgcn_mfma_f32_16x16x32_f16(a2f0, b2, acc2[0][nf], 0,0,0);
      acc2[1][nf] = __builtin_amdgcn_mfma_f32_16x16x32_f16(a2f1, b2, acc2[1][nf], 0,0,0);
    }
  }

  #pragma unroll
  for (int mf = 0; mf < 2; mf++){
    #pragma unroll
    for (int nf = 0; nf < 4; nf++){
      int gn = colBase + nf*16 + l15;
      int gnc = min(gn, 299);
      float bv = bias[gnc];
      #pragma unroll
      for (int r = 0; r < 4; r++){
        int gm = rowBase + mf*16 + lg*4 + r;
        int gmc = min(gm, M-1);
        float xv = X[(size_t)gmc * 300 + gnc];
        float g = 1.f / (1.f + expf(-(acc2[mf][nf][r] + bv)));
        float val = g * acc1[mf][nf][r] + (1.f - g) * xv;
        if (gm < M && gn < 300) O[(size_t)gm * ldo + gn] = val;
      }
    }
  }
}

// wjq (grouped by i=row0): out[i,600:700] = sum a*lrelu(re[r]); out[i,700:1000] = sum a*lrelu(x2[j]);
// out[i,300:600] = lrelu(x2[i]) * sum(a)
__global__ __launch_bounds__(256)
void k_wjq_gather(const int* __restrict__ off, const int* __restrict__ perm,
                  const int* __restrict__ row1, const int* __restrict__ relI,
                  const float* __restrict__ ex, const float* __restrict__ sums,
                  const float* __restrict__ relEmb, float* __restrict__ out){
  int i = blockIdx.x, t = threadIdx.x;
  int p0 = off[i], p1 = off[i+1];
  float inv = 1.f / (sums[i] + 1e-16f);
  __shared__ int sjv[64], srv[64]; __shared__ float sal[64];
  float a0 = 0.f, a1 = 0.f, sa = 0.f;
  for (int pb = p0; pb < p1; pb += 64){
    int m = min(64, p1 - pb);
    if (t < m){ int e = perm[pb + t]; sjv[t] = row1[e]; srv[t] = relI[e]; sal[t] = ex[e] * inv; }
    __syncthreads();
    for (int q = 0; q < m; q++){
      float al = sal[q]; sa += al;
      const float* rr = relEmb + (size_t)srv[q] * 100;
      const float* xj = out + (size_t)sjv[q] * 2000;   // x2 in cols 0:300
      float v0 = (t < 100) ? rr[t] : xj[t - 100];
      a0 += al * lrelu_f(v0);
      if (t < 144) a1 += al * lrelu_f(xj[t + 156]);
    }
    __syncthreads();
  }
  float* oi = out + (size_t)i * 2000;
  if (t < 100) oi[600 + t] = a0;
  else         oi[700 + (t - 100)] = a0;
  if (t < 144) oi[856 + t] = a1;
  oi[300 + t] = lrelu_f(oi[t]) * sa;
  if (t < 44) oi[556 + t] = lrelu_f(oi[256 + t]) * sa;
}

// gat (grouped by i=row1): out[i,1000:2000] = relu(sum a * x_wjq[j,0:1000])
__global__ __launch_bounds__(256)
void k_gat_gather(const int* __restrict__ off, const int* __restrict__ perm,
                  const int* __restrict__ src, const float* __restrict__ ex,
                  const float* __restrict__ sums, float* __restrict__ out){
  int i = blockIdx.x, t = threadIdx.x;
  int p0 = off[i], p1 = off[i+1];
  float inv = 1.f / (sums[i] + 1e-16f);
  __shared__ int sjv[64]; __shared__ float sal[64];
  float acc[4] = {0.f, 0.f, 0.f, 0.f};
  for (int pb = p0; pb < p1; pb += 64){
    int m = min(64, p1 - pb);
    if (t < m){ int e = perm[pb + t]; sjv[t] = src[e]; sal[t] = ex[e] * inv; }
    __syncthreads();
    for (int q = 0; q < m; q++){
      const float* xj = out + (size_t)sjv[q] * 2000;
      float al = sal[q];
      #pragma unroll
      for (int k = 0; k < 4; k++){
        int c = t + k * 256;
        if (c < 1000) acc[k] += al * xj[c];
      }
    }
    __syncthreads();
  }
  float* oi = out + (size_t)i * 2000 + 1000;
  #pragma unroll
  for (int k = 0; k < 4; k++){
    int c = t + k * 256;
    if (c < 1000) oi[c] = fmaxf(acc[k], 0.f);
  }
}

// ---------------- small kernels ----------------
__global__ void k_dot2_small(const float* __restrict__ X, int ld, int len,
                             const float* __restrict__ wA, const float* __restrict__ wB,
                             float* __restrict__ oA, float* __restrict__ oB,
                             int n, int applyL){
  int v = blockIdx.x * blockDim.x + threadIdx.x;
  if (v >= n) return;
  const float* row = X + (size_t)v * ld;
  float a = 0.f, b = 0.f;
  for (int c = 0; c < len; c++){
    float f = row[c];
    if (applyL) f = lrelu_f(f);
    a += f * wA[c];
    if (wB) b += f * wB[c];
  }
  oA[v] = a;
  if (oB) oB[v] = b;
}

__global__ void k_wave_dot2(const float* __restrict__ X, long ld, int len,
                            const float* __restrict__ wA, const float* __restrict__ wB,
                            float* __restrict__ oA, float* __restrict__ oB,
                            int n, int applyL){
  int gw = (int)(((long)blockIdx.x * blockDim.x + threadIdx.x) >> 6);
  int lane = threadIdx.x & 63;
  if (gw >= n) return;
  const float* row = X + (size_t)gw * ld;
  float a = 0.f, b = 0.f;
  for (int c = lane; c < len; c += 64){
    float f = row[c];
    if (applyL) f = lrelu_f(f);
    a += f * wA[c];
    b += f * wB[c];
  }
  #pragma unroll
  for (int o = 32; o > 0; o >>= 1){
    a += __shfl_down(a, o);
    b += __shfl_down(b, o);
  }
  if (lane == 0){ oA[gw] = a; oB[gw] = b; }
}

__global__ void k_edge_logit(const int* __restrict__ segI, const int* __restrict__ othI,
                             const int* __restrict__ relI,
                             const float* __restrict__ sSeg, const float* __restrict__ sOth,
                             const float* __restrict__ sRel,
                             float* __restrict__ elog, unsigned* __restrict__ mEnc,
                             int E, int applyL){
  int e = blockIdx.x * blockDim.x + threadIdx.x;
  if (e >= E) return;
  int s = segI[e];
  float v = sSeg[s] + sOth[othI[e]];
  if (relI) v += sRel[relI[e]];
  if (applyL) v = lrelu_f(v);
  elog[e] = v;
  atomicMax(mEnc + s, encF(v));
}

__global__ void k_edge_exp(const int* __restrict__ segI, float* __restrict__ elog,
                           const unsigned* __restrict__ mEnc, float* __restrict__ segSum, int E){
  int e = blockIdx.x * blockDim.x + threadIdx.x;
  if (e >= E) return;
  int s = segI[e];
  float ex = expf(elog[e] - decF(mEnc[s]));
  elog[e] = ex;
  atomAddF(segSum + s, ex);
}

__global__ void k_gatr_scatter(const int* __restrict__ src, const int* __restrict__ dst,
                               const float* __restrict__ ex, const float* __restrict__ segSum,
                               const float* __restrict__ xin, float* __restrict__ oagg, int F){
  int e = blockIdx.x;
  int j = src[e], i = dst[e];
  float alpha = ex[e] / (segSum[j] + 1e-16f);
  const float* xj = xin + (size_t)j * F;
  float* oi = oagg + (size_t)i * F;
  for (int c = threadIdx.x; c < F; c += blockDim.x)
    atomAddF(oi + c, alpha * xj[c]);
}

__global__ void k_relu_lin(float* __restrict__ p, long n){
  long t = (long)blockIdx.x * blockDim.x + threadIdx.x;
  if (t < n) p[t] = fmaxf(p[t], 0.f);
}

extern "C" void kernel_launch(void* const* d_in, const int* in_sizes, int n_in,
                              void* d_out, int out_size, void* d_ws, size_t ws_size,
                              hipStream_t stream){
  const float* x_e     = (const float*)d_in[0];
  const int*   eiA     = (const int*)  d_in[3];   // edge_index_all [2,E]
  const int*   relAll  = (const int*)  d_in[4];
  const int*   lgOut   = (const int*)  d_in[5];
  const int*   lgIn    = (const int*)  d_in[7];
  const float* gcn1_w  = (const float*)d_in[9];
  const float* gcn2_w  = (const float*)d_in[10];
  const float* hw1_w   = (const float*)d_in[11];
  const float* hw1_b   = (const float*)d_in[12];
  const float* hw2_w   = (const float*)d_in[13];
  const float* hw2_b   = (const float*)d_in[14];
  const float* ww1     = (const float*)d_in[15];
  const float* gat_ai  = (const float*)d_in[16];
  const float* gat_aj  = (const float*)d_in[17];
  const float* gat_ar  = (const float*)d_in[18];
  const float* gatr_ai = (const float*)d_in[19];
  const float* gatr_aj = (const float*)d_in[20];
  const float* relEmb1 = (const float*)d_in[21];

  const int EH = 300, RH = 100;
  const int N   = in_sizes[0] / EH;
  const int E   = in_sizes[3] / 2;
  const int ELG = in_sizes[5] / 2;
  const int R   = in_sizes[21] / RH;
  const int Mtiles = (N + 127) / 128;
  const int Mpad = Mtiles * 128;

  // ---- workspace layout (16B-aligned blocks first) ----
  char* base = (char*)d_ws;
  _Float16* A1f16 = (_Float16*)base;  base += (size_t)Mpad * 320 * 2;
  _Float16* BfAll = (_Float16*)base;  base += (size_t)4 * 102400 * 2;
  float* w = (float*)base;
  float* dis    = w; w += N;
  float* bufB   = w; w += (size_t)N * EH;   // x1
  float* relEmb = w; w += (size_t)2 * R * RH;
  float* sxi    = w; w += N;
  float* sxj    = w; w += N;
  unsigned* mEncN = (unsigned*)w; w += N;
  float* sumN   = w; w += N;
  float* sR_i   = w; w += R;
  float* sR_j   = w; w += R;
  unsigned* mEncR = (unsigned*)w; w += R;
  float* sumR   = w; w += R;
  float* aRel   = w; w += 2 * R;
  float* srr    = w; w += 2 * R;
  float* eE     = w; w += E;
  int* degI   = (int*)w; w += N;
  int* cursor = (int*)w; w += N;
  int* offD   = (int*)w; w += N + 1;
  int* offS   = (int*)w; w += N + 1;
  int* permD  = (int*)w; w += E;
  int* permS  = (int*)w; w += E;

  _Float16* Bf_g1 = BfAll;
  _Float16* Bf_h1 = BfAll + 102400;
  _Float16* Bf_g2 = BfAll + 2 * 102400;
  _Float16* Bf_h2 = BfAll + 3 * 102400;

  float* out = (float*)d_out;
  const int* srcA = eiA;         // row0 (j in gcn/gat, i in wjq)
  const int* dstA = eiA + E;     // row1

  auto cdiv = [](int a, int b){ return (a + b - 1) / b; };

  // ---- CSR by dst (gcn agg + gat agg) ; dis = in-degree^-0.5 ----
  hipMemsetAsync(degI, 0, (size_t)N * 4, stream);
  hipMemsetAsync(cursor, 0, (size_t)N * 4, stream);
  k_count_int<<<cdiv(E,256),256,0,stream>>>(dstA, degI, E);
  k_scan_excl<<<1,256,0,stream>>>(degI, offD, N);
  k_fill_csr<<<cdiv(E,256),256,0,stream>>>(dstA, offD, cursor, permD, E);
  k_inv_sqrt_int<<<cdiv(N,256),256,0,stream>>>(degI, dis, N);

  // ---- CSR by src (wjq grouping) ----
  hipMemsetAsync(degI, 0, (size_t)N * 4, stream);
  hipMemsetAsync(cursor, 0, (size_t)N * 4, stream);
  k_count_int<<<cdiv(E,256),256,0,stream>>>(srcA, degI, E);
  k_scan_excl<<<1,256,0,stream>>>(degI, offS, N);
  k_fill_csr<<<cdiv(E,256),256,0,stream>>>(srcA, offS, cursor, permS, E);

  // ---- pack weights into MFMA fragment layout (tiny, once per call) ----
  k_prep_B<<<50,256,0,stream>>>(gcn1_w, Bf_g1, EH, EH);
  k_prep_B<<<50,256,0,stream>>>(hw1_w,  Bf_h1, EH, EH);
  k_prep_B<<<50,256,0,stream>>>(gcn2_w, Bf_g2, EH, EH);
  k_prep_B<<<50,256,0,stream>>>(hw2_w,  Bf_h2, EH, EH);

  dim3 gmm(5, (unsigned)Mtiles);

  // layer 1: x1 = highway(x_e, gcn(x_e))
  k_gcn_gather<<<N,256,0,stream>>>(offD, permD, srcA, x_e, dis, A1f16);
  k_dual_mfma<<<gmm,256,0,stream>>>(A1f16, x_e, Bf_g1, Bf_h1, hw1_b, bufB, N, EH);

  // layer 2: x2 = highway(x1, gcn(x1)) -> out cols 0:300
  k_gcn_gather<<<N,256,0,stream>>>(offD, permD, srcA, bufB, dis, A1f16);
  k_dual_mfma<<<gmm,256,0,stream>>>(A1f16, bufB, Bf_g2, Bf_h2, hw2_b, out, N, 2000);

  // gat_r -> relEmb [2R,100]
  k_dot2_small<<<cdiv(R,256),256,0,stream>>>(relEmb1, RH, RH, gatr_ai, gatr_aj, sR_i, sR_j, R, 0);
  hipMemsetAsync(relEmb, 0, (size_t)2*R*RH*4, stream);
  for (int g = 0; g < 2; g++){
    const int* lg = (g == 0) ? lgOut : lgIn;
    float* part = relEmb + (size_t)g * R * RH;
    hipMemsetAsync(mEncR, 0, (size_t)2*R*4, stream);   // mEncR + sumR contiguous
    k_edge_logit<<<cdiv(ELG,256),256,0,stream>>>(lg, lg + ELG, nullptr, sR_j, sR_i, nullptr,
                                                 eE, mEncR, ELG, 1);
    k_edge_exp<<<cdiv(ELG,256),256,0,stream>>>(lg, eE, mEncR, sumR, ELG);
    k_gatr_scatter<<<ELG,128,0,stream>>>(lg, lg + ELG, eE, sumR, relEmb1, part, RH);
  }
  k_relu_lin<<<cdiv(2*R*RH,256),256,0,stream>>>(relEmb, (long)2*R*RH);

  // wjq: softmax grouped by row0 (=i), feat = [ef[i] | re[rel] | ef[j]]
  k_dot2_small<<<cdiv(2*R,256),256,0,stream>>>(relEmb, RH, RH, ww1 + EH, nullptr, aRel, nullptr, 2*R, 1);
  k_wave_dot2<<<cdiv(N,4),256,0,stream>>>(out, 2000, EH, ww1, ww1 + EH + RH, sxi, sxj, N, 1);
  hipMemsetAsync(mEncN, 0, (size_t)2*N*4, stream);     // mEncN + sumN contiguous
  k_edge_logit<<<cdiv(E,256),256,0,stream>>>(srcA, dstA, relAll, sxi, sxj, aRel, eE, mEncN, E, 0);
  k_edge_exp<<<cdiv(E,256),256,0,stream>>>(srcA, eE, mEncN, sumN, E);
  k_wjq_gather<<<N,256,0,stream>>>(offS, permS, dstA, relAll, eE, sumN, relEmb, out);

  // gat over x_wjq (out cols 0:1000), softmax grouped by row1 (=i)
  k_wave_dot2<<<cdiv(N,4),256,0,stream>>>(out, 2000, 1000, gat_ai, gat_aj, sxi, sxj, N, 0);
  k_dot2_small<<<cdiv(2*R,256),256,0,stream>>>(relEmb, RH, RH, gat_ar, nullptr, srr, nullptr, 2*R, 0);
  hipMemsetAsync(mEncN, 0, (size_t)2*N*4, stream);
  k_edge_logit<<<cdiv(E,256),256,0,stream>>>(dstA, srcA, relAll, sxi, sxj, srr, eE, mEncN, E, 1);
  k_edge_exp<<<cdiv(E,256),256,0,stream>>>(dstA, eE, mEncN, sumN, E);
  k_gat_gather<<<N,256,0,stream>>>(offD, permD, srcA, eE, sumN, out);
}

// Round 4
// 832.515 us; speedup vs baseline: 2.5124x; 1.0296x over previous
//
#include <hip/hip_runtime.h>
#include <math.h>

#define LSL 0.01f

typedef _Float16 half8 __attribute__((ext_vector_type(8)));
typedef _Float16 half4 __attribute__((ext_vector_type(4)));
typedef _Float16 half2 __attribute__((ext_vector_type(2)));
typedef float floatx4 __attribute__((ext_vector_type(4)));

static __device__ __forceinline__ float lrelu_f(float x){ return x > 0.f ? x : LSL * x; }
static __device__ __forceinline__ void atomAddF(float* p, float v){ unsafeAtomicAdd(p, v); }

// monotone float <-> uint bijection so atomicMax(uint) == float max; 0 encodes < -inf
static __device__ __forceinline__ unsigned encF(float f){
  unsigned u = __float_as_uint(f);
  return (u & 0x80000000u) ? ~u : (u | 0x80000000u);
}
static __device__ __forceinline__ float decF(unsigned u){
  return (u & 0x80000000u) ? __uint_as_float(u & 0x7FFFFFFFu) : __uint_as_float(~u);
}

// ---------------- CSR build ----------------
__global__ void k_count_int(const int* __restrict__ idx, int* __restrict__ deg, int E){
  int e = blockIdx.x * blockDim.x + threadIdx.x;
  if (e < E) atomicAdd(deg + idx[e], 1);
}

__global__ void k_scan_excl(const int* __restrict__ cnt, int* __restrict__ off, int n){
  __shared__ int buf[256];
  __shared__ int carry;
  if (threadIdx.x == 0) carry = 0;
  __syncthreads();
  for (int base = 0; base < n; base += 256){
    int idx = base + threadIdx.x;
    int v = (idx < n) ? cnt[idx] : 0;
    buf[threadIdx.x] = v;
    __syncthreads();
    for (int o = 1; o < 256; o <<= 1){
      int t = (threadIdx.x >= o) ? buf[threadIdx.x - o] : 0;
      __syncthreads();
      buf[threadIdx.x] += t;
      __syncthreads();
    }
    if (idx < n) off[idx] = carry + buf[threadIdx.x] - v;
    __syncthreads();
    if (threadIdx.x == 255) carry += buf[255];
    __syncthreads();
  }
  if (threadIdx.x == 0) off[n] = carry;
}

__global__ void k_fill_csr(const int* __restrict__ idx, const int* __restrict__ off,
                           int* __restrict__ cursor, int* __restrict__ perm, int E){
  int e = blockIdx.x * blockDim.x + threadIdx.x;
  if (e >= E) return;
  int i = idx[e];
  int p = off[i] + atomicAdd(cursor + i, 1);
  perm[p] = e;
}

__global__ void k_inv_sqrt_int(const int* __restrict__ deg, float* __restrict__ dis, int N){
  int v = blockIdx.x * blockDim.x + threadIdx.x;
  if (v < N){ int d = deg[v]; dis[v] = d > 0 ? rsqrtf((float)d) : 0.f; }
}

// x_e f32 [N][300] -> xhA f16 [Mpad][320] zero-padded (cols 300:320, rows N:Mpad)
__global__ __launch_bounds__(256)
void k_conv_f16(const float* __restrict__ x, _Float16* __restrict__ xh, int N){
  int i = blockIdx.x, t = threadIdx.x;
  _Float16* o = xh + (size_t)i * 320;
  if (i < N){
    const float* r = x + (size_t)i * 300;
    o[t] = (_Float16)r[t];
    if (t < 44) o[t + 256] = (_Float16)r[t + 256];
    else if (t < 64) o[t + 256] = (_Float16)0.f;
  } else {
    o[t] = (_Float16)0.f;
    if (t < 64) o[t + 256] = (_Float16)0.f;
  }
}

// ---------------- CSR gathers (no atomics, f16 sources) ----------------
// agg_f16[i][0:320] = relu(sum_e dis[i]*dis[j] * xh[j]) zero-padded, F=300
__global__ __launch_bounds__(256)
void k_gcn_gather(const int* __restrict__ off, const int* __restrict__ perm,
                  const int* __restrict__ src, const _Float16* __restrict__ x,
                  const float* __restrict__ dis, _Float16* __restrict__ agg){
  int i = blockIdx.x, t = threadIdx.x;
  int p0 = off[i], p1 = off[i+1];
  float di = dis[i];
  __shared__ int sjv[64]; __shared__ float sw[64];
  float a0 = 0.f, a1 = 0.f;
  for (int pb = p0; pb < p1; pb += 64){
    int m = min(64, p1 - pb);
    if (t < m){ int e = perm[pb + t]; int j = src[e]; sjv[t] = j; sw[t] = di * dis[j]; }
    __syncthreads();
    for (int q = 0; q < m; q++){
      const _Float16* xj = x + (size_t)sjv[q] * 320;
      a0 += sw[q] * (float)xj[t];
      if (t < 44) a1 += sw[q] * (float)xj[t + 256];
    }
    __syncthreads();
  }
  _Float16* o = agg + (size_t)i * 320;
  o[t] = (_Float16)fmaxf(a0, 0.f);
  if (t < 44) o[t + 256] = (_Float16)fmaxf(a1, 0.f);
  else if (t < 64) o[t + 256] = (_Float16)0.f;
}

// ---------------- MFMA dual-GEMM + highway ----------------
// pack W [K x Nn] f32 into fragment-ready f16: Bf[((ks*5+nt)*4+nf)*64+lane][8]
__global__ void k_prep_B(const float* __restrict__ W, _Float16* __restrict__ Bf,
                         int K, int Nn){
  int idx = blockIdx.x * 256 + threadIdx.x;
  if (idx >= 10*5*4*64) return;
  int lane = idx & 63;
  int rem = idx >> 6;
  int nf = rem & 3; rem >>= 2;
  int nt = rem % 5;
  int ks = rem / 5;
  int n = nt*64 + nf*16 + (lane & 15);
  int kb = ks*32 + (lane >> 4) * 8;
  _Float16* o = Bf + (size_t)idx * 8;
  #pragma unroll
  for (int e = 0; e < 8; e++){
    int k = kb + e;
    float v = (k < K && n < Nn) ? W[(size_t)k * Nn + n] : 0.f;
    o[e] = (_Float16)v;
  }
}

// O = sig(X@Wh + b) * (A1@Wg) + (1-sig)*X ; A1 = relu(agg) f16 [Mpad][320]
// A2/X source: Xf32 (f32 [N][300], clamped rows) OR Xh (f16 [Mpad][320], padded).
// Outputs: optional f32 (ldo) and optional f16 mirror (ldm).
__global__ __launch_bounds__(256)
void k_dual_mfma(const _Float16* __restrict__ A1, const float* __restrict__ Xf32,
                 const _Float16* __restrict__ Xh,
                 const _Float16* __restrict__ Bf1, const _Float16* __restrict__ Bf2,
                 const float* __restrict__ bias, float* __restrict__ Of32, long ldo,
                 _Float16* __restrict__ Oh, long ldm, int M){
  int tid = threadIdx.x;
  int w = tid >> 6, lane = tid & 63;
  int l15 = lane & 15, lg = lane >> 4;
  int nt = blockIdx.x;
  int rowBase = blockIdx.y * 128 + w * 32;
  int colBase = nt * 64;

  floatx4 acc1[2][4], acc2[2][4];
  #pragma unroll
  for (int a = 0; a < 2; a++)
    #pragma unroll
    for (int b = 0; b < 4; b++){
      acc1[a][b] = (floatx4){0.f,0.f,0.f,0.f};
      acc2[a][b] = (floatx4){0.f,0.f,0.f,0.f};
    }

  int row0 = rowBase + l15, row1 = rowBase + 16 + l15;
  int rX0 = min(row0, M-1), rX1 = min(row1, M-1);
  const _Float16* a1p0 = A1 + (size_t)row0 * 320;
  const _Float16* a1p1 = A1 + (size_t)row1 * 320;

  for (int ks = 0; ks < 10; ks++){
    int kA = ks*32 + lg*8;
    half8 a1f0 = *(const half8*)(a1p0 + kA);
    half8 a1f1 = *(const half8*)(a1p1 + kA);
    half8 a2f0, a2f1;
    if (Xh){
      a2f0 = *(const half8*)(Xh + (size_t)row0 * 320 + kA);
      a2f1 = *(const half8*)(Xh + (size_t)row1 * 320 + kA);
    } else {
      const float* xp0 = Xf32 + (size_t)rX0 * 300;
      const float* xp1 = Xf32 + (size_t)rX1 * 300;
      int lo = min(kA, 296), hi = min(kA + 4, 292);
      floatx4 x0l = *(const floatx4*)(xp0 + lo);
      floatx4 x0h = *(const floatx4*)(xp0 + hi);
      floatx4 x1l = *(const floatx4*)(xp1 + lo);
      floatx4 x1h = *(const floatx4*)(xp1 + hi);
      #pragma unroll
      for (int e = 0; e < 4; e++){
        a2f0[e] = (_Float16)x0l[e]; a2f0[e+4] = (_Float16)x0h[e];
        a2f1[e] = (_Float16)x1l[e]; a2f1[e+4] = (_Float16)x1h[e];
      }
    }
    const half8* b1p = (const half8*)Bf1 + ((size_t)(ks*5 + nt) * 4 * 64 + lane);
    const half8* b2p = (const half8*)Bf2 + ((size_t)(ks*5 + nt) * 4 * 64 + lane);
    #pragma unroll
    for (int nf = 0; nf < 4; nf++){
      half8 b1 = b1p[nf*64];
      half8 b2 = b2p[nf*64];
      acc1[0][nf] = __builtin_amdgcn_mfma_f32_16x16x32_f16(a1f0, b1, acc1[0][nf], 0,0,0);
      acc1[1][nf] = __builtin_amdgcn_mfma_f32_16x16x32_f16(a1f1, b1, acc1[1][nf], 0,0,0);
      acc2[0][nf] = __builtin_amdgcn_mfma_f32_16x16x32_f16(a2f0, b2, acc2[0][nf], 0,0,0);
      acc2[1][nf] = __builtin_amdgcn_mfma_f32_16x16x32_f16(a2f1, b2, acc2[1][nf], 0,0,0);
    }
  }

  #pragma unroll
  for (int mf = 0; mf < 2; mf++){
    #pragma unroll
    for (int nf = 0; nf < 4; nf++){
      int gn = colBase + nf*16 + l15;
      int gnc = min(gn, 299);
      float bv = bias[gnc];
      #pragma unroll
      for (int r = 0; r < 4; r++){
        int gm = rowBase + mf*16 + lg*4 + r;
        int gmc = min(gm, M-1);
        float xv = Xh ? (float)Xh[(size_t)gmc * 320 + gnc]
                      : Xf32[(size_t)gmc * 300 + gnc];
        float g = 1.f / (1.f + expf(-(acc2[mf][nf][r] + bv)));
        float val = g * acc1[mf][nf][r] + (1.f - g) * xv;
        if (gm < M && gn < 300){
          if (Of32) Of32[(size_t)gm * ldo + gn] = val;
          if (Oh)   Oh[(size_t)gm * ldm + gn] = (_Float16)val;
        }
      }
    }
  }
}

// wjq (grouped by i=row0): out[i,600:700] = sum a*lrelu(re[r]); out[i,700:1000] = sum a*lrelu(x2[j]);
// out[i,300:600] = lrelu(x2[i]) * sum(a). Also mirrors cols 300:1000 into xh2 f16.
__global__ __launch_bounds__(256)
void k_wjq_gather(const int* __restrict__ off, const int* __restrict__ perm,
                  const int* __restrict__ row1, const int* __restrict__ relI,
                  const float* __restrict__ ex, const float* __restrict__ sums,
                  const float* __restrict__ relEmb, float* __restrict__ out,
                  _Float16* __restrict__ xh2){
  int i = blockIdx.x, t = threadIdx.x;
  int p0 = off[i], p1 = off[i+1];
  float inv = 1.f / (sums[i] + 1e-16f);
  __shared__ int sjv[64], srv[64]; __shared__ float sal[64];
  float a0 = 0.f, a1 = 0.f, sa = 0.f;
  for (int pb = p0; pb < p1; pb += 64){
    int m = min(64, p1 - pb);
    if (t < m){ int e = perm[pb + t]; sjv[t] = row1[e]; srv[t] = relI[e]; sal[t] = ex[e] * inv; }
    __syncthreads();
    for (int q = 0; q < m; q++){
      float al = sal[q]; sa += al;
      const float* rr = relEmb + (size_t)srv[q] * 100;
      const _Float16* xj = xh2 + (size_t)sjv[q] * 1024;   // x2 f16 in cols 0:300
      float v0 = (t < 100) ? rr[t] : (float)xj[t - 100];
      a0 += al * lrelu_f(v0);
      if (t < 144) a1 += al * lrelu_f((float)xj[t + 156]);
    }
    __syncthreads();
  }
  float* oi = out + (size_t)i * 2000;
  _Float16* hi = xh2 + (size_t)i * 1024;
  int c0 = (t < 100) ? (600 + t) : (700 + (t - 100));
  oi[c0] = a0; hi[c0] = (_Float16)a0;
  if (t < 144){ oi[856 + t] = a1; hi[856 + t] = (_Float16)a1; }
  float h0 = lrelu_f(oi[t]) * sa;
  oi[300 + t] = h0; hi[300 + t] = (_Float16)h0;
  if (t < 44){
    float h1 = lrelu_f(oi[256 + t]) * sa;
    oi[556 + t] = h1; hi[556 + t] = (_Float16)h1;
  }
}

// gat (grouped by i=row1): out[i,1000:2000] = relu(sum a * xh2[j,0:1000])
__global__ __launch_bounds__(256)
void k_gat_gather(const int* __restrict__ off, const int* __restrict__ perm,
                  const int* __restrict__ src, const float* __restrict__ ex,
                  const float* __restrict__ sums, const _Float16* __restrict__ xh2,
                  float* __restrict__ out){
  int i = blockIdx.x, t = threadIdx.x;
  int p0 = off[i], p1 = off[i+1];
  float inv = 1.f / (sums[i] + 1e-16f);
  __shared__ int sjv[64]; __shared__ float sal[64];
  float acc[4] = {0.f, 0.f, 0.f, 0.f};
  for (int pb = p0; pb < p1; pb += 64){
    int m = min(64, p1 - pb);
    if (t < m){ int e = perm[pb + t]; sjv[t] = src[e]; sal[t] = ex[e] * inv; }
    __syncthreads();
    for (int q = 0; q < m; q++){
      float al = sal[q];
      if (t < 250){
        half4 v = *(const half4*)(xh2 + (size_t)sjv[q] * 1024 + 4*t);
        #pragma unroll
        for (int k = 0; k < 4; k++) acc[k] += al * (float)v[k];
      }
    }
    __syncthreads();
  }
  if (t < 250){
    floatx4 o;
    #pragma unroll
    for (int k = 0; k < 4; k++) o[k] = fmaxf(acc[k], 0.f);
    *(floatx4*)(out + (size_t)i * 2000 + 1000 + 4*t) = o;
  }
}

// ---------------- small kernels ----------------
__global__ void k_dot2_small(const float* __restrict__ X, int ld, int len,
                             const float* __restrict__ wA, const float* __restrict__ wB,
                             float* __restrict__ oA, float* __restrict__ oB,
                             int n, int applyL){
  int v = blockIdx.x * blockDim.x + threadIdx.x;
  if (v >= n) return;
  const float* row = X + (size_t)v * ld;
  float a = 0.f, b = 0.f;
  for (int c = 0; c < len; c++){
    float f = row[c];
    if (applyL) f = lrelu_f(f);
    a += f * wA[c];
    if (wB) b += f * wB[c];
  }
  oA[v] = a;
  if (oB) oB[v] = b;
}

// wave-per-row dual dot over f16 rows
__global__ void k_wave_dot2_h(const _Float16* __restrict__ X, long ld, int len,
                              const float* __restrict__ wA, const float* __restrict__ wB,
                              float* __restrict__ oA, float* __restrict__ oB,
                              int n, int applyL){
  int gw = (int)(((long)blockIdx.x * blockDim.x + threadIdx.x) >> 6);
  int lane = threadIdx.x & 63;
  if (gw >= n) return;
  const _Float16* row = X + (size_t)gw * ld;
  float a = 0.f, b = 0.f;
  for (int c = lane*2; c < len; c += 128){
    half2 v = *(const half2*)(row + c);
    float f0 = (float)v[0], f1 = (float)v[1];
    if (applyL){ f0 = lrelu_f(f0); f1 = lrelu_f(f1); }
    a += f0 * wA[c] + f1 * wA[c+1];
    b += f0 * wB[c] + f1 * wB[c+1];
  }
  #pragma unroll
  for (int o = 32; o > 0; o >>= 1){
    a += __shfl_down(a, o);
    b += __shfl_down(b, o);
  }
  if (lane == 0){ oA[gw] = a; oB[gw] = b; }
}

__global__ void k_edge_logit(const int* __restrict__ segI, const int* __restrict__ othI,
                             const int* __restrict__ relI,
                             const float* __restrict__ sSeg, const float* __restrict__ sOth,
                             const float* __restrict__ sRel,
                             float* __restrict__ elog, unsigned* __restrict__ mEnc,
                             int E, int applyL){
  int e = blockIdx.x * blockDim.x + threadIdx.x;
  if (e >= E) return;
  int s = segI[e];
  float v = sSeg[s] + sOth[othI[e]];
  if (relI) v += sRel[relI[e]];
  if (applyL) v = lrelu_f(v);
  elog[e] = v;
  atomicMax(mEnc + s, encF(v));
}

__global__ void k_edge_exp(const int* __restrict__ segI, float* __restrict__ elog,
                           const unsigned* __restrict__ mEnc, float* __restrict__ segSum, int E){
  int e = blockIdx.x * blockDim.x + threadIdx.x;
  if (e >= E) return;
  int s = segI[e];
  float ex = expf(elog[e] - decF(mEnc[s]));
  elog[e] = ex;
  atomAddF(segSum + s, ex);
}

__global__ void k_gatr_scatter(const int* __restrict__ src, const int* __restrict__ dst,
                               const float* __restrict__ ex, const float* __restrict__ segSum,
                               const float* __restrict__ xin, float* __restrict__ oagg, int F){
  int e = blockIdx.x;
  int j = src[e], i = dst[e];
  float alpha = ex[e] / (segSum[j] + 1e-16f);
  const float* xj = xin + (size_t)j * F;
  float* oi = oagg + (size_t)i * F;
  for (int c = threadIdx.x; c < F; c += blockDim.x)
    atomAddF(oi + c, alpha * xj[c]);
}

__global__ void k_relu_lin(float* __restrict__ p, long n){
  long t = (long)blockIdx.x * blockDim.x + threadIdx.x;
  if (t < n) p[t] = fmaxf(p[t], 0.f);
}

extern "C" void kernel_launch(void* const* d_in, const int* in_sizes, int n_in,
                              void* d_out, int out_size, void* d_ws, size_t ws_size,
                              hipStream_t stream){
  const float* x_e     = (const float*)d_in[0];
  const int*   eiA     = (const int*)  d_in[3];   // edge_index_all [2,E]
  const int*   relAll  = (const int*)  d_in[4];
  const int*   lgOut   = (const int*)  d_in[5];
  const int*   lgIn    = (const int*)  d_in[7];
  const float* gcn1_w  = (const float*)d_in[9];
  const float* gcn2_w  = (const float*)d_in[10];
  const float* hw1_w   = (const float*)d_in[11];
  const float* hw1_b   = (const float*)d_in[12];
  const float* hw2_w   = (const float*)d_in[13];
  const float* hw2_b   = (const float*)d_in[14];
  const float* ww1     = (const float*)d_in[15];
  const float* gat_ai  = (const float*)d_in[16];
  const float* gat_aj  = (const float*)d_in[17];
  const float* gat_ar  = (const float*)d_in[18];
  const float* gatr_ai = (const float*)d_in[19];
  const float* gatr_aj = (const float*)d_in[20];
  const float* relEmb1 = (const float*)d_in[21];

  const int EH = 300, RH = 100;
  const int N   = in_sizes[0] / EH;
  const int E   = in_sizes[3] / 2;
  const int ELG = in_sizes[5] / 2;
  const int R   = in_sizes[21] / RH;
  const int Mtiles = (N + 127) / 128;
  const int Mpad = Mtiles * 128;

  // ---- workspace layout (16B-aligned f16 blocks first) ----
  char* base = (char*)d_ws;
  _Float16* xhA   = (_Float16*)base;  base += (size_t)Mpad * 320 * 2;   // x_e f16 -> x1 f16
  _Float16* A1f16 = (_Float16*)base;  base += (size_t)Mpad * 320 * 2;   // relu(agg) f16
  _Float16* xh2   = (_Float16*)base;  base += (size_t)N * 1024 * 2;     // x_wjq f16 mirror
  _Float16* BfAll = (_Float16*)base;  base += (size_t)4 * 102400 * 2;
  float* w = (float*)base;
  float* dis    = w; w += N;
  float* relEmb = w; w += (size_t)2 * R * RH;
  float* sxi    = w; w += N;
  float* sxj    = w; w += N;
  unsigned* mEncN = (unsigned*)w; w += N;
  float* sumN   = w; w += N;
  float* sR_i   = w; w += R;
  float* sR_j   = w; w += R;
  unsigned* mEncR = (unsigned*)w; w += R;
  float* sumR   = w; w += R;
  float* aRel   = w; w += 2 * R;
  float* srr    = w; w += 2 * R;
  float* eE     = w; w += E;
  int* degI   = (int*)w; w += N;
  int* cursor = (int*)w; w += N;
  int* offD   = (int*)w; w += N + 1;
  int* offS   = (int*)w; w += N + 1;
  int* permD  = (int*)w; w += E;
  int* permS  = (int*)w; w += E;

  _Float16* Bf_g1 = BfAll;
  _Float16* Bf_h1 = BfAll + 102400;
  _Float16* Bf_g2 = BfAll + 2 * 102400;
  _Float16* Bf_h2 = BfAll + 3 * 102400;

  float* out = (float*)d_out;
  const int* srcA = eiA;         // row0 (j in gcn/gat, i in wjq)
  const int* dstA = eiA + E;     // row1

  auto cdiv = [](int a, int b){ return (a + b - 1) / b; };

  // ---- CSR by dst (gcn agg + gat agg) ; dis = in-degree^-0.5 ----
  hipMemsetAsync(degI, 0, (size_t)N * 4, stream);
  hipMemsetAsync(cursor, 0, (size_t)N * 4, stream);
  k_count_int<<<cdiv(E,256),256,0,stream>>>(dstA, degI, E);
  k_scan_excl<<<1,256,0,stream>>>(degI, offD, N);
  k_fill_csr<<<cdiv(E,256),256,0,stream>>>(dstA, offD, cursor, permD, E);
  k_inv_sqrt_int<<<cdiv(N,256),256,0,stream>>>(degI, dis, N);

  // ---- CSR by src (wjq grouping) ----
  hipMemsetAsync(degI, 0, (size_t)N * 4, stream);
  hipMemsetAsync(cursor, 0, (size_t)N * 4, stream);
  k_count_int<<<cdiv(E,256),256,0,stream>>>(srcA, degI, E);
  k_scan_excl<<<1,256,0,stream>>>(degI, offS, N);
  k_fill_csr<<<cdiv(E,256),256,0,stream>>>(srcA, offS, cursor, permS, E);

  // ---- pack weights into MFMA fragment layout; convert x_e to f16 ----
  k_prep_B<<<50,256,0,stream>>>(gcn1_w, Bf_g1, EH, EH);
  k_prep_B<<<50,256,0,stream>>>(hw1_w,  Bf_h1, EH, EH);
  k_prep_B<<<50,256,0,stream>>>(gcn2_w, Bf_g2, EH, EH);
  k_prep_B<<<50,256,0,stream>>>(hw2_w,  Bf_h2, EH, EH);
  k_conv_f16<<<Mpad,256,0,stream>>>(x_e, xhA, N);
  // zero A1f16 pad rows once per call (gathers rewrite rows < N)
  if (Mpad > N)
    hipMemsetAsync(A1f16 + (size_t)N*320, 0, (size_t)(Mpad - N)*320*2, stream);

  dim3 gmm(5, (unsigned)Mtiles);

  // layer 1: x1 = highway(x_e, gcn(x_e)) -> xhA (f16 mirror only)
  k_gcn_gather<<<N,256,0,stream>>>(offD, permD, srcA, xhA, dis, A1f16);
  k_dual_mfma<<<gmm,256,0,stream>>>(A1f16, x_e, nullptr, Bf_g1, Bf_h1, hw1_b,
                                    nullptr, 0, xhA, 320, N);

  // layer 2: x2 = highway(x1, gcn(x1)) -> out cols 0:300 + xh2 cols 0:300
  k_gcn_gather<<<N,256,0,stream>>>(offD, permD, srcA, xhA, dis, A1f16);
  k_dual_mfma<<<gmm,256,0,stream>>>(A1f16, nullptr, xhA, Bf_g2, Bf_h2, hw2_b,
                                    out, 2000, xh2, 1024, N);

  // gat_r -> relEmb [2R,100]
  k_dot2_small<<<cdiv(R,256),256,0,stream>>>(relEmb1, RH, RH, gatr_ai, gatr_aj, sR_i, sR_j, R, 0);
  hipMemsetAsync(relEmb, 0, (size_t)2*R*RH*4, stream);
  for (int g = 0; g < 2; g++){
    const int* lg = (g == 0) ? lgOut : lgIn;
    float* part = relEmb + (size_t)g * R * RH;
    hipMemsetAsync(mEncR, 0, (size_t)2*R*4, stream);   // mEncR + sumR contiguous
    k_edge_logit<<<cdiv(ELG,256),256,0,stream>>>(lg, lg + ELG, nullptr, sR_j, sR_i, nullptr,
                                                 eE, mEncR, ELG, 1);
    k_edge_exp<<<cdiv(ELG,256),256,0,stream>>>(lg, eE, mEncR, sumR, ELG);
    k_gatr_scatter<<<ELG,128,0,stream>>>(lg, lg + ELG, eE, sumR, relEmb1, part, RH);
  }
  k_relu_lin<<<cdiv(2*R*RH,256),256,0,stream>>>(relEmb, (long)2*R*RH);

  // wjq: softmax grouped by row0 (=i), feat = [ef[i] | re[rel] | ef[j]]
  k_dot2_small<<<cdiv(2*R,256),256,0,stream>>>(relEmb, RH, RH, ww1 + EH, nullptr, aRel, nullptr, 2*R, 1);
  k_wave_dot2_h<<<cdiv(N,4),256,0,stream>>>(xh2, 1024, EH, ww1, ww1 + EH + RH, sxi, sxj, N, 1);
  hipMemsetAsync(mEncN, 0, (size_t)2*N*4, stream);     // mEncN + sumN contiguous
  k_edge_logit<<<cdiv(E,256),256,0,stream>>>(srcA, dstA, relAll, sxi, sxj, aRel, eE, mEncN, E, 0);
  k_edge_exp<<<cdiv(E,256),256,0,stream>>>(srcA, eE, mEncN, sumN, E);
  k_wjq_gather<<<N,256,0,stream>>>(offS, permS, dstA, relAll, eE, sumN, relEmb, out, xh2);

  // gat over x_wjq (xh2 cols 0:1000), softmax grouped by row1 (=i)
  k_wave_dot2_h<<<cdiv(N,4),256,0,stream>>>(xh2, 1024, 1000, gat_ai, gat_aj, sxi, sxj, N, 0);
  k_dot2_small<<<cdiv(2*R,256),256,0,stream>>>(relEmb, RH, RH, gat_ar, nullptr, srr, nullptr, 2*R, 0);
  hipMemsetAsync(mEncN, 0, (size_t)2*N*4, stream);
  k_edge_logit<<<cdiv(E,256),256,0,stream>>>(dstA, srcA, relAll, sxi, sxj, srr, eE, mEncN, E, 1);
  k_edge_exp<<<cdiv(E,256),256,0,stream>>>(dstA, eE, mEncN, sumN, E);
  k_gat_gather<<<N,256,0,stream>>>(offD, permD, srcA, eE, sumN, xh2, out);
}

// Round 5
// 725.560 us; speedup vs baseline: 2.8828x; 1.1474x over previous
//
#include <hip/hip_runtime.h>
#include <math.h>

#define LSL 0.01f

typedef _Float16 half8 __attribute__((ext_vector_type(8)));
typedef _Float16 half4 __attribute__((ext_vector_type(4)));
typedef _Float16 half2 __attribute__((ext_vector_type(2)));
typedef float floatx4 __attribute__((ext_vector_type(4)));

static __device__ __forceinline__ float lrelu_f(float x){ return x > 0.f ? x : LSL * x; }
static __device__ __forceinline__ void atomAddF(float* p, float v){ unsafeAtomicAdd(p, v); }

// monotone float <-> uint bijection so atomicMax(uint) == float max; 0 encodes < -inf
static __device__ __forceinline__ unsigned encF(float f){
  unsigned u = __float_as_uint(f);
  return (u & 0x80000000u) ? ~u : (u | 0x80000000u);
}
static __device__ __forceinline__ float decF(unsigned u){
  return (u & 0x80000000u) ? __uint_as_float(u & 0x7FFFFFFFu) : __uint_as_float(~u);
}

// ---------------- CSR build ----------------
__global__ void k_count_int(const int* __restrict__ idx, int* __restrict__ deg, int E){
  int e = blockIdx.x * blockDim.x + threadIdx.x;
  if (e < E) atomicAdd(deg + idx[e], 1);
}

// single-block exclusive scan, wave-shuffle based
__global__ void k_scan_excl(const int* __restrict__ cnt, int* __restrict__ off, int n){
  __shared__ int wsum[4];
  __shared__ int carry;
  int t = threadIdx.x, lane = t & 63, wid = t >> 6;
  if (t == 0) carry = 0;
  __syncthreads();
  for (int base = 0; base < n; base += 256){
    int idx = base + t;
    int v = (idx < n) ? cnt[idx] : 0;
    int s = v;
    #pragma unroll
    for (int o = 1; o < 64; o <<= 1){
      int u = __shfl_up(s, o);
      if (lane >= o) s += u;
    }
    if (lane == 63) wsum[wid] = s;
    __syncthreads();
    int wo = 0;
    #pragma unroll
    for (int k = 0; k < 3; k++) wo += (k < wid) ? wsum[k] : 0;
    if (idx < n) off[idx] = carry + wo + s - v;
    int tot = wsum[0] + wsum[1] + wsum[2] + wsum[3];
    __syncthreads();
    if (t == 0) carry += tot;
    __syncthreads();
  }
  if (t == 0) off[n] = carry;
}

__global__ void k_fill_csr(const int* __restrict__ idx, const int* __restrict__ off,
                           int* __restrict__ cursor, int* __restrict__ perm, int E){
  int e = blockIdx.x * blockDim.x + threadIdx.x;
  if (e >= E) return;
  int i = idx[e];
  int p = off[i] + atomicAdd(cursor + i, 1);
  perm[p] = e;
}

__global__ void k_inv_sqrt_int(const int* __restrict__ deg, float* __restrict__ dis, int N){
  int v = blockIdx.x * blockDim.x + threadIdx.x;
  if (v < N){ int d = deg[v]; dis[v] = d > 0 ? rsqrtf((float)d) : 0.f; }
}

// x_e f32 [N][300] -> xhA f16 [Mpad][320] zero-padded (cols 300:320, rows N:Mpad)
__global__ __launch_bounds__(256)
void k_conv_f16(const float* __restrict__ x, _Float16* __restrict__ xh, int N){
  int i = blockIdx.x, t = threadIdx.x;
  _Float16* o = xh + (size_t)i * 320;
  if (i < N){
    const float* r = x + (size_t)i * 300;
    o[t] = (_Float16)r[t];
    if (t < 44) o[t + 256] = (_Float16)r[t + 256];
    else if (t < 64) o[t + 256] = (_Float16)0.f;
  } else {
    o[t] = (_Float16)0.f;
    if (t < 64) o[t + 256] = (_Float16)0.f;
  }
}

// ---------------- CSR gathers (no atomics, f16 sources) ----------------
// agg_f16[i][0:320] = relu(sum_e dis[i]*dis[j] * xh[j]) zero-padded, F=300
__global__ __launch_bounds__(256)
void k_gcn_gather(const int* __restrict__ off, const int* __restrict__ perm,
                  const int* __restrict__ src, const _Float16* __restrict__ x,
                  const float* __restrict__ dis, _Float16* __restrict__ agg){
  int i = blockIdx.x, t = threadIdx.x;
  int p0 = off[i], p1 = off[i+1];
  float di = dis[i];
  __shared__ int sjv[64]; __shared__ float sw[64];
  float a0 = 0.f, a1 = 0.f;
  for (int pb = p0; pb < p1; pb += 64){
    int m = min(64, p1 - pb);
    if (t < m){ int e = perm[pb + t]; int j = src[e]; sjv[t] = j; sw[t] = di * dis[j]; }
    __syncthreads();
    for (int q = 0; q < m; q++){
      const _Float16* xj = x + (size_t)sjv[q] * 320;
      a0 += sw[q] * (float)xj[t];
      if (t < 44) a1 += sw[q] * (float)xj[t + 256];
    }
    __syncthreads();
  }
  _Float16* o = agg + (size_t)i * 320;
  o[t] = (_Float16)fmaxf(a0, 0.f);
  if (t < 44) o[t + 256] = (_Float16)fmaxf(a1, 0.f);
  else if (t < 64) o[t + 256] = (_Float16)0.f;
}

// ---------------- MFMA dual-GEMM + highway ----------------
// pack W [K x Nn] f32 into fragment-ready f16: Bf[((ks*5+nt)*4+nf)*64+lane][8]
__global__ void k_prep_B(const float* __restrict__ W, _Float16* __restrict__ Bf,
                         int K, int Nn){
  int idx = blockIdx.x * 256 + threadIdx.x;
  if (idx >= 10*5*4*64) return;
  int lane = idx & 63;
  int rem = idx >> 6;
  int nf = rem & 3; rem >>= 2;
  int nt = rem % 5;
  int ks = rem / 5;
  int n = nt*64 + nf*16 + (lane & 15);
  int kb = ks*32 + (lane >> 4) * 8;
  _Float16* o = Bf + (size_t)idx * 8;
  #pragma unroll
  for (int e = 0; e < 8; e++){
    int k = kb + e;
    float v = (k < K && n < Nn) ? W[(size_t)k * Nn + n] : 0.f;
    o[e] = (_Float16)v;
  }
}

// O = sig(X@Wh + b) * (A1@Wg) + (1-sig)*X ; A1 = relu(agg) f16 [Mpad][320]
// 1-D grid of 5*Mtiles blocks; bijective XCD swizzle so the 5 column-tile
// blocks sharing an A-panel are co-resident on one XCD (L2 panel reuse).
__global__ __launch_bounds__(256)
void k_dual_mfma(const _Float16* __restrict__ A1, const float* __restrict__ Xf32,
                 const _Float16* __restrict__ Xh,
                 const _Float16* __restrict__ Bf1, const _Float16* __restrict__ Bf2,
                 const float* __restrict__ bias, float* __restrict__ Of32, long ldo,
                 _Float16* __restrict__ Oh, long ldm, int M){
  int nb = gridDim.x;
  int q = nb >> 3, r = nb & 7;
  int xcd = blockIdx.x & 7, kk0 = blockIdx.x >> 3;
  int pseudo = (xcd < r ? xcd * (q + 1) : r * (q + 1) + (xcd - r) * q) + kk0;
  int nt = pseudo % 5;
  int panel = pseudo / 5;

  int tid = threadIdx.x;
  int w = tid >> 6, lane = tid & 63;
  int l15 = lane & 15, lg = lane >> 4;
  int rowBase = panel * 128 + w * 32;
  int colBase = nt * 64;

  floatx4 acc1[2][4], acc2[2][4];
  #pragma unroll
  for (int a = 0; a < 2; a++)
    #pragma unroll
    for (int b = 0; b < 4; b++){
      acc1[a][b] = (floatx4){0.f,0.f,0.f,0.f};
      acc2[a][b] = (floatx4){0.f,0.f,0.f,0.f};
    }

  int row0 = rowBase + l15, row1 = rowBase + 16 + l15;
  int rX0 = min(row0, M-1), rX1 = min(row1, M-1);
  const _Float16* a1p0 = A1 + (size_t)row0 * 320;
  const _Float16* a1p1 = A1 + (size_t)row1 * 320;

  for (int ks = 0; ks < 10; ks++){
    int kA = ks*32 + lg*8;
    half8 a1f0 = *(const half8*)(a1p0 + kA);
    half8 a1f1 = *(const half8*)(a1p1 + kA);
    half8 a2f0, a2f1;
    if (Xh){
      a2f0 = *(const half8*)(Xh + (size_t)row0 * 320 + kA);
      a2f1 = *(const half8*)(Xh + (size_t)row1 * 320 + kA);
    } else {
      const float* xp0 = Xf32 + (size_t)rX0 * 300;
      const float* xp1 = Xf32 + (size_t)rX1 * 300;
      int lo = min(kA, 296), hi = min(kA + 4, 292);
      floatx4 x0l = *(const floatx4*)(xp0 + lo);
      floatx4 x0h = *(const floatx4*)(xp0 + hi);
      floatx4 x1l = *(const floatx4*)(xp1 + lo);
      floatx4 x1h = *(const floatx4*)(xp1 + hi);
      #pragma unroll
      for (int e = 0; e < 4; e++){
        a2f0[e] = (_Float16)x0l[e]; a2f0[e+4] = (_Float16)x0h[e];
        a2f1[e] = (_Float16)x1l[e]; a2f1[e+4] = (_Float16)x1h[e];
      }
    }
    const half8* b1p = (const half8*)Bf1 + ((size_t)(ks*5 + nt) * 4 * 64 + lane);
    const half8* b2p = (const half8*)Bf2 + ((size_t)(ks*5 + nt) * 4 * 64 + lane);
    #pragma unroll
    for (int nf = 0; nf < 4; nf++){
      half8 b1 = b1p[nf*64];
      half8 b2 = b2p[nf*64];
      acc1[0][nf] = __builtin_amdgcn_mfma_f32_16x16x32_f16(a1f0, b1, acc1[0][nf], 0,0,0);
      acc1[1][nf] = __builtin_amdgcn_mfma_f32_16x16x32_f16(a1f1, b1, acc1[1][nf], 0,0,0);
      acc2[0][nf] = __builtin_amdgcn_mfma_f32_16x16x32_f16(a2f0, b2, acc2[0][nf], 0,0,0);
      acc2[1][nf] = __builtin_amdgcn_mfma_f32_16x16x32_f16(a2f1, b2, acc2[1][nf], 0,0,0);
    }
  }

  #pragma unroll
  for (int mf = 0; mf < 2; mf++){
    #pragma unroll
    for (int nf = 0; nf < 4; nf++){
      int gn = colBase + nf*16 + l15;
      int gnc = min(gn, 299);
      float bv = bias[gnc];
      #pragma unroll
      for (int r2 = 0; r2 < 4; r2++){
        int gm = rowBase + mf*16 + lg*4 + r2;
        int gmc = min(gm, M-1);
        float xv = Xh ? (float)Xh[(size_t)gmc * 320 + gnc]
                      : Xf32[(size_t)gmc * 300 + gnc];
        float g = 1.f / (1.f + expf(-(acc2[mf][nf][r2] + bv)));
        float val = g * acc1[mf][nf][r2] + (1.f - g) * xv;
        if (gm < M && gn < 300){
          if (Of32) Of32[(size_t)gm * ldo + gn] = val;
          if (Oh)   Oh[(size_t)gm * ldm + gn] = (_Float16)val;
        }
      }
    }
  }
}

// wjq (grouped by i=row0): out[i,600:700] = sum a*lrelu(re[r]); out[i,700:1000] = sum a*lrelu(x2[j]);
// out[i,300:600] = lrelu(x2[i]) * sum(a). Also mirrors cols 300:1000 into xh2 f16.
__global__ __launch_bounds__(256)
void k_wjq_gather(const int* __restrict__ off, const int* __restrict__ perm,
                  const int* __restrict__ row1, const int* __restrict__ relI,
                  const float* __restrict__ ex, const float* __restrict__ sums,
                  const float* __restrict__ relEmb, float* __restrict__ out,
                  _Float16* __restrict__ xh2){
  int i = blockIdx.x, t = threadIdx.x;
  int p0 = off[i], p1 = off[i+1];
  float inv = 1.f / (sums[i] + 1e-16f);
  __shared__ int sjv[64], srv[64]; __shared__ float sal[64];
  float a0 = 0.f, a1 = 0.f, sa = 0.f;
  for (int pb = p0; pb < p1; pb += 64){
    int m = min(64, p1 - pb);
    if (t < m){ int e = perm[pb + t]; sjv[t] = row1[e]; srv[t] = relI[e]; sal[t] = ex[e] * inv; }
    __syncthreads();
    for (int q = 0; q < m; q++){
      float al = sal[q]; sa += al;
      const float* rr = relEmb + (size_t)srv[q] * 100;
      const _Float16* xj = xh2 + (size_t)sjv[q] * 1024;   // x2 f16 in cols 0:300
      float v0 = (t < 100) ? rr[t] : (float)xj[t - 100];
      a0 += al * lrelu_f(v0);
      if (t < 144) a1 += al * lrelu_f((float)xj[t + 156]);
    }
    __syncthreads();
  }
  float* oi = out + (size_t)i * 2000;
  _Float16* hi = xh2 + (size_t)i * 1024;
  int c0 = (t < 100) ? (600 + t) : (700 + (t - 100));
  oi[c0] = a0; hi[c0] = (_Float16)a0;
  if (t < 144){ oi[856 + t] = a1; hi[856 + t] = (_Float16)a1; }
  float h0 = lrelu_f(oi[t]) * sa;
  oi[300 + t] = h0; hi[300 + t] = (_Float16)h0;
  if (t < 44){
    float h1 = lrelu_f(oi[256 + t]) * sa;
    oi[556 + t] = h1; hi[556 + t] = (_Float16)h1;
  }
}

// gat (grouped by i=row1): out[i,1000:2000] = relu(sum a * xh2[j,0:1000])
__global__ __launch_bounds__(256)
void k_gat_gather(const int* __restrict__ off, const int* __restrict__ perm,
                  const int* __restrict__ src, const float* __restrict__ ex,
                  const float* __restrict__ sums, const _Float16* __restrict__ xh2,
                  float* __restrict__ out){
  int i = blockIdx.x, t = threadIdx.x;
  int p0 = off[i], p1 = off[i+1];
  float inv = 1.f / (sums[i] + 1e-16f);
  __shared__ int sjv[64]; __shared__ float sal[64];
  float acc[4] = {0.f, 0.f, 0.f, 0.f};
  for (int pb = p0; pb < p1; pb += 64){
    int m = min(64, p1 - pb);
    if (t < m){ int e = perm[pb + t]; sjv[t] = src[e]; sal[t] = ex[e] * inv; }
    __syncthreads();
    for (int q = 0; q < m; q++){
      float al = sal[q];
      if (t < 250){
        half4 v = *(const half4*)(xh2 + (size_t)sjv[q] * 1024 + 4*t);
        #pragma unroll
        for (int k = 0; k < 4; k++) acc[k] += al * (float)v[k];
      }
    }
    __syncthreads();
  }
  if (t < 250){
    floatx4 o;
    #pragma unroll
    for (int k = 0; k < 4; k++) o[k] = fmaxf(acc[k], 0.f);
    *(floatx4*)(out + (size_t)i * 2000 + 1000 + 4*t) = o;
  }
}

// ---------------- small kernels ----------------
__global__ void k_dot2_small(const float* __restrict__ X, int ld, int len,
                             const float* __restrict__ wA, const float* __restrict__ wB,
                             float* __restrict__ oA, float* __restrict__ oB,
                             int n, int applyL){
  int v = blockIdx.x * blockDim.x + threadIdx.x;
  if (v >= n) return;
  const float* row = X + (size_t)v * ld;
  float a = 0.f, b = 0.f;
  for (int c = 0; c < len; c++){
    float f = row[c];
    if (applyL) f = lrelu_f(f);
    a += f * wA[c];
    if (wB) b += f * wB[c];
  }
  oA[v] = a;
  if (oB) oB[v] = b;
}

// wave-per-row dual dot over f16 rows
__global__ void k_wave_dot2_h(const _Float16* __restrict__ X, long ld, int len,
                              const float* __restrict__ wA, const float* __restrict__ wB,
                              float* __restrict__ oA, float* __restrict__ oB,
                              int n, int applyL){
  int gw = (int)(((long)blockIdx.x * blockDim.x + threadIdx.x) >> 6);
  int lane = threadIdx.x & 63;
  if (gw >= n) return;
  const _Float16* row = X + (size_t)gw * ld;
  float a = 0.f, b = 0.f;
  for (int c = lane*2; c < len; c += 128){
    half2 v = *(const half2*)(row + c);
    float f0 = (float)v[0], f1 = (float)v[1];
    if (applyL){ f0 = lrelu_f(f0); f1 = lrelu_f(f1); }
    a += f0 * wA[c] + f1 * wA[c+1];
    b += f0 * wB[c] + f1 * wB[c+1];
  }
  #pragma unroll
  for (int o = 32; o > 0; o >>= 1){
    a += __shfl_down(a, o);
    b += __shfl_down(b, o);
  }
  if (lane == 0){ oA[gw] = a; oB[gw] = b; }
}

__global__ void k_edge_logit(const int* __restrict__ segI, const int* __restrict__ othI,
                             const int* __restrict__ relI,
                             const float* __restrict__ sSeg, const float* __restrict__ sOth,
                             const float* __restrict__ sRel,
                             float* __restrict__ elog, unsigned* __restrict__ mEnc,
                             int E, int applyL){
  int e = blockIdx.x * blockDim.x + threadIdx.x;
  if (e >= E) return;
  int s = segI[e];
  float v = sSeg[s] + sOth[othI[e]];
  if (relI) v += sRel[relI[e]];
  if (applyL) v = lrelu_f(v);
  elog[e] = v;
  atomicMax(mEnc + s, encF(v));
}

__global__ void k_edge_exp(const int* __restrict__ segI, float* __restrict__ elog,
                           const unsigned* __restrict__ mEnc, float* __restrict__ segSum, int E){
  int e = blockIdx.x * blockDim.x + threadIdx.x;
  if (e >= E) return;
  int s = segI[e];
  float ex = expf(elog[e] - decF(mEnc[s]));
  elog[e] = ex;
  atomAddF(segSum + s, ex);
}

__global__ void k_gatr_scatter(const int* __restrict__ src, const int* __restrict__ dst,
                               const float* __restrict__ ex, const float* __restrict__ segSum,
                               const float* __restrict__ xin, float* __restrict__ oagg, int F){
  int e = blockIdx.x;
  int j = src[e], i = dst[e];
  float alpha = ex[e] / (segSum[j] + 1e-16f);
  const float* xj = xin + (size_t)j * F;
  float* oi = oagg + (size_t)i * F;
  for (int c = threadIdx.x; c < F; c += blockDim.x)
    atomAddF(oi + c, alpha * xj[c]);
}

__global__ void k_relu_lin(float* __restrict__ p, long n){
  long t = (long)blockIdx.x * blockDim.x + threadIdx.x;
  if (t < n) p[t] = fmaxf(p[t], 0.f);
}

extern "C" void kernel_launch(void* const* d_in, const int* in_sizes, int n_in,
                              void* d_out, int out_size, void* d_ws, size_t ws_size,
                              hipStream_t stream){
  const float* x_e     = (const float*)d_in[0];
  const int*   eiA     = (const int*)  d_in[3];   // edge_index_all [2,E]
  const int*   relAll  = (const int*)  d_in[4];
  const int*   lgOut   = (const int*)  d_in[5];
  const int*   lgIn    = (const int*)  d_in[7];
  const float* gcn1_w  = (const float*)d_in[9];
  const float* gcn2_w  = (const float*)d_in[10];
  const float* hw1_w   = (const float*)d_in[11];
  const float* hw1_b   = (const float*)d_in[12];
  const float* hw2_w   = (const float*)d_in[13];
  const float* hw2_b   = (const float*)d_in[14];
  const float* ww1     = (const float*)d_in[15];
  const float* gat_ai  = (const float*)d_in[16];
  const float* gat_aj  = (const float*)d_in[17];
  const float* gat_ar  = (const float*)d_in[18];
  const float* gatr_ai = (const float*)d_in[19];
  const float* gatr_aj = (const float*)d_in[20];
  const float* relEmb1 = (const float*)d_in[21];

  const int EH = 300, RH = 100;
  const int N   = in_sizes[0] / EH;
  const int E   = in_sizes[3] / 2;
  const int ELG = in_sizes[5] / 2;
  const int R   = in_sizes[21] / RH;
  const int Mtiles = (N + 127) / 128;
  const int Mpad = Mtiles * 128;

  // ---- workspace layout (16B-aligned f16 blocks first) ----
  char* base = (char*)d_ws;
  _Float16* xhA   = (_Float16*)base;  base += (size_t)Mpad * 320 * 2;   // x_e f16 -> x1 f16
  _Float16* A1f16 = (_Float16*)base;  base += (size_t)Mpad * 320 * 2;   // relu(agg) f16
  _Float16* xh2   = (_Float16*)base;  base += (size_t)N * 1024 * 2;     // x_wjq f16 mirror
  _Float16* BfAll = (_Float16*)base;  base += (size_t)4 * 102400 * 2;
  float* w = (float*)base;
  float* dis    = w; w += N;
  float* relEmb = w; w += (size_t)2 * R * RH;
  float* sxi    = w; w += N;
  float* sxj    = w; w += N;
  unsigned* mEncN = (unsigned*)w; w += N;
  float* sumN   = w; w += N;
  float* sR_i   = w; w += R;
  float* sR_j   = w; w += R;
  unsigned* mEncR = (unsigned*)w; w += R;
  float* sumR   = w; w += R;
  float* aRel   = w; w += 2 * R;
  float* srr    = w; w += 2 * R;
  float* eE     = w; w += E;
  int* degI   = (int*)w; w += N;
  int* cursor = (int*)w; w += N;
  int* offD   = (int*)w; w += N + 1;
  int* offS   = (int*)w; w += N + 1;
  int* permD  = (int*)w; w += E;
  int* permS  = (int*)w; w += E;

  _Float16* Bf_g1 = BfAll;
  _Float16* Bf_h1 = BfAll + 102400;
  _Float16* Bf_g2 = BfAll + 2 * 102400;
  _Float16* Bf_h2 = BfAll + 3 * 102400;

  float* out = (float*)d_out;
  const int* srcA = eiA;         // row0 (j in gcn/gat, i in wjq)
  const int* dstA = eiA + E;     // row1

  auto cdiv = [](int a, int b){ return (a + b - 1) / b; };

  // ---- CSR by dst (gcn agg + gat agg) ; dis = in-degree^-0.5 ----
  hipMemsetAsync(degI, 0, (size_t)N * 4, stream);
  hipMemsetAsync(cursor, 0, (size_t)N * 4, stream);
  k_count_int<<<cdiv(E,256),256,0,stream>>>(dstA, degI, E);
  k_scan_excl<<<1,256,0,stream>>>(degI, offD, N);
  k_fill_csr<<<cdiv(E,256),256,0,stream>>>(dstA, offD, cursor, permD, E);
  k_inv_sqrt_int<<<cdiv(N,256),256,0,stream>>>(degI, dis, N);

  // ---- CSR by src (wjq grouping) ----
  hipMemsetAsync(degI, 0, (size_t)N * 4, stream);
  hipMemsetAsync(cursor, 0, (size_t)N * 4, stream);
  k_count_int<<<cdiv(E,256),256,0,stream>>>(srcA, degI, E);
  k_scan_excl<<<1,256,0,stream>>>(degI, offS, N);
  k_fill_csr<<<cdiv(E,256),256,0,stream>>>(srcA, offS, cursor, permS, E);

  // ---- pack weights into MFMA fragment layout; convert x_e to f16 ----
  k_prep_B<<<50,256,0,stream>>>(gcn1_w, Bf_g1, EH, EH);
  k_prep_B<<<50,256,0,stream>>>(hw1_w,  Bf_h1, EH, EH);
  k_prep_B<<<50,256,0,stream>>>(gcn2_w, Bf_g2, EH, EH);
  k_prep_B<<<50,256,0,stream>>>(hw2_w,  Bf_h2, EH, EH);
  k_conv_f16<<<Mpad,256,0,stream>>>(x_e, xhA, N);
  // zero A1f16 pad rows once per call (gathers rewrite rows < N)
  if (Mpad > N)
    hipMemsetAsync(A1f16 + (size_t)N*320, 0, (size_t)(Mpad - N)*320*2, stream);

  int NB = 5 * Mtiles;

  // layer 1: x1 = highway(x_e, gcn(x_e)) -> xhA (f16 mirror only)
  k_gcn_gather<<<N,256,0,stream>>>(offD, permD, srcA, xhA, dis, A1f16);
  k_dual_mfma<<<NB,256,0,stream>>>(A1f16, x_e, nullptr, Bf_g1, Bf_h1, hw1_b,
                                   nullptr, 0, xhA, 320, N);

  // layer 2: x2 = highway(x1, gcn(x1)) -> out cols 0:300 + xh2 cols 0:300
  k_gcn_gather<<<N,256,0,stream>>>(offD, permD, srcA, xhA, dis, A1f16);
  k_dual_mfma<<<NB,256,0,stream>>>(A1f16, nullptr, xhA, Bf_g2, Bf_h2, hw2_b,
                                   out, 2000, xh2, 1024, N);

  // gat_r -> relEmb [2R,100]
  k_dot2_small<<<cdiv(R,256),256,0,stream>>>(relEmb1, RH, RH, gatr_ai, gatr_aj, sR_i, sR_j, R, 0);
  hipMemsetAsync(relEmb, 0, (size_t)2*R*RH*4, stream);
  for (int g = 0; g < 2; g++){
    const int* lg = (g == 0) ? lgOut : lgIn;
    float* part = relEmb + (size_t)g * R * RH;
    hipMemsetAsync(mEncR, 0, (size_t)2*R*4, stream);   // mEncR + sumR contiguous
    k_edge_logit<<<cdiv(ELG,256),256,0,stream>>>(lg, lg + ELG, nullptr, sR_j, sR_i, nullptr,
                                                 eE, mEncR, ELG, 1);
    k_edge_exp<<<cdiv(ELG,256),256,0,stream>>>(lg, eE, mEncR, sumR, ELG);
    k_gatr_scatter<<<ELG,128,0,stream>>>(lg, lg + ELG, eE, sumR, relEmb1, part, RH);
  }
  k_relu_lin<<<cdiv(2*R*RH,256),256,0,stream>>>(relEmb, (long)2*R*RH);

  // wjq: softmax grouped by row0 (=i), feat = [ef[i] | re[rel] | ef[j]]
  k_dot2_small<<<cdiv(2*R,256),256,0,stream>>>(relEmb, RH, RH, ww1 + EH, nullptr, aRel, nullptr, 2*R, 1);
  k_wave_dot2_h<<<cdiv(N,4),256,0,stream>>>(xh2, 1024, EH, ww1, ww1 + EH + RH, sxi, sxj, N, 1);
  hipMemsetAsync(mEncN, 0, (size_t)2*N*4, stream);     // mEncN + sumN contiguous
  k_edge_logit<<<cdiv(E,256),256,0,stream>>>(srcA, dstA, relAll, sxi, sxj, aRel, eE, mEncN, E, 0);
  k_edge_exp<<<cdiv(E,256),256,0,stream>>>(srcA, eE, mEncN, sumN, E);
  k_wjq_gather<<<N,256,0,stream>>>(offS, permS, dstA, relAll, eE, sumN, relEmb, out, xh2);

  // gat over x_wjq (xh2 cols 0:1000), softmax grouped by row1 (=i)
  k_wave_dot2_h<<<cdiv(N,4),256,0,stream>>>(xh2, 1024, 1000, gat_ai, gat_aj, sxi, sxj, N, 0);
  k_dot2_small<<<cdiv(2*R,256),256,0,stream>>>(relEmb, RH, RH, gat_ar, nullptr, srr, nullptr, 2*R, 0);
  hipMemsetAsync(mEncN, 0, (size_t)2*N*4, stream);
  k_edge_logit<<<cdiv(E,256),256,0,stream>>>(dstA, srcA, relAll, sxi, sxj, srr, eE, mEncN, E, 1);
  k_edge_exp<<<cdiv(E,256),256,0,stream>>>(dstA, eE, mEncN, sumN, E);
  k_gat_gather<<<N,256,0,stream>>>(offD, permD, srcA, eE, sumN, xh2, out);
}

// Round 6
// 622.395 us; speedup vs baseline: 3.3606x; 1.1658x over previous
//
#include <hip/hip_runtime.h>
#include <math.h>

#define LSL 0.01f

typedef _Float16 half8 __attribute__((ext_vector_type(8)));
typedef _Float16 half4 __attribute__((ext_vector_type(4)));
typedef _Float16 half2 __attribute__((ext_vector_type(2)));
typedef float floatx4 __attribute__((ext_vector_type(4)));

static __device__ __forceinline__ float lrelu_f(float x){ return x > 0.f ? x : LSL * x; }
static __device__ __forceinline__ void atomAddF(float* p, float v){ unsafeAtomicAdd(p, v); }

// monotone float <-> uint bijection so atomicMax(uint) == float max; 0 encodes < -inf
static __device__ __forceinline__ unsigned encF(float f){
  unsigned u = __float_as_uint(f);
  return (u & 0x80000000u) ? ~u : (u | 0x80000000u);
}
static __device__ __forceinline__ float decF(unsigned u){
  return (u & 0x80000000u) ? __uint_as_float(u & 0x7FFFFFFFu) : __uint_as_float(~u);
}

// ---------------- CSR build (fused) ----------------
__global__ void k_count2(const int* __restrict__ dstA, const int* __restrict__ srcA,
                         int* __restrict__ degD, int* __restrict__ degS, int E){
  int e = blockIdx.x * blockDim.x + threadIdx.x;
  if (e < E){ atomicAdd(degD + dstA[e], 1); atomicAdd(degS + srcA[e], 1); }
}

// two single-block exclusive scans in parallel (block 0 -> D, block 1 -> S)
__global__ void k_scan2(const int* __restrict__ cntD, int* __restrict__ offD,
                        const int* __restrict__ cntS, int* __restrict__ offS, int n){
  const int* cnt = blockIdx.x ? cntS : cntD;
  int* off = blockIdx.x ? offS : offD;
  __shared__ int wsum[4];
  __shared__ int carry;
  int t = threadIdx.x, lane = t & 63, wid = t >> 6;
  if (t == 0) carry = 0;
  __syncthreads();
  for (int base = 0; base < n; base += 256){
    int idx = base + t;
    int v = (idx < n) ? cnt[idx] : 0;
    int s = v;
    #pragma unroll
    for (int o = 1; o < 64; o <<= 1){
      int u = __shfl_up(s, o);
      if (lane >= o) s += u;
    }
    if (lane == 63) wsum[wid] = s;
    __syncthreads();
    int wo = 0;
    #pragma unroll
    for (int k = 0; k < 3; k++) wo += (k < wid) ? wsum[k] : 0;
    if (idx < n) off[idx] = carry + wo + s - v;
    int tot = wsum[0] + wsum[1] + wsum[2] + wsum[3];
    __syncthreads();
    if (t == 0) carry += tot;
    __syncthreads();
  }
  if (t == 0) off[n] = carry;
}

__global__ void k_fill2(const int* __restrict__ dstA, const int* __restrict__ srcA,
                        const int* __restrict__ offD, const int* __restrict__ offS,
                        int* __restrict__ curD, int* __restrict__ curS,
                        int* __restrict__ permD, int* __restrict__ permS, int E){
  int e = blockIdx.x * blockDim.x + threadIdx.x;
  if (e >= E) return;
  int i = dstA[e];
  permD[offD[i] + atomicAdd(curD + i, 1)] = e;
  int j = srcA[e];
  permS[offS[j] + atomicAdd(curS + j, 1)] = e;
}

__global__ void k_inv_sqrt_int(const int* __restrict__ deg, float* __restrict__ dis, int N){
  int v = blockIdx.x * blockDim.x + threadIdx.x;
  if (v < N){ int d = deg[v]; dis[v] = d > 0 ? rsqrtf((float)d) : 0.f; }
}

// x_e f32 [N][300] -> xhA f16 [Mpad][320] zero-padded (cols 300:320, rows N:Mpad)
__global__ __launch_bounds__(256)
void k_conv_f16(const float* __restrict__ x, _Float16* __restrict__ xh, int N){
  int i = blockIdx.x, t = threadIdx.x;
  _Float16* o = xh + (size_t)i * 320;
  if (i < N){
    const float* r = x + (size_t)i * 300;
    o[t] = (_Float16)r[t];
    if (t < 44) o[t + 256] = (_Float16)r[t + 256];
    else if (t < 64) o[t + 256] = (_Float16)0.f;
  } else {
    o[t] = (_Float16)0.f;
    if (t < 64) o[t + 256] = (_Float16)0.f;
  }
}

// ---------------- CSR gathers: wave-per-edge, vectorized ----------------
// agg_f16[i][0:320] = relu(sum_e dis[i]*dis[j] * xh[j]); 4 waves, wave=edge, lane<40 x half8
__global__ __launch_bounds__(256)
void k_gcn_gather(const int* __restrict__ off, const int* __restrict__ perm,
                  const int* __restrict__ src, const _Float16* __restrict__ x,
                  const float* __restrict__ dis, _Float16* __restrict__ agg){
  int i = blockIdx.x, t = threadIdx.x, w = t >> 6, lane = t & 63;
  int p0 = off[i], p1 = off[i+1];
  float di = dis[i];
  float acc[8] = {0.f,0.f,0.f,0.f,0.f,0.f,0.f,0.f};
  for (int p = p0 + w; p < p1; p += 4){
    int e = perm[p];
    int j = src[e];
    float wt = di * dis[j];
    if (lane < 40){
      half8 v = *(const half8*)(x + (size_t)j * 320 + 8*lane);
      #pragma unroll
      for (int k = 0; k < 8; k++) acc[k] += wt * (float)v[k];
    }
  }
  __shared__ float red[4][320];
  if (lane < 40){
    #pragma unroll
    for (int k = 0; k < 8; k++) red[w][8*lane + k] = acc[k];
  }
  __syncthreads();
  _Float16* o = agg + (size_t)i * 320;
  float s = red[0][t] + red[1][t] + red[2][t] + red[3][t];
  o[t] = (_Float16)fmaxf(s, 0.f);
  if (t < 64){
    int c = t + 256;
    float s2 = red[0][c] + red[1][c] + red[2][c] + red[3][c];
    o[c] = (_Float16)fmaxf(s2, 0.f);
  }
}

// ---------------- MFMA dual-GEMM + highway ----------------
// pack W [K x Nn] f32 into fragment-ready f16: Bf[((ks*5+nt)*4+nf)*64+lane][8]
__global__ void k_prep_B(const float* __restrict__ W, _Float16* __restrict__ Bf,
                         int K, int Nn){
  int idx = blockIdx.x * 256 + threadIdx.x;
  if (idx >= 10*5*4*64) return;
  int lane = idx & 63;
  int rem = idx >> 6;
  int nf = rem & 3; rem >>= 2;
  int nt = rem % 5;
  int ks = rem / 5;
  int n = nt*64 + nf*16 + (lane & 15);
  int kb = ks*32 + (lane >> 4) * 8;
  _Float16* o = Bf + (size_t)idx * 8;
  #pragma unroll
  for (int e = 0; e < 8; e++){
    int k = kb + e;
    float v = (k < K && n < Nn) ? W[(size_t)k * Nn + n] : 0.f;
    o[e] = (_Float16)v;
  }
}

// O = sig(X@Wh + b) * (A1@Wg) + (1-sig)*X ; A1 = relu(agg) f16 [Mpad][320]
// 1-D grid, bijective XCD swizzle: 5 column-tile blocks of one A-panel co-resident per XCD.
__global__ __launch_bounds__(256)
void k_dual_mfma(const _Float16* __restrict__ A1, const float* __restrict__ Xf32,
                 const _Float16* __restrict__ Xh,
                 const _Float16* __restrict__ Bf1, const _Float16* __restrict__ Bf2,
                 const float* __restrict__ bias, float* __restrict__ Of32, long ldo,
                 _Float16* __restrict__ Oh, long ldm, int M){
  int nb = gridDim.x;
  int q = nb >> 3, r = nb & 7;
  int xcd = blockIdx.x & 7, kk0 = blockIdx.x >> 3;
  int pseudo = (xcd < r ? xcd * (q + 1) : r * (q + 1) + (xcd - r) * q) + kk0;
  int nt = pseudo % 5;
  int panel = pseudo / 5;

  int tid = threadIdx.x;
  int w = tid >> 6, lane = tid & 63;
  int l15 = lane & 15, lg = lane >> 4;
  int rowBase = panel * 128 + w * 32;
  int colBase = nt * 64;

  floatx4 acc1[2][4], acc2[2][4];
  #pragma unroll
  for (int a = 0; a < 2; a++)
    #pragma unroll
    for (int b = 0; b < 4; b++){
      acc1[a][b] = (floatx4){0.f,0.f,0.f,0.f};
      acc2[a][b] = (floatx4){0.f,0.f,0.f,0.f};
    }

  int row0 = rowBase + l15, row1 = rowBase + 16 + l15;
  int rX0 = min(row0, M-1), rX1 = min(row1, M-1);
  const _Float16* a1p0 = A1 + (size_t)row0 * 320;
  const _Float16* a1p1 = A1 + (size_t)row1 * 320;

  for (int ks = 0; ks < 10; ks++){
    int kA = ks*32 + lg*8;
    half8 a1f0 = *(const half8*)(a1p0 + kA);
    half8 a1f1 = *(const half8*)(a1p1 + kA);
    half8 a2f0, a2f1;
    if (Xh){
      a2f0 = *(const half8*)(Xh + (size_t)row0 * 320 + kA);
      a2f1 = *(const half8*)(Xh + (size_t)row1 * 320 + kA);
    } else {
      const float* xp0 = Xf32 + (size_t)rX0 * 300;
      const float* xp1 = Xf32 + (size_t)rX1 * 300;
      int lo = min(kA, 296), hi = min(kA + 4, 292);
      floatx4 x0l = *(const floatx4*)(xp0 + lo);
      floatx4 x0h = *(const floatx4*)(xp0 + hi);
      floatx4 x1l = *(const floatx4*)(xp1 + lo);
      floatx4 x1h = *(const floatx4*)(xp1 + hi);
      #pragma unroll
      for (int e = 0; e < 4; e++){
        a2f0[e] = (_Float16)x0l[e]; a2f0[e+4] = (_Float16)x0h[e];
        a2f1[e] = (_Float16)x1l[e]; a2f1[e+4] = (_Float16)x1h[e];
      }
    }
    const half8* b1p = (const half8*)Bf1 + ((size_t)(ks*5 + nt) * 4 * 64 + lane);
    const half8* b2p = (const half8*)Bf2 + ((size_t)(ks*5 + nt) * 4 * 64 + lane);
    #pragma unroll
    for (int nf = 0; nf < 4; nf++){
      half8 b1 = b1p[nf*64];
      half8 b2 = b2p[nf*64];
      acc1[0][nf] = __builtin_amdgcn_mfma_f32_16x16x32_f16(a1f0, b1, acc1[0][nf], 0,0,0);
      acc1[1][nf] = __builtin_amdgcn_mfma_f32_16x16x32_f16(a1f1, b1, acc1[1][nf], 0,0,0);
      acc2[0][nf] = __builtin_amdgcn_mfma_f32_16x16x32_f16(a2f0, b2, acc2[0][nf], 0,0,0);
      acc2[1][nf] = __builtin_amdgcn_mfma_f32_16x16x32_f16(a2f1, b2, acc2[1][nf], 0,0,0);
    }
  }

  #pragma unroll
  for (int mf = 0; mf < 2; mf++){
    #pragma unroll
    for (int nf = 0; nf < 4; nf++){
      int gn = colBase + nf*16 + l15;
      int gnc = min(gn, 299);
      float bv = bias[gnc];
      #pragma unroll
      for (int r2 = 0; r2 < 4; r2++){
        int gm = rowBase + mf*16 + lg*4 + r2;
        int gmc = min(gm, M-1);
        float xv = Xh ? (float)Xh[(size_t)gmc * 320 + gnc]
                      : Xf32[(size_t)gmc * 300 + gnc];
        float g = 1.f / (1.f + expf(-(acc2[mf][nf][r2] + bv)));
        float val = g * acc1[mf][nf][r2] + (1.f - g) * xv;
        if (gm < M && gn < 300){
          if (Of32) Of32[(size_t)gm * ldo + gn] = val;
          if (Oh)   Oh[(size_t)gm * ldm + gn] = (_Float16)val;
        }
      }
    }
  }
}

// wjq (grouped by i=row0): 4 waves, wave=edge; lane<38 x half8 (x2 row), lane 38..62 float4 (relEmb)
__global__ __launch_bounds__(256)
void k_wjq_gather(const int* __restrict__ off, const int* __restrict__ perm,
                  const int* __restrict__ row1, const int* __restrict__ relI,
                  const float* __restrict__ ex, const float* __restrict__ sums,
                  const float* __restrict__ relEmb, float* __restrict__ out,
                  _Float16* __restrict__ xh2){
  int i = blockIdx.x, t = threadIdx.x, w = t >> 6, lane = t & 63;
  int p0 = off[i], p1 = off[i+1];
  float inv = 1.f / (sums[i] + 1e-16f);
  float accx[8] = {0.f,0.f,0.f,0.f,0.f,0.f,0.f,0.f};
  float accr[4] = {0.f,0.f,0.f,0.f};
  float sa = 0.f;
  for (int p = p0 + w; p < p1; p += 4){
    int e = perm[p];
    float al = ex[e] * inv;
    sa += al;
    if (lane < 38){
      int j = row1[e];
      half8 v = *(const half8*)(xh2 + (size_t)j * 1024 + 8*lane);  // cols>=300 garbage, never stored
      #pragma unroll
      for (int k = 0; k < 8; k++) accx[k] += al * lrelu_f((float)v[k]);
    } else if (lane < 63){
      int r = relI[e];
      floatx4 v = *(const floatx4*)(relEmb + (size_t)r * 100 + 4*(lane - 38));
      #pragma unroll
      for (int k = 0; k < 4; k++) accr[k] += al * lrelu_f(v[k]);
    }
  }
  __shared__ float redx[4][304];
  __shared__ float redr[4][100];
  __shared__ float redsa[4];
  if (lane < 38){
    #pragma unroll
    for (int k = 0; k < 8; k++) redx[w][8*lane + k] = accx[k];
  } else if (lane < 63){
    #pragma unroll
    for (int k = 0; k < 4; k++) redr[w][4*(lane - 38) + k] = accr[k];
  }
  if (lane == 63) redsa[w] = sa;
  __syncthreads();
  float sumA = redsa[0] + redsa[1] + redsa[2] + redsa[3];
  float* oi = out + (size_t)i * 2000;
  _Float16* hi = xh2 + (size_t)i * 1024;
  for (int c = t; c < 300; c += 256){
    float ax = redx[0][c] + redx[1][c] + redx[2][c] + redx[3][c];
    oi[700 + c] = ax; hi[700 + c] = (_Float16)ax;
  }
  if (t < 100){
    float ar = redr[0][t] + redr[1][t] + redr[2][t] + redr[3][t];
    oi[600 + t] = ar; hi[600 + t] = (_Float16)ar;
  }
  for (int c = t; c < 300; c += 256){
    float h = lrelu_f((float)hi[c]) * sumA;    // x2 f16 mirror cols 0:300
    oi[300 + c] = h; hi[300 + c] = (_Float16)h;
  }
}

// gat (grouped by i=row1): 4 waves, wave=edge; 64 lanes x 2 half8 cover 1024 cols
__global__ __launch_bounds__(256)
void k_gat_gather(const int* __restrict__ off, const int* __restrict__ perm,
                  const int* __restrict__ src, const float* __restrict__ ex,
                  const float* __restrict__ sums, const _Float16* __restrict__ xh2,
                  float* __restrict__ out){
  int i = blockIdx.x, t = threadIdx.x, w = t >> 6, lane = t & 63;
  int p0 = off[i], p1 = off[i+1];
  float inv = 1.f / (sums[i] + 1e-16f);
  float acc[16];
  #pragma unroll
  for (int k = 0; k < 16; k++) acc[k] = 0.f;
  for (int p = p0 + w; p < p1; p += 4){
    int e = perm[p];
    int j = src[e];
    float al = ex[e] * inv;
    const _Float16* xr = xh2 + (size_t)j * 1024;
    half8 v0 = *(const half8*)(xr + 8*lane);
    half8 v1 = *(const half8*)(xr + 512 + 8*lane);   // cols>=1000 garbage, never stored
    #pragma unroll
    for (int k = 0; k < 8; k++){
      acc[k]     += al * (float)v0[k];
      acc[8 + k] += al * (float)v1[k];
    }
  }
  __shared__ float red[4][1024];
  #pragma unroll
  for (int k = 0; k < 8; k++){
    red[w][8*lane + k]       = acc[k];
    red[w][512 + 8*lane + k] = acc[8 + k];
  }
  __syncthreads();
  int c = 4 * t;
  if (c < 1000){
    floatx4 o;
    #pragma unroll
    for (int k = 0; k < 4; k++)
      o[k] = fmaxf(red[0][c+k] + red[1][c+k] + red[2][c+k] + red[3][c+k], 0.f);
    *(floatx4*)(out + (size_t)i * 2000 + 1000 + c) = o;
  }
}

// ---------------- small kernels ----------------
__global__ void k_dot2_small(const float* __restrict__ X, int ld, int len,
                             const float* __restrict__ wA, const float* __restrict__ wB,
                             float* __restrict__ oA, float* __restrict__ oB,
                             int n, int applyL){
  int v = blockIdx.x * blockDim.x + threadIdx.x;
  if (v >= n) return;
  const float* row = X + (size_t)v * ld;
  float a = 0.f, b = 0.f;
  for (int c = 0; c < len; c++){
    float f = row[c];
    if (applyL) f = lrelu_f(f);
    a += f * wA[c];
    if (wB) b += f * wB[c];
  }
  oA[v] = a;
  if (oB) oB[v] = b;
}

// wave-per-row dual dot over f16 rows
__global__ void k_wave_dot2_h(const _Float16* __restrict__ X, long ld, int len,
                              const float* __restrict__ wA, const float* __restrict__ wB,
                              float* __restrict__ oA, float* __restrict__ oB,
                              int n, int applyL){
  int gw = (int)(((long)blockIdx.x * blockDim.x + threadIdx.x) >> 6);
  int lane = threadIdx.x & 63;
  if (gw >= n) return;
  const _Float16* row = X + (size_t)gw * ld;
  float a = 0.f, b = 0.f;
  for (int c = lane*2; c < len; c += 128){
    half2 v = *(const half2*)(row + c);
    float f0 = (float)v[0], f1 = (float)v[1];
    if (applyL){ f0 = lrelu_f(f0); f1 = lrelu_f(f1); }
    a += f0 * wA[c] + f1 * wA[c+1];
    b += f0 * wB[c] + f1 * wB[c+1];
  }
  #pragma unroll
  for (int o = 32; o > 0; o >>= 1){
    a += __shfl_down(a, o);
    b += __shfl_down(b, o);
  }
  if (lane == 0){ oA[gw] = a; oB[gw] = b; }
}

__global__ void k_edge_logit(const int* __restrict__ segI, const int* __restrict__ othI,
                             const int* __restrict__ relI,
                             const float* __restrict__ sSeg, const float* __restrict__ sOth,
                             const float* __restrict__ sRel,
                             float* __restrict__ elog, unsigned* __restrict__ mEnc,
                             int E, int applyL){
  int e = blockIdx.x * blockDim.x + threadIdx.x;
  if (e >= E) return;
  int s = segI[e];
  float v = sSeg[s] + sOth[othI[e]];
  if (relI) v += sRel[relI[e]];
  if (applyL) v = lrelu_f(v);
  elog[e] = v;
  atomicMax(mEnc + s, encF(v));
}

__global__ void k_edge_exp(const int* __restrict__ segI, float* __restrict__ elog,
                           const unsigned* __restrict__ mEnc, float* __restrict__ segSum, int E){
  int e = blockIdx.x * blockDim.x + threadIdx.x;
  if (e >= E) return;
  int s = segI[e];
  float ex = expf(elog[e] - decF(mEnc[s]));
  elog[e] = ex;
  atomAddF(segSum + s, ex);
}

__global__ void k_gatr_scatter(const int* __restrict__ src, const int* __restrict__ dst,
                               const float* __restrict__ ex, const float* __restrict__ segSum,
                               const float* __restrict__ xin, float* __restrict__ oagg, int F){
  int e = blockIdx.x;
  int j = src[e], i = dst[e];
  float alpha = ex[e] / (segSum[j] + 1e-16f);
  const float* xj = xin + (size_t)j * F;
  float* oi = oagg + (size_t)i * F;
  for (int c = threadIdx.x; c < F; c += blockDim.x)
    atomAddF(oi + c, alpha * xj[c]);
}

__global__ void k_relu_lin(float* __restrict__ p, long n){
  long t = (long)blockIdx.x * blockDim.x + threadIdx.x;
  if (t < n) p[t] = fmaxf(p[t], 0.f);
}

extern "C" void kernel_launch(void* const* d_in, const int* in_sizes, int n_in,
                              void* d_out, int out_size, void* d_ws, size_t ws_size,
                              hipStream_t stream){
  const float* x_e     = (const float*)d_in[0];
  const int*   eiA     = (const int*)  d_in[3];   // edge_index_all [2,E]
  const int*   relAll  = (const int*)  d_in[4];
  const int*   lgOut   = (const int*)  d_in[5];
  const int*   lgIn    = (const int*)  d_in[7];
  const float* gcn1_w  = (const float*)d_in[9];
  const float* gcn2_w  = (const float*)d_in[10];
  const float* hw1_w   = (const float*)d_in[11];
  const float* hw1_b   = (const float*)d_in[12];
  const float* hw2_w   = (const float*)d_in[13];
  const float* hw2_b   = (const float*)d_in[14];
  const float* ww1     = (const float*)d_in[15];
  const float* gat_ai  = (const float*)d_in[16];
  const float* gat_aj  = (const float*)d_in[17];
  const float* gat_ar  = (const float*)d_in[18];
  const float* gatr_ai = (const float*)d_in[19];
  const float* gatr_aj = (const float*)d_in[20];
  const float* relEmb1 = (const float*)d_in[21];

  const int EH = 300, RH = 100;
  const int N   = in_sizes[0] / EH;
  const int E   = in_sizes[3] / 2;
  const int ELG = in_sizes[5] / 2;
  const int R   = in_sizes[21] / RH;
  const int Mtiles = (N + 127) / 128;
  const int Mpad = Mtiles * 128;

  // ---- workspace layout (16B-aligned f16 blocks first) ----
  char* base = (char*)d_ws;
  _Float16* xhA   = (_Float16*)base;  base += (size_t)Mpad * 320 * 2;   // x_e f16 -> x1 f16
  _Float16* A1f16 = (_Float16*)base;  base += (size_t)Mpad * 320 * 2;   // relu(agg) f16
  _Float16* xh2   = (_Float16*)base;  base += (size_t)N * 1024 * 2;     // x_wjq f16 mirror
  _Float16* BfAll = (_Float16*)base;  base += (size_t)4 * 102400 * 2;
  float* w = (float*)base;
  float* dis    = w; w += N;
  float* relEmb = w; w += (size_t)2 * R * RH;
  float* sxi    = w; w += N;
  float* sxj    = w; w += N;
  unsigned* mEncN = (unsigned*)w; w += N;
  float* sumN   = w; w += N;
  float* sR_i   = w; w += R;
  float* sR_j   = w; w += R;
  unsigned* mEncR = (unsigned*)w; w += R;
  float* sumR   = w; w += R;
  float* aRel   = w; w += 2 * R;
  float* srr    = w; w += 2 * R;
  float* eE     = w; w += E;
  int* degD   = (int*)w; w += N;
  int* degS   = (int*)w; w += N;
  int* curD   = (int*)w; w += N;
  int* curS   = (int*)w; w += N;
  int* offD   = (int*)w; w += N + 1;
  int* offS   = (int*)w; w += N + 1;
  int* permD  = (int*)w; w += E;
  int* permS  = (int*)w; w += E;

  _Float16* Bf_g1 = BfAll;
  _Float16* Bf_h1 = BfAll + 102400;
  _Float16* Bf_g2 = BfAll + 2 * 102400;
  _Float16* Bf_h2 = BfAll + 3 * 102400;

  float* out = (float*)d_out;
  const int* srcA = eiA;         // row0 (j in gcn/gat, i in wjq)
  const int* dstA = eiA + E;     // row1

  auto cdiv = [](int a, int b){ return (a + b - 1) / b; };

  // ---- fused CSR build (dst grouping + src grouping) ----
  hipMemsetAsync(degD, 0, (size_t)4 * N * 4, stream);   // degD,degS,curD,curS contiguous
  k_count2<<<cdiv(E,256),256,0,stream>>>(dstA, srcA, degD, degS, E);
  k_scan2<<<2,256,0,stream>>>(degD, offD, degS, offS, N);
  k_fill2<<<cdiv(E,256),256,0,stream>>>(dstA, srcA, offD, offS, curD, curS, permD, permS, E);
  k_inv_sqrt_int<<<cdiv(N,256),256,0,stream>>>(degD, dis, N);

  // ---- pack weights into MFMA fragment layout; convert x_e to f16 ----
  k_prep_B<<<50,256,0,stream>>>(gcn1_w, Bf_g1, EH, EH);
  k_prep_B<<<50,256,0,stream>>>(hw1_w,  Bf_h1, EH, EH);
  k_prep_B<<<50,256,0,stream>>>(gcn2_w, Bf_g2, EH, EH);
  k_prep_B<<<50,256,0,stream>>>(hw2_w,  Bf_h2, EH, EH);
  k_conv_f16<<<Mpad,256,0,stream>>>(x_e, xhA, N);
  // zero A1f16 pad rows once per call (gathers rewrite rows < N)
  if (Mpad > N)
    hipMemsetAsync(A1f16 + (size_t)N*320, 0, (size_t)(Mpad - N)*320*2, stream);

  int NB = 5 * Mtiles;

  // layer 1: x1 = highway(x_e, gcn(x_e)) -> xhA (f16 mirror only)
  k_gcn_gather<<<N,256,0,stream>>>(offD, permD, srcA, xhA, dis, A1f16);
  k_dual_mfma<<<NB,256,0,stream>>>(A1f16, x_e, nullptr, Bf_g1, Bf_h1, hw1_b,
                                   nullptr, 0, xhA, 320, N);

  // layer 2: x2 = highway(x1, gcn(x1)) -> out cols 0:300 + xh2 cols 0:300
  k_gcn_gather<<<N,256,0,stream>>>(offD, permD, srcA, xhA, dis, A1f16);
  k_dual_mfma<<<NB,256,0,stream>>>(A1f16, nullptr, xhA, Bf_g2, Bf_h2, hw2_b,
                                   out, 2000, xh2, 1024, N);

  // gat_r -> relEmb [2R,100]
  k_dot2_small<<<cdiv(R,256),256,0,stream>>>(relEmb1, RH, RH, gatr_ai, gatr_aj, sR_i, sR_j, R, 0);
  hipMemsetAsync(relEmb, 0, (size_t)2*R*RH*4, stream);
  for (int g = 0; g < 2; g++){
    const int* lg = (g == 0) ? lgOut : lgIn;
    float* part = relEmb + (size_t)g * R * RH;
    hipMemsetAsync(mEncR, 0, (size_t)2*R*4, stream);   // mEncR + sumR contiguous
    k_edge_logit<<<cdiv(ELG,256),256,0,stream>>>(lg, lg + ELG, nullptr, sR_j, sR_i, nullptr,
                                                 eE, mEncR, ELG, 1);
    k_edge_exp<<<cdiv(ELG,256),256,0,stream>>>(lg, eE, mEncR, sumR, ELG);
    k_gatr_scatter<<<ELG,128,0,stream>>>(lg, lg + ELG, eE, sumR, relEmb1, part, RH);
  }
  k_relu_lin<<<cdiv(2*R*RH,256),256,0,stream>>>(relEmb, (long)2*R*RH);

  // wjq: softmax grouped by row0 (=i), feat = [ef[i] | re[rel] | ef[j]]
  k_dot2_small<<<cdiv(2*R,256),256,0,stream>>>(relEmb, RH, RH, ww1 + EH, nullptr, aRel, nullptr, 2*R, 1);
  k_wave_dot2_h<<<cdiv(N,4),256,0,stream>>>(xh2, 1024, EH, ww1, ww1 + EH + RH, sxi, sxj, N, 1);
  hipMemsetAsync(mEncN, 0, (size_t)2*N*4, stream);     // mEncN + sumN contiguous
  k_edge_logit<<<cdiv(E,256),256,0,stream>>>(srcA, dstA, relAll, sxi, sxj, aRel, eE, mEncN, E, 0);
  k_edge_exp<<<cdiv(E,256),256,0,stream>>>(srcA, eE, mEncN, sumN, E);
  k_wjq_gather<<<N,256,0,stream>>>(offS, permS, dstA, relAll, eE, sumN, relEmb, out, xh2);

  // gat over x_wjq (xh2 cols 0:1000), softmax grouped by row1 (=i)
  k_wave_dot2_h<<<cdiv(N,4),256,0,stream>>>(xh2, 1024, 1000, gat_ai, gat_aj, sxi, sxj, N, 0);
  k_dot2_small<<<cdiv(2*R,256),256,0,stream>>>(relEmb, RH, RH, gat_ar, nullptr, srr, nullptr, 2*R, 0);
  hipMemsetAsync(mEncN, 0, (size_t)2*N*4, stream);
  k_edge_logit<<<cdiv(E,256),256,0,stream>>>(dstA, srcA, relAll, sxi, sxj, srr, eE, mEncN, E, 1);
  k_edge_exp<<<cdiv(E,256),256,0,stream>>>(dstA, eE, mEncN, sumN, E);
  k_gat_gather<<<N,256,0,stream>>>(offD, permD, srcA, eE, sumN, xh2, out);
}

// Round 7
// 521.147 us; speedup vs baseline: 4.0135x; 1.1943x over previous
//
#include <hip/hip_runtime.h>
#include <math.h>

#define LSL 0.01f

typedef _Float16 half8 __attribute__((ext_vector_type(8)));
typedef _Float16 half2 __attribute__((ext_vector_type(2)));
typedef float floatx4 __attribute__((ext_vector_type(4)));

static __device__ __forceinline__ float lrelu_f(float x){ return x > 0.f ? x : LSL * x; }
static __device__ __forceinline__ void atomAddF(float* p, float v){ unsafeAtomicAdd(p, v); }

// monotone float <-> uint bijection so atomicMax(uint) == float max; 0 encodes < -inf
static __device__ __forceinline__ unsigned encF(float f){
  unsigned u = __float_as_uint(f);
  return (u & 0x80000000u) ? ~u : (u | 0x80000000u);
}
static __device__ __forceinline__ float decF(unsigned u){
  return (u & 0x80000000u) ? __uint_as_float(u & 0x7FFFFFFFu) : __uint_as_float(~u);
}

// ---------------- CSR build (fused) ----------------
__global__ void k_count2(const int* __restrict__ dstA, const int* __restrict__ srcA,
                         int* __restrict__ degD, int* __restrict__ degS, int E){
  int e = blockIdx.x * blockDim.x + threadIdx.x;
  if (e < E){ atomicAdd(degD + dstA[e], 1); atomicAdd(degS + srcA[e], 1); }
}

// two single-block exclusive scans in parallel (block 0 -> D, block 1 -> S)
__global__ void k_scan2(const int* __restrict__ cntD, int* __restrict__ offD,
                        const int* __restrict__ cntS, int* __restrict__ offS, int n){
  const int* cnt = blockIdx.x ? cntS : cntD;
  int* off = blockIdx.x ? offS : offD;
  __shared__ int wsum[4];
  __shared__ int carry;
  int t = threadIdx.x, lane = t & 63, wid = t >> 6;
  if (t == 0) carry = 0;
  __syncthreads();
  for (int base = 0; base < n; base += 256){
    int idx = base + t;
    int v = (idx < n) ? cnt[idx] : 0;
    int s = v;
    #pragma unroll
    for (int o = 1; o < 64; o <<= 1){
      int u = __shfl_up(s, o);
      if (lane >= o) s += u;
    }
    if (lane == 63) wsum[wid] = s;
    __syncthreads();
    int wo = 0;
    #pragma unroll
    for (int k = 0; k < 3; k++) wo += (k < wid) ? wsum[k] : 0;
    if (idx < n) off[idx] = carry + wo + s - v;
    int tot = wsum[0] + wsum[1] + wsum[2] + wsum[3];
    __syncthreads();
    if (t == 0) carry += tot;
    __syncthreads();
  }
  if (t == 0) off[n] = carry;
}

__global__ void k_fill2(const int* __restrict__ dstA, const int* __restrict__ srcA,
                        const int* __restrict__ offD, const int* __restrict__ offS,
                        int* __restrict__ curD, int* __restrict__ curS,
                        int* __restrict__ permD, int* __restrict__ permS, int E){
  int e = blockIdx.x * blockDim.x + threadIdx.x;
  if (e >= E) return;
  int i = dstA[e];
  permD[offD[i] + atomicAdd(curD + i, 1)] = e;
  int j = srcA[e];
  permS[offS[j] + atomicAdd(curS + j, 1)] = e;
}

__global__ void k_inv_sqrt_int(const int* __restrict__ deg, float* __restrict__ dis, int N){
  int v = blockIdx.x * blockDim.x + threadIdx.x;
  if (v < N){ int d = deg[v]; dis[v] = d > 0 ? rsqrtf((float)d) : 0.f; }
}

// x_e f32 [N][300] -> xhA f16 [Mpad][320] zero-padded (cols 300:320, rows N:Mpad)
__global__ __launch_bounds__(256)
void k_conv_f16(const float* __restrict__ x, _Float16* __restrict__ xh, int N){
  int i = blockIdx.x, t = threadIdx.x;
  _Float16* o = xh + (size_t)i * 320;
  if (i < N){
    const float* r = x + (size_t)i * 300;
    o[t] = (_Float16)r[t];
    if (t < 44) o[t + 256] = (_Float16)r[t + 256];
    else if (t < 64) o[t + 256] = (_Float16)0.f;
  } else {
    o[t] = (_Float16)0.f;
    if (t < 64) o[t + 256] = (_Float16)0.f;
  }
}

// ---------------- CSR gathers: wave-per-node, register accumulate ----------------
// agg_f16[i][0:320] = relu(sum_e dis[i]*dis[j] * xh[j]); wave = node, lane<40 x half8
__global__ __launch_bounds__(256)
void k_gcn_gather(const int* __restrict__ off, const int* __restrict__ perm,
                  const int* __restrict__ src, const _Float16* __restrict__ x,
                  const float* __restrict__ dis, _Float16* __restrict__ agg, int N){
  int i = (int)(((long)blockIdx.x * blockDim.x + threadIdx.x) >> 6);
  int lane = threadIdx.x & 63;
  if (i >= N) return;
  int p0 = off[i], p1 = off[i+1];
  float di = dis[i];
  float acc[8] = {0.f,0.f,0.f,0.f,0.f,0.f,0.f,0.f};
  for (int base = p0; base < p1; base += 64){
    int m = min(64, p1 - base);
    int jj = 0; float wl = 0.f;
    if (base + lane < p1){
      int e = perm[base + lane];
      jj = src[e];
      wl = di * dis[jj];
    }
    for (int q = 0; q < m; q++){
      int j = __shfl(jj, q);
      float wt = __shfl(wl, q);
      if (lane < 40){
        half8 v = *(const half8*)(x + (size_t)j * 320 + 8*lane);
        #pragma unroll
        for (int k = 0; k < 8; k++) acc[k] += wt * (float)v[k];
      }
    }
  }
  if (lane < 40){
    half8 o;
    #pragma unroll
    for (int k = 0; k < 8; k++) o[k] = (_Float16)fmaxf(acc[k], 0.f);
    *(half8*)(agg + (size_t)i * 320 + 8*lane) = o;
  }
}

// ---------------- MFMA dual-GEMM + highway ----------------
// pack W [K x Nn] f32 into fragment-ready f16: Bf[((ks*5+nt)*4+nf)*64+lane][8]
__global__ void k_prep_B(const float* __restrict__ W, _Float16* __restrict__ Bf,
                         int K, int Nn){
  int idx = blockIdx.x * 256 + threadIdx.x;
  if (idx >= 10*5*4*64) return;
  int lane = idx & 63;
  int rem = idx >> 6;
  int nf = rem & 3; rem >>= 2;
  int nt = rem % 5;
  int ks = rem / 5;
  int n = nt*64 + nf*16 + (lane & 15);
  int kb = ks*32 + (lane >> 4) * 8;
  _Float16* o = Bf + (size_t)idx * 8;
  #pragma unroll
  for (int e = 0; e < 8; e++){
    int k = kb + e;
    float v = (k < K && n < Nn) ? W[(size_t)k * Nn + n] : 0.f;
    o[e] = (_Float16)v;
  }
}

// O = sig(X@Wh + b) * (A1@Wg) + (1-sig)*X ; A1 = relu(agg) f16 [Mpad][320]
// 1-D grid, bijective XCD swizzle: 5 column-tile blocks of one A-panel co-resident per XCD.
__global__ __launch_bounds__(256)
void k_dual_mfma(const _Float16* __restrict__ A1, const float* __restrict__ Xf32,
                 const _Float16* __restrict__ Xh,
                 const _Float16* __restrict__ Bf1, const _Float16* __restrict__ Bf2,
                 const float* __restrict__ bias, float* __restrict__ Of32, long ldo,
                 _Float16* __restrict__ Oh, long ldm, int M){
  int nb = gridDim.x;
  int q = nb >> 3, r = nb & 7;
  int xcd = blockIdx.x & 7, kk0 = blockIdx.x >> 3;
  int pseudo = (xcd < r ? xcd * (q + 1) : r * (q + 1) + (xcd - r) * q) + kk0;
  int nt = pseudo % 5;
  int panel = pseudo / 5;

  int tid = threadIdx.x;
  int w = tid >> 6, lane = tid & 63;
  int l15 = lane & 15, lg = lane >> 4;
  int rowBase = panel * 128 + w * 32;
  int colBase = nt * 64;

  floatx4 acc1[2][4], acc2[2][4];
  #pragma unroll
  for (int a = 0; a < 2; a++)
    #pragma unroll
    for (int b = 0; b < 4; b++){
      acc1[a][b] = (floatx4){0.f,0.f,0.f,0.f};
      acc2[a][b] = (floatx4){0.f,0.f,0.f,0.f};
    }

  int row0 = rowBase + l15, row1 = rowBase + 16 + l15;
  int rX0 = min(row0, M-1), rX1 = min(row1, M-1);
  const _Float16* a1p0 = A1 + (size_t)row0 * 320;
  const _Float16* a1p1 = A1 + (size_t)row1 * 320;

  for (int ks = 0; ks < 10; ks++){
    int kA = ks*32 + lg*8;
    half8 a1f0 = *(const half8*)(a1p0 + kA);
    half8 a1f1 = *(const half8*)(a1p1 + kA);
    half8 a2f0, a2f1;
    if (Xh){
      a2f0 = *(const half8*)(Xh + (size_t)row0 * 320 + kA);
      a2f1 = *(const half8*)(Xh + (size_t)row1 * 320 + kA);
    } else {
      const float* xp0 = Xf32 + (size_t)rX0 * 300;
      const float* xp1 = Xf32 + (size_t)rX1 * 300;
      int lo = min(kA, 296), hi = min(kA + 4, 292);
      floatx4 x0l = *(const floatx4*)(xp0 + lo);
      floatx4 x0h = *(const floatx4*)(xp0 + hi);
      floatx4 x1l = *(const floatx4*)(xp1 + lo);
      floatx4 x1h = *(const floatx4*)(xp1 + hi);
      #pragma unroll
      for (int e = 0; e < 4; e++){
        a2f0[e] = (_Float16)x0l[e]; a2f0[e+4] = (_Float16)x0h[e];
        a2f1[e] = (_Float16)x1l[e]; a2f1[e+4] = (_Float16)x1h[e];
      }
    }
    const half8* b1p = (const half8*)Bf1 + ((size_t)(ks*5 + nt) * 4 * 64 + lane);
    const half8* b2p = (const half8*)Bf2 + ((size_t)(ks*5 + nt) * 4 * 64 + lane);
    #pragma unroll
    for (int nf = 0; nf < 4; nf++){
      half8 b1 = b1p[nf*64];
      half8 b2 = b2p[nf*64];
      acc1[0][nf] = __builtin_amdgcn_mfma_f32_16x16x32_f16(a1f0, b1, acc1[0][nf], 0,0,0);
      acc1[1][nf] = __builtin_amdgcn_mfma_f32_16x16x32_f16(a1f1, b1, acc1[1][nf], 0,0,0);
      acc2[0][nf] = __builtin_amdgcn_mfma_f32_16x16x32_f16(a2f0, b2, acc2[0][nf], 0,0,0);
      acc2[1][nf] = __builtin_amdgcn_mfma_f32_16x16x32_f16(a2f1, b2, acc2[1][nf], 0,0,0);
    }
  }

  #pragma unroll
  for (int mf = 0; mf < 2; mf++){
    #pragma unroll
    for (int nf = 0; nf < 4; nf++){
      int gn = colBase + nf*16 + l15;
      int gnc = min(gn, 299);
      float bv = bias[gnc];
      #pragma unroll
      for (int r2 = 0; r2 < 4; r2++){
        int gm = rowBase + mf*16 + lg*4 + r2;
        int gmc = min(gm, M-1);
        float xv = Xh ? (float)Xh[(size_t)gmc * 320 + gnc]
                      : Xf32[(size_t)gmc * 300 + gnc];
        float g = 1.f / (1.f + expf(-(acc2[mf][nf][r2] + bv)));
        float val = g * acc1[mf][nf][r2] + (1.f - g) * xv;
        if (gm < M && gn < 300){
          if (Of32) Of32[(size_t)gm * ldo + gn] = val;
          if (Oh)   Oh[(size_t)gm * ldm + gn] = (_Float16)val;
        }
      }
    }
  }
}

// wjq: wave-per-node (grouped by i=row0), FUSED segment softmax + gather + head
// + fused GAT logit dots gxi/gxj over the completed 1000-col row.
__global__ __launch_bounds__(256)
void k_wjq_gather(const int* __restrict__ off, const int* __restrict__ perm,
                  const int* __restrict__ dstA, const int* __restrict__ relI,
                  const float* __restrict__ sxi, const float* __restrict__ sxj,
                  const float* __restrict__ aRel, const float* __restrict__ relEmb,
                  const float* __restrict__ gat_ai, const float* __restrict__ gat_aj,
                  float* __restrict__ out, _Float16* __restrict__ xh2,
                  float* __restrict__ gxi, float* __restrict__ gxj, int N){
  int i = (int)(((long)blockIdx.x * blockDim.x + threadIdx.x) >> 6);
  int lane = threadIdx.x & 63;
  if (i >= N) return;
  int p0 = off[i], p1 = off[i+1];
  float si = sxi[i];

  // segment max
  float lm = -3.4e38f;
  for (int p = p0 + lane; p < p1; p += 64){
    int e = perm[p];
    lm = fmaxf(lm, si + sxj[dstA[e]] + aRel[relI[e]]);
  }
  #pragma unroll
  for (int o = 32; o > 0; o >>= 1) lm = fmaxf(lm, __shfl_xor(lm, o));
  // segment sum
  float ls = 0.f;
  for (int p = p0 + lane; p < p1; p += 64){
    int e = perm[p];
    ls += expf(si + sxj[dstA[e]] + aRel[relI[e]] - lm);
  }
  #pragma unroll
  for (int o = 32; o > 0; o >>= 1) ls += __shfl_xor(ls, o);
  float inv = 1.f / (ls + 1e-16f);
  float sumA = ls * inv;

  // gather: chunked edge-metadata preload + shfl broadcast
  float accx[8] = {0.f,0.f,0.f,0.f,0.f,0.f,0.f,0.f};
  float accr[4] = {0.f,0.f,0.f,0.f};
  for (int base = p0; base < p1; base += 64){
    int m = min(64, p1 - base);
    int jj = 0, rr = 0; float all = 0.f;
    if (base + lane < p1){
      int e = perm[base + lane];
      jj = dstA[e]; rr = relI[e];
      all = expf(si + sxj[jj] + aRel[rr] - lm) * inv;
    }
    for (int qe = 0; qe < m; qe++){
      int j = __shfl(jj, qe);
      int r = __shfl(rr, qe);
      float al = __shfl(all, qe);
      if (lane < 38){
        half8 v = *(const half8*)(xh2 + (size_t)j * 1024 + 8*lane);  // cols>=300 garbage, never used
        #pragma unroll
        for (int k = 0; k < 8; k++) accx[k] += al * lrelu_f((float)v[k]);
      } else if (lane < 63){
        floatx4 v = *(const floatx4*)(relEmb + (size_t)r * 100 + 4*(lane - 38));
        #pragma unroll
        for (int k = 0; k < 4; k++) accr[k] += al * lrelu_f(v[k]);
      }
    }
  }

  // epilogue: write cols 600:1000, head 300:600; fused gxi/gxj dots over full row
  float* oi = out + (size_t)i * 2000;
  _Float16* hi = xh2 + (size_t)i * 1024;
  float dA = 0.f, dB = 0.f;
  if (lane < 38){
    #pragma unroll
    for (int k = 0; k < 8; k++){
      int c = 8*lane + k;
      if (c < 300){
        oi[700 + c] = accx[k]; hi[700 + c] = (_Float16)accx[k];
        dA += accx[k] * gat_ai[700 + c];
        dB += accx[k] * gat_aj[700 + c];
      }
    }
    half8 v = *(const half8*)(hi + 8*lane);   // x2 f16 (cols 0:300, written by dual_mfma)
    #pragma unroll
    for (int k = 0; k < 8; k++){
      int c = 8*lane + k;
      if (c < 300){
        float x2v = (float)v[k];
        float h = lrelu_f(x2v) * sumA;
        oi[300 + c] = h; hi[300 + c] = (_Float16)h;
        dA += x2v * gat_ai[c] + h * gat_ai[300 + c];
        dB += x2v * gat_aj[c] + h * gat_aj[300 + c];
      }
    }
  } else if (lane < 63){
    #pragma unroll
    for (int k = 0; k < 4; k++){
      int c = 4*(lane - 38) + k;
      oi[600 + c] = accr[k]; hi[600 + c] = (_Float16)accr[k];
      dA += accr[k] * gat_ai[600 + c];
      dB += accr[k] * gat_aj[600 + c];
    }
  }
  #pragma unroll
  for (int o = 32; o > 0; o >>= 1){
    dA += __shfl_xor(dA, o);
    dB += __shfl_xor(dB, o);
  }
  if (lane == 0){ gxi[i] = dA; gxj[i] = dB; }
}

// gat: wave-per-node (grouped by i=row1), FUSED segment softmax + gather + relu
__global__ __launch_bounds__(256)
void k_gat_gather(const int* __restrict__ off, const int* __restrict__ perm,
                  const int* __restrict__ srcA, const int* __restrict__ relI,
                  const float* __restrict__ gxi, const float* __restrict__ gxj,
                  const float* __restrict__ srr, const _Float16* __restrict__ xh2,
                  float* __restrict__ out, int N){
  int i = (int)(((long)blockIdx.x * blockDim.x + threadIdx.x) >> 6);
  int lane = threadIdx.x & 63;
  if (i >= N) return;
  int p0 = off[i], p1 = off[i+1];
  float gi = gxi[i];

  float lm = -3.4e38f;
  for (int p = p0 + lane; p < p1; p += 64){
    int e = perm[p];
    lm = fmaxf(lm, lrelu_f(gi + gxj[srcA[e]] + srr[relI[e]]));
  }
  #pragma unroll
  for (int o = 32; o > 0; o >>= 1) lm = fmaxf(lm, __shfl_xor(lm, o));
  float ls = 0.f;
  for (int p = p0 + lane; p < p1; p += 64){
    int e = perm[p];
    ls += expf(lrelu_f(gi + gxj[srcA[e]] + srr[relI[e]]) - lm);
  }
  #pragma unroll
  for (int o = 32; o > 0; o >>= 1) ls += __shfl_xor(ls, o);
  float inv = 1.f / (ls + 1e-16f);

  float acc[16];
  #pragma unroll
  for (int k = 0; k < 16; k++) acc[k] = 0.f;
  for (int base = p0; base < p1; base += 64){
    int m = min(64, p1 - base);
    int jj = 0; float all = 0.f;
    if (base + lane < p1){
      int e = perm[base + lane];
      jj = srcA[e];
      all = expf(lrelu_f(gi + gxj[jj] + srr[relI[e]]) - lm) * inv;
    }
    for (int qe = 0; qe < m; qe++){
      int j = __shfl(jj, qe);
      float al = __shfl(all, qe);
      const _Float16* xr = xh2 + (size_t)j * 1024;
      half8 v0 = *(const half8*)(xr + 8*lane);
      half8 v1 = *(const half8*)(xr + 512 + 8*lane);   // cols>=1000 garbage, never stored
      #pragma unroll
      for (int k = 0; k < 8; k++){
        acc[k]     += al * (float)v0[k];
        acc[8 + k] += al * (float)v1[k];
      }
    }
  }
  float* oi = out + (size_t)i * 2000 + 1000;
  floatx4 s0, s1;
  #pragma unroll
  for (int k = 0; k < 4; k++){ s0[k] = fmaxf(acc[k], 0.f); s1[k] = fmaxf(acc[4+k], 0.f); }
  *(floatx4*)(oi + 8*lane) = s0;
  *(floatx4*)(oi + 8*lane + 4) = s1;
  if (lane < 61){
    floatx4 s2, s3;
    #pragma unroll
    for (int k = 0; k < 4; k++){ s2[k] = fmaxf(acc[8+k], 0.f); s3[k] = fmaxf(acc[12+k], 0.f); }
    *(floatx4*)(oi + 512 + 8*lane) = s2;
    *(floatx4*)(oi + 512 + 8*lane + 4) = s3;
  }
}

// ---------------- small kernels ----------------
__global__ void k_dot2_small(const float* __restrict__ X, int ld, int len,
                             const float* __restrict__ wA, const float* __restrict__ wB,
                             float* __restrict__ oA, float* __restrict__ oB,
                             int n, int applyL){
  int v = blockIdx.x * blockDim.x + threadIdx.x;
  if (v >= n) return;
  const float* row = X + (size_t)v * ld;
  float a = 0.f, b = 0.f;
  for (int c = 0; c < len; c++){
    float f = row[c];
    if (applyL) f = lrelu_f(f);
    a += f * wA[c];
    if (wB) b += f * wB[c];
  }
  oA[v] = a;
  if (oB) oB[v] = b;
}

// wave-per-row dual dot over f16 rows
__global__ void k_wave_dot2_h(const _Float16* __restrict__ X, long ld, int len,
                              const float* __restrict__ wA, const float* __restrict__ wB,
                              float* __restrict__ oA, float* __restrict__ oB,
                              int n, int applyL){
  int gw = (int)(((long)blockIdx.x * blockDim.x + threadIdx.x) >> 6);
  int lane = threadIdx.x & 63;
  if (gw >= n) return;
  const _Float16* row = X + (size_t)gw * ld;
  float a = 0.f, b = 0.f;
  for (int c = lane*2; c < len; c += 128){
    half2 v = *(const half2*)(row + c);
    float f0 = (float)v[0], f1 = (float)v[1];
    if (applyL){ f0 = lrelu_f(f0); f1 = lrelu_f(f1); }
    a += f0 * wA[c] + f1 * wA[c+1];
    b += f0 * wB[c] + f1 * wB[c+1];
  }
  #pragma unroll
  for (int o = 32; o > 0; o >>= 1){
    a += __shfl_down(a, o);
    b += __shfl_down(b, o);
  }
  if (lane == 0){ oA[gw] = a; oB[gw] = b; }
}

__global__ void k_edge_logit(const int* __restrict__ segI, const int* __restrict__ othI,
                             const int* __restrict__ relI,
                             const float* __restrict__ sSeg, const float* __restrict__ sOth,
                             const float* __restrict__ sRel,
                             float* __restrict__ elog, unsigned* __restrict__ mEnc,
                             int E, int applyL){
  int e = blockIdx.x * blockDim.x + threadIdx.x;
  if (e >= E) return;
  int s = segI[e];
  float v = sSeg[s] + sOth[othI[e]];
  if (relI) v += sRel[relI[e]];
  if (applyL) v = lrelu_f(v);
  elog[e] = v;
  atomicMax(mEnc + s, encF(v));
}

__global__ void k_edge_exp(const int* __restrict__ segI, float* __restrict__ elog,
                           const unsigned* __restrict__ mEnc, float* __restrict__ segSum, int E){
  int e = blockIdx.x * blockDim.x + threadIdx.x;
  if (e >= E) return;
  int s = segI[e];
  float ex = expf(elog[e] - decF(mEnc[s]));
  elog[e] = ex;
  atomAddF(segSum + s, ex);
}

__global__ void k_gatr_scatter(const int* __restrict__ src, const int* __restrict__ dst,
                               const float* __restrict__ ex, const float* __restrict__ segSum,
                               const float* __restrict__ xin, float* __restrict__ oagg, int F){
  int e = blockIdx.x;
  int j = src[e], i = dst[e];
  float alpha = ex[e] / (segSum[j] + 1e-16f);
  const float* xj = xin + (size_t)j * F;
  float* oi = oagg + (size_t)i * F;
  for (int c = threadIdx.x; c < F; c += blockDim.x)
    atomAddF(oi + c, alpha * xj[c]);
}

__global__ void k_relu_lin(float* __restrict__ p, long n){
  long t = (long)blockIdx.x * blockDim.x + threadIdx.x;
  if (t < n) p[t] = fmaxf(p[t], 0.f);
}

extern "C" void kernel_launch(void* const* d_in, const int* in_sizes, int n_in,
                              void* d_out, int out_size, void* d_ws, size_t ws_size,
                              hipStream_t stream){
  const float* x_e     = (const float*)d_in[0];
  const int*   eiA     = (const int*)  d_in[3];   // edge_index_all [2,E]
  const int*   relAll  = (const int*)  d_in[4];
  const int*   lgOut   = (const int*)  d_in[5];
  const int*   lgIn    = (const int*)  d_in[7];
  const float* gcn1_w  = (const float*)d_in[9];
  const float* gcn2_w  = (const float*)d_in[10];
  const float* hw1_w   = (const float*)d_in[11];
  const float* hw1_b   = (const float*)d_in[12];
  const float* hw2_w   = (const float*)d_in[13];
  const float* hw2_b   = (const float*)d_in[14];
  const float* ww1     = (const float*)d_in[15];
  const float* gat_ai  = (const float*)d_in[16];
  const float* gat_aj  = (const float*)d_in[17];
  const float* gat_ar  = (const float*)d_in[18];
  const float* gatr_ai = (const float*)d_in[19];
  const float* gatr_aj = (const float*)d_in[20];
  const float* relEmb1 = (const float*)d_in[21];

  const int EH = 300, RH = 100;
  const int N   = in_sizes[0] / EH;
  const int E   = in_sizes[3] / 2;
  const int ELG = in_sizes[5] / 2;
  const int R   = in_sizes[21] / RH;
  const int Mtiles = (N + 127) / 128;
  const int Mpad = Mtiles * 128;

  // ---- workspace layout (16B-aligned f16 blocks first) ----
  char* base = (char*)d_ws;
  _Float16* xhA   = (_Float16*)base;  base += (size_t)Mpad * 320 * 2;   // x_e f16 -> x1 f16
  _Float16* A1f16 = (_Float16*)base;  base += (size_t)Mpad * 320 * 2;   // relu(agg) f16
  _Float16* xh2   = (_Float16*)base;  base += (size_t)N * 1024 * 2;     // x_wjq f16 mirror
  _Float16* BfAll = (_Float16*)base;  base += (size_t)4 * 102400 * 2;
  float* w = (float*)base;
  float* dis    = w; w += N;
  float* relEmb = w; w += (size_t)2 * R * RH;
  float* sxi    = w; w += N;
  float* sxj    = w; w += N;
  float* gxi    = w; w += N;
  float* gxj    = w; w += N;
  float* sR_i   = w; w += R;
  float* sR_j   = w; w += R;
  unsigned* mEncR = (unsigned*)w; w += R;
  float* sumR   = w; w += R;
  float* aRel   = w; w += 2 * R;
  float* srr    = w; w += 2 * R;
  float* eE     = w; w += E;
  int* degD   = (int*)w; w += N;
  int* degS   = (int*)w; w += N;
  int* curD   = (int*)w; w += N;
  int* curS   = (int*)w; w += N;
  int* offD   = (int*)w; w += N + 1;
  int* offS   = (int*)w; w += N + 1;
  int* permD  = (int*)w; w += E;
  int* permS  = (int*)w; w += E;

  _Float16* Bf_g1 = BfAll;
  _Float16* Bf_h1 = BfAll + 102400;
  _Float16* Bf_g2 = BfAll + 2 * 102400;
  _Float16* Bf_h2 = BfAll + 3 * 102400;

  float* out = (float*)d_out;
  const int* srcA = eiA;         // row0 (j in gcn/gat, i in wjq)
  const int* dstA = eiA + E;     // row1

  auto cdiv = [](int a, int b){ return (a + b - 1) / b; };

  // ---- fused CSR build (dst grouping + src grouping) ----
  hipMemsetAsync(degD, 0, (size_t)4 * N * 4, stream);   // degD,degS,curD,curS contiguous
  k_count2<<<cdiv(E,256),256,0,stream>>>(dstA, srcA, degD, degS, E);
  k_scan2<<<2,256,0,stream>>>(degD, offD, degS, offS, N);
  k_fill2<<<cdiv(E,256),256,0,stream>>>(dstA, srcA, offD, offS, curD, curS, permD, permS, E);
  k_inv_sqrt_int<<<cdiv(N,256),256,0,stream>>>(degD, dis, N);

  // ---- pack weights into MFMA fragment layout; convert x_e to f16 ----
  k_prep_B<<<50,256,0,stream>>>(gcn1_w, Bf_g1, EH, EH);
  k_prep_B<<<50,256,0,stream>>>(hw1_w,  Bf_h1, EH, EH);
  k_prep_B<<<50,256,0,stream>>>(gcn2_w, Bf_g2, EH, EH);
  k_prep_B<<<50,256,0,stream>>>(hw2_w,  Bf_h2, EH, EH);
  k_conv_f16<<<Mpad,256,0,stream>>>(x_e, xhA, N);
  // zero A1f16 pad rows once per call (gathers rewrite rows < N)
  if (Mpad > N)
    hipMemsetAsync(A1f16 + (size_t)N*320, 0, (size_t)(Mpad - N)*320*2, stream);

  int NB = 5 * Mtiles;
  int GW = cdiv(N, 4);   // wave-per-node grids

  // layer 1: x1 = highway(x_e, gcn(x_e)) -> xhA (f16 mirror only)
  k_gcn_gather<<<GW,256,0,stream>>>(offD, permD, srcA, xhA, dis, A1f16, N);
  k_dual_mfma<<<NB,256,0,stream>>>(A1f16, x_e, nullptr, Bf_g1, Bf_h1, hw1_b,
                                   nullptr, 0, xhA, 320, N);

  // layer 2: x2 = highway(x1, gcn(x1)) -> out cols 0:300 + xh2 cols 0:300
  k_gcn_gather<<<GW,256,0,stream>>>(offD, permD, srcA, xhA, dis, A1f16, N);
  k_dual_mfma<<<NB,256,0,stream>>>(A1f16, nullptr, xhA, Bf_g2, Bf_h2, hw2_b,
                                   out, 2000, xh2, 1024, N);

  // gat_r -> relEmb [2R,100]  (small; keep atomic path)
  k_dot2_small<<<cdiv(R,256),256,0,stream>>>(relEmb1, RH, RH, gatr_ai, gatr_aj, sR_i, sR_j, R, 0);
  hipMemsetAsync(relEmb, 0, (size_t)2*R*RH*4, stream);
  for (int g = 0; g < 2; g++){
    const int* lg = (g == 0) ? lgOut : lgIn;
    float* part = relEmb + (size_t)g * R * RH;
    hipMemsetAsync(mEncR, 0, (size_t)2*R*4, stream);   // mEncR + sumR contiguous
    k_edge_logit<<<cdiv(ELG,256),256,0,stream>>>(lg, lg + ELG, nullptr, sR_j, sR_i, nullptr,
                                                 eE, mEncR, ELG, 1);
    k_edge_exp<<<cdiv(ELG,256),256,0,stream>>>(lg, eE, mEncR, sumR, ELG);
    k_gatr_scatter<<<ELG,128,0,stream>>>(lg, lg + ELG, eE, sumR, relEmb1, part, RH);
  }
  k_relu_lin<<<cdiv(2*R*RH,256),256,0,stream>>>(relEmb, (long)2*R*RH);

  // relEmb >= 0 so lrelu is a no-op: one pass computes aRel (ww1 mid) and srr (gat_ar)
  k_dot2_small<<<cdiv(2*R,256),256,0,stream>>>(relEmb, RH, RH, ww1 + EH, gat_ar, aRel, srr, 2*R, 0);

  // wjq per-node logit dots over x2 (xh2 cols 0:300, lrelu applied)
  k_wave_dot2_h<<<cdiv(N,4),256,0,stream>>>(xh2, 1024, EH, ww1, ww1 + EH + RH, sxi, sxj, N, 1);

  // wjq: fused softmax + gather + head + gat-logit dots (gxi,gxj)
  k_wjq_gather<<<GW,256,0,stream>>>(offS, permS, dstA, relAll, sxi, sxj, aRel, relEmb,
                                    gat_ai, gat_aj, out, xh2, gxi, gxj, N);

  // gat: fused softmax + gather + relu
  k_gat_gather<<<GW,256,0,stream>>>(offD, permD, srcA, relAll, gxi, gxj, srr, xh2, out, N);
}

// Round 8
// 454.650 us; speedup vs baseline: 4.6005x; 1.1463x over previous
//
#include <hip/hip_runtime.h>
#include <math.h>

#define LSL 0.01f

typedef _Float16 half8 __attribute__((ext_vector_type(8)));
typedef _Float16 half2 __attribute__((ext_vector_type(2)));
typedef float floatx4 __attribute__((ext_vector_type(4)));

static __device__ __forceinline__ float lrelu_f(float x){ return x > 0.f ? x : LSL * x; }
static __device__ __forceinline__ void atomAddF(float* p, float v){ unsafeAtomicAdd(p, v); }

// monotone float <-> uint bijection so atomicMax(uint) == float max; 0 encodes < -inf
static __device__ __forceinline__ unsigned encF(float f){
  unsigned u = __float_as_uint(f);
  return (u & 0x80000000u) ? ~u : (u | 0x80000000u);
}
static __device__ __forceinline__ float decF(unsigned u){
  return (u & 0x80000000u) ? __uint_as_float(u & 0x7FFFFFFFu) : __uint_as_float(~u);
}

// ---------------- CSR build (fused) ----------------
__global__ void k_count2(const int* __restrict__ dstA, const int* __restrict__ srcA,
                         int* __restrict__ degD, int* __restrict__ degS, int E){
  int e = blockIdx.x * blockDim.x + threadIdx.x;
  if (e < E){ atomicAdd(degD + dstA[e], 1); atomicAdd(degS + srcA[e], 1); }
}

// two single-block exclusive scans in parallel (block 0 -> D, block 1 -> S)
__global__ void k_scan2(const int* __restrict__ cntD, int* __restrict__ offD,
                        const int* __restrict__ cntS, int* __restrict__ offS, int n){
  const int* cnt = blockIdx.x ? cntS : cntD;
  int* off = blockIdx.x ? offS : offD;
  __shared__ int wsum[4];
  __shared__ int carry;
  int t = threadIdx.x, lane = t & 63, wid = t >> 6;
  if (t == 0) carry = 0;
  __syncthreads();
  for (int base = 0; base < n; base += 256){
    int idx = base + t;
    int v = (idx < n) ? cnt[idx] : 0;
    int s = v;
    #pragma unroll
    for (int o = 1; o < 64; o <<= 1){
      int u = __shfl_up(s, o);
      if (lane >= o) s += u;
    }
    if (lane == 63) wsum[wid] = s;
    __syncthreads();
    int wo = 0;
    #pragma unroll
    for (int k = 0; k < 3; k++) wo += (k < wid) ? wsum[k] : 0;
    if (idx < n) off[idx] = carry + wo + s - v;
    int tot = wsum[0] + wsum[1] + wsum[2] + wsum[3];
    __syncthreads();
    if (t == 0) carry += tot;
    __syncthreads();
  }
  if (t == 0) off[n] = carry;
}

__global__ void k_fill2(const int* __restrict__ dstA, const int* __restrict__ srcA,
                        const int* __restrict__ offD, const int* __restrict__ offS,
                        int* __restrict__ curD, int* __restrict__ curS,
                        int* __restrict__ permD, int* __restrict__ permS, int E){
  int e = blockIdx.x * blockDim.x + threadIdx.x;
  if (e >= E) return;
  int i = dstA[e];
  permD[offD[i] + atomicAdd(curD + i, 1)] = e;
  int j = srcA[e];
  permS[offS[j] + atomicAdd(curS + j, 1)] = e;
}

__global__ void k_inv_sqrt_int(const int* __restrict__ deg, float* __restrict__ dis, int N){
  int v = blockIdx.x * blockDim.x + threadIdx.x;
  if (v < N){ int d = deg[v]; dis[v] = d > 0 ? rsqrtf((float)d) : 0.f; }
}

// x_e f32 [N][300] -> xh0 f16 [Mpad][320] zero-padded (cols 300:320, rows N:Mpad)
__global__ __launch_bounds__(256)
void k_conv_f16(const float* __restrict__ x, _Float16* __restrict__ xh, int N){
  int i = blockIdx.x, t = threadIdx.x;
  _Float16* o = xh + (size_t)i * 320;
  if (i < N){
    const float* r = x + (size_t)i * 300;
    o[t] = (_Float16)r[t];
    if (t < 44) o[t + 256] = (_Float16)r[t + 256];
    else if (t < 64) o[t + 256] = (_Float16)0.f;
  } else {
    o[t] = (_Float16)0.f;
    if (t < 64) o[t + 256] = (_Float16)0.f;
  }
}

// ---------------- CSR gathers: wave-per-node, register accumulate ----------------
// agg_f16[i][0:320] = relu(sum_e dis[i]*dis[j] * xh[j]); wave = node, lane<40 x half8
__global__ __launch_bounds__(256)
void k_gcn_gather(const int* __restrict__ off, const int* __restrict__ perm,
                  const int* __restrict__ src, const _Float16* __restrict__ x,
                  const float* __restrict__ dis, _Float16* __restrict__ agg, int N){
  int i = (int)(((long)blockIdx.x * blockDim.x + threadIdx.x) >> 6);
  int lane = threadIdx.x & 63;
  if (i >= N) return;
  int p0 = off[i], p1 = off[i+1];
  float di = dis[i];
  float acc[8] = {0.f,0.f,0.f,0.f,0.f,0.f,0.f,0.f};
  for (int base = p0; base < p1; base += 64){
    int m = min(64, p1 - base);
    int jj = 0; float wl = 0.f;
    if (base + lane < p1){
      int e = perm[base + lane];
      jj = src[e];
      wl = di * dis[jj];
    }
    for (int q = 0; q < m; q++){
      int j = __shfl(jj, q);
      float wt = __shfl(wl, q);
      if (lane < 40){
        half8 v = *(const half8*)(x + (size_t)j * 320 + 8*lane);
        #pragma unroll
        for (int k = 0; k < 8; k++) acc[k] += wt * (float)v[k];
      }
    }
  }
  if (lane < 40){
    half8 o;
    #pragma unroll
    for (int k = 0; k < 8; k++) o[k] = (_Float16)fmaxf(acc[k], 0.f);
    *(half8*)(agg + (size_t)i * 320 + 8*lane) = o;
  }
}

// ---------------- MFMA dual-GEMM + highway ----------------
// pack 4 weights W [300x300] f32 into fragment-ready f16 (one launch)
__global__ void k_prep_B4(const float* __restrict__ W0, const float* __restrict__ W1,
                          const float* __restrict__ W2, const float* __restrict__ W3,
                          _Float16* __restrict__ BfAll){
  int idx = blockIdx.x * 256 + threadIdx.x;
  if (idx >= 4*12800) return;
  int wsel = idx / 12800;
  int rem2 = idx % 12800;
  const float* W = (wsel == 0) ? W0 : (wsel == 1) ? W1 : (wsel == 2) ? W2 : W3;
  int lane = rem2 & 63;
  int rem = rem2 >> 6;
  int nf = rem & 3; rem >>= 2;
  int nt = rem % 5;
  int ks = rem / 5;
  int n = nt*64 + nf*16 + (lane & 15);
  int kb = ks*32 + (lane >> 4) * 8;
  _Float16* o = BfAll + (size_t)wsel * 102400 + (size_t)rem2 * 8;
  #pragma unroll
  for (int e = 0; e < 8; e++){
    int k = kb + e;
    float v = (k < 300 && n < 300) ? W[(size_t)k * 300 + n] : 0.f;
    o[e] = (_Float16)v;
  }
}

// O = sig(X@Wh + b) * (A1@Wg) + (1-sig)*X ; A1, Xh f16 [Mpad][320]
// 1-D grid, bijective XCD swizzle: 5 column-tile blocks of one A-panel co-resident per XCD.
__global__ __launch_bounds__(256)
void k_dual_mfma(const _Float16* __restrict__ A1, const _Float16* __restrict__ Xh,
                 const _Float16* __restrict__ Bf1, const _Float16* __restrict__ Bf2,
                 const float* __restrict__ bias, float* __restrict__ Of32, long ldo,
                 _Float16* __restrict__ Oh, long ldm, int M){
  int nb = gridDim.x;
  int q = nb >> 3, r = nb & 7;
  int xcd = blockIdx.x & 7, kk0 = blockIdx.x >> 3;
  int pseudo = (xcd < r ? xcd * (q + 1) : r * (q + 1) + (xcd - r) * q) + kk0;
  int nt = pseudo % 5;
  int panel = pseudo / 5;

  int tid = threadIdx.x;
  int w = tid >> 6, lane = tid & 63;
  int l15 = lane & 15, lg = lane >> 4;
  int rowBase = panel * 128 + w * 32;
  int colBase = nt * 64;

  floatx4 acc1[2][4], acc2[2][4];
  #pragma unroll
  for (int a = 0; a < 2; a++)
    #pragma unroll
    for (int b = 0; b < 4; b++){
      acc1[a][b] = (floatx4){0.f,0.f,0.f,0.f};
      acc2[a][b] = (floatx4){0.f,0.f,0.f,0.f};
    }

  int row0 = rowBase + l15, row1 = rowBase + 16 + l15;
  const _Float16* a1p0 = A1 + (size_t)row0 * 320;
  const _Float16* a1p1 = A1 + (size_t)row1 * 320;
  const _Float16* a2p0 = Xh + (size_t)row0 * 320;
  const _Float16* a2p1 = Xh + (size_t)row1 * 320;

  for (int ks = 0; ks < 10; ks++){
    int kA = ks*32 + lg*8;
    half8 a1f0 = *(const half8*)(a1p0 + kA);
    half8 a1f1 = *(const half8*)(a1p1 + kA);
    half8 a2f0 = *(const half8*)(a2p0 + kA);
    half8 a2f1 = *(const half8*)(a2p1 + kA);
    const half8* b1p = (const half8*)Bf1 + ((size_t)(ks*5 + nt) * 4 * 64 + lane);
    const half8* b2p = (const half8*)Bf2 + ((size_t)(ks*5 + nt) * 4 * 64 + lane);
    #pragma unroll
    for (int nf = 0; nf < 4; nf++){
      half8 b1 = b1p[nf*64];
      half8 b2 = b2p[nf*64];
      acc1[0][nf] = __builtin_amdgcn_mfma_f32_16x16x32_f16(a1f0, b1, acc1[0][nf], 0,0,0);
      acc1[1][nf] = __builtin_amdgcn_mfma_f32_16x16x32_f16(a1f1, b1, acc1[1][nf], 0,0,0);
      acc2[0][nf] = __builtin_amdgcn_mfma_f32_16x16x32_f16(a2f0, b2, acc2[0][nf], 0,0,0);
      acc2[1][nf] = __builtin_amdgcn_mfma_f32_16x16x32_f16(a2f1, b2, acc2[1][nf], 0,0,0);
    }
  }

  #pragma unroll
  for (int mf = 0; mf < 2; mf++){
    #pragma unroll
    for (int nf = 0; nf < 4; nf++){
      int gn = colBase + nf*16 + l15;
      int gnc = min(gn, 299);
      float bv = bias[gnc];
      #pragma unroll
      for (int r2 = 0; r2 < 4; r2++){
        int gm = rowBase + mf*16 + lg*4 + r2;
        int gmc = min(gm, M-1);
        float xv = (float)Xh[(size_t)gmc * 320 + gnc];
        float g = 1.f / (1.f + expf(-(acc2[mf][nf][r2] + bv)));
        float val = g * acc1[mf][nf][r2] + (1.f - g) * xv;
        if (gm < M && gn < 300){
          if (Of32) Of32[(size_t)gm * ldo + gn] = val;
          if (Oh)   Oh[(size_t)gm * ldm + gn] = (_Float16)val;
        }
      }
    }
  }
}

// wjq: wave-per-node (grouped by i=row0), fused softmax (single-pass logits for deg<=64)
// + gather + head + fused GAT logit dots gxi/gxj over the completed 1000-col row.
__global__ __launch_bounds__(256)
void k_wjq_gather(const int* __restrict__ off, const int* __restrict__ perm,
                  const int* __restrict__ dstA, const int* __restrict__ relI,
                  const float* __restrict__ sxi, const float* __restrict__ sxj,
                  const float* __restrict__ aRel, const float* __restrict__ relEmb,
                  const float* __restrict__ gat_ai, const float* __restrict__ gat_aj,
                  float* __restrict__ out, _Float16* __restrict__ xh2,
                  float* __restrict__ gxi, float* __restrict__ gxj, int N){
  int i = (int)(((long)blockIdx.x * blockDim.x + threadIdx.x) >> 6);
  int lane = threadIdx.x & 63;
  if (i >= N) return;
  int p0 = off[i], p1 = off[i+1];
  int deg = p1 - p0;
  float si = sxi[i];
  float accx[8] = {0.f,0.f,0.f,0.f,0.f,0.f,0.f,0.f};
  float accr[4] = {0.f,0.f,0.f,0.f};
  float sumA;

  if (deg <= 64){
    // single-pass: each lane owns one edge
    int jj = 0, rr = 0; float l = -3.4e38f;
    if (lane < deg){
      int e = perm[p0 + lane];
      jj = dstA[e]; rr = relI[e];
      l = si + sxj[jj] + aRel[rr];
    }
    float lm = l;
    #pragma unroll
    for (int o = 32; o > 0; o >>= 1) lm = fmaxf(lm, __shfl_xor(lm, o));
    float exl = (lane < deg) ? expf(l - lm) : 0.f;
    float ls = exl;
    #pragma unroll
    for (int o = 32; o > 0; o >>= 1) ls += __shfl_xor(ls, o);
    float inv = 1.f / (ls + 1e-16f);
    sumA = ls * inv;
    float wgt = exl * inv;
    for (int qe = 0; qe < deg; qe++){
      int j = __shfl(jj, qe);
      int r = __shfl(rr, qe);
      float al = __shfl(wgt, qe);
      if (lane < 38){
        half8 v = *(const half8*)(xh2 + (size_t)j * 1024 + 8*lane);  // cols>=300 garbage, never used
        #pragma unroll
        for (int k = 0; k < 8; k++) accx[k] += al * lrelu_f((float)v[k]);
      } else if (lane < 63){
        floatx4 v = *(const floatx4*)(relEmb + (size_t)r * 100 + 4*(lane - 38));
        #pragma unroll
        for (int k = 0; k < 4; k++) accr[k] += al * lrelu_f(v[k]);
      }
    }
  } else {
    // generic 3-pass path
    float lm = -3.4e38f;
    for (int p = p0 + lane; p < p1; p += 64){
      int e = perm[p];
      lm = fmaxf(lm, si + sxj[dstA[e]] + aRel[relI[e]]);
    }
    #pragma unroll
    for (int o = 32; o > 0; o >>= 1) lm = fmaxf(lm, __shfl_xor(lm, o));
    float ls = 0.f;
    for (int p = p0 + lane; p < p1; p += 64){
      int e = perm[p];
      ls += expf(si + sxj[dstA[e]] + aRel[relI[e]] - lm);
    }
    #pragma unroll
    for (int o = 32; o > 0; o >>= 1) ls += __shfl_xor(ls, o);
    float inv = 1.f / (ls + 1e-16f);
    sumA = ls * inv;
    for (int base = p0; base < p1; base += 64){
      int m = min(64, p1 - base);
      int jj = 0, rr = 0; float all = 0.f;
      if (base + lane < p1){
        int e = perm[base + lane];
        jj = dstA[e]; rr = relI[e];
        all = expf(si + sxj[jj] + aRel[rr] - lm) * inv;
      }
      for (int qe = 0; qe < m; qe++){
        int j = __shfl(jj, qe);
        int r = __shfl(rr, qe);
        float al = __shfl(all, qe);
        if (lane < 38){
          half8 v = *(const half8*)(xh2 + (size_t)j * 1024 + 8*lane);
          #pragma unroll
          for (int k = 0; k < 8; k++) accx[k] += al * lrelu_f((float)v[k]);
        } else if (lane < 63){
          floatx4 v = *(const floatx4*)(relEmb + (size_t)r * 100 + 4*(lane - 38));
          #pragma unroll
          for (int k = 0; k < 4; k++) accr[k] += al * lrelu_f(v[k]);
        }
      }
    }
  }

  // epilogue: write cols 600:1000, head 300:600; fused gxi/gxj dots over full row
  float* oi = out + (size_t)i * 2000;
  _Float16* hi = xh2 + (size_t)i * 1024;
  float dA = 0.f, dB = 0.f;
  if (lane < 38){
    #pragma unroll
    for (int k = 0; k < 8; k++){
      int c = 8*lane + k;
      if (c < 300){
        oi[700 + c] = accx[k]; hi[700 + c] = (_Float16)accx[k];
        dA += accx[k] * gat_ai[700 + c];
        dB += accx[k] * gat_aj[700 + c];
      }
    }
    half8 v = *(const half8*)(hi + 8*lane);   // x2 f16 (cols 0:300, written by dual_mfma)
    #pragma unroll
    for (int k = 0; k < 8; k++){
      int c = 8*lane + k;
      if (c < 300){
        float x2v = (float)v[k];
        float h = lrelu_f(x2v) * sumA;
        oi[300 + c] = h; hi[300 + c] = (_Float16)h;
        dA += x2v * gat_ai[c] + h * gat_ai[300 + c];
        dB += x2v * gat_aj[c] + h * gat_aj[300 + c];
      }
    }
  } else if (lane < 63){
    #pragma unroll
    for (int k = 0; k < 4; k++){
      int c = 4*(lane - 38) + k;
      oi[600 + c] = accr[k]; hi[600 + c] = (_Float16)accr[k];
      dA += accr[k] * gat_ai[600 + c];
      dB += accr[k] * gat_aj[600 + c];
    }
  }
  #pragma unroll
  for (int o = 32; o > 0; o >>= 1){
    dA += __shfl_xor(dA, o);
    dB += __shfl_xor(dB, o);
  }
  if (lane == 0){ gxi[i] = dA; gxj[i] = dB; }
}

// gat: TWO waves per node (512 cols each), fused softmax (single-pass for deg<=64) + gather + relu
__global__ __launch_bounds__(256)
void k_gat_gather(const int* __restrict__ off, const int* __restrict__ perm,
                  const int* __restrict__ srcA, const int* __restrict__ relI,
                  const float* __restrict__ gxi, const float* __restrict__ gxj,
                  const float* __restrict__ srr, const _Float16* __restrict__ xh2,
                  float* __restrict__ out, int N){
  long gw = ((long)blockIdx.x * blockDim.x + threadIdx.x) >> 6;
  int lane = threadIdx.x & 63;
  int i = (int)(gw >> 1), half = (int)(gw & 1);
  if (i >= N) return;
  int p0 = off[i], p1 = off[i+1];
  int deg = p1 - p0;
  float gi = gxi[i];
  int colBase = half * 512;
  int c0 = colBase + 8*lane;
  bool act = c0 < 1000;
  float acc[8] = {0.f,0.f,0.f,0.f,0.f,0.f,0.f,0.f};

  if (deg <= 64){
    int jj = 0; float l = -3.4e38f;
    if (lane < deg){
      int e = perm[p0 + lane];
      jj = srcA[e];
      l = lrelu_f(gi + gxj[jj] + srr[relI[e]]);
    }
    float lm = l;
    #pragma unroll
    for (int o = 32; o > 0; o >>= 1) lm = fmaxf(lm, __shfl_xor(lm, o));
    float exl = (lane < deg) ? expf(l - lm) : 0.f;
    float ls = exl;
    #pragma unroll
    for (int o = 32; o > 0; o >>= 1) ls += __shfl_xor(ls, o);
    float wgt = exl / (ls + 1e-16f);
    for (int qe = 0; qe < deg; qe++){
      int j = __shfl(jj, qe);
      float al = __shfl(wgt, qe);
      if (act){
        half8 v = *(const half8*)(xh2 + (size_t)j * 1024 + c0);
        #pragma unroll
        for (int k = 0; k < 8; k++) acc[k] += al * (float)v[k];
      }
    }
  } else {
    float lm = -3.4e38f;
    for (int p = p0 + lane; p < p1; p += 64){
      int e = perm[p];
      lm = fmaxf(lm, lrelu_f(gi + gxj[srcA[e]] + srr[relI[e]]));
    }
    #pragma unroll
    for (int o = 32; o > 0; o >>= 1) lm = fmaxf(lm, __shfl_xor(lm, o));
    float ls = 0.f;
    for (int p = p0 + lane; p < p1; p += 64){
      int e = perm[p];
      ls += expf(lrelu_f(gi + gxj[srcA[e]] + srr[relI[e]]) - lm);
    }
    #pragma unroll
    for (int o = 32; o > 0; o >>= 1) ls += __shfl_xor(ls, o);
    float inv = 1.f / (ls + 1e-16f);
    for (int base = p0; base < p1; base += 64){
      int m = min(64, p1 - base);
      int jj = 0; float all = 0.f;
      if (base + lane < p1){
        int e = perm[base + lane];
        jj = srcA[e];
        all = expf(lrelu_f(gi + gxj[jj] + srr[relI[e]]) - lm) * inv;
      }
      for (int qe = 0; qe < m; qe++){
        int j = __shfl(jj, qe);
        float al = __shfl(all, qe);
        if (act){
          half8 v = *(const half8*)(xh2 + (size_t)j * 1024 + c0);
          #pragma unroll
          for (int k = 0; k < 8; k++) acc[k] += al * (float)v[k];
        }
      }
    }
  }

  if (act){
    float* oi = out + (size_t)i * 2000 + 1000 + c0;
    floatx4 s0, s1;
    #pragma unroll
    for (int k = 0; k < 4; k++){ s0[k] = fmaxf(acc[k], 0.f); s1[k] = fmaxf(acc[4+k], 0.f); }
    *(floatx4*)(oi) = s0;
    *(floatx4*)(oi + 4) = s1;
  }
}

// ---------------- small kernels ----------------
__global__ void k_dot2_small(const float* __restrict__ X, int ld, int len,
                             const float* __restrict__ wA, const float* __restrict__ wB,
                             float* __restrict__ oA, float* __restrict__ oB,
                             int n, int applyL){
  int v = blockIdx.x * blockDim.x + threadIdx.x;
  if (v >= n) return;
  const float* row = X + (size_t)v * ld;
  float a = 0.f, b = 0.f;
  for (int c = 0; c < len; c++){
    float f = row[c];
    if (applyL) f = lrelu_f(f);
    a += f * wA[c];
    if (wB) b += f * wB[c];
  }
  oA[v] = a;
  if (oB) oB[v] = b;
}

// relu relEmb in place + two dots (ww1 mid, gat_ar)
__global__ void k_relu_dots(float* __restrict__ relEmb, const float* __restrict__ wA,
                            const float* __restrict__ wB, float* __restrict__ aRel,
                            float* __restrict__ srr, int n){
  int v = blockIdx.x * blockDim.x + threadIdx.x;
  if (v >= n) return;
  float* row = relEmb + (size_t)v * 100;
  float a = 0.f, b = 0.f;
  for (int c = 0; c < 100; c++){
    float f = fmaxf(row[c], 0.f);
    row[c] = f;
    a += f * wA[c];
    b += f * wB[c];
  }
  aRel[v] = a;
  srr[v] = b;
}

// wave-per-row dual dot over f16 rows
__global__ void k_wave_dot2_h(const _Float16* __restrict__ X, long ld, int len,
                              const float* __restrict__ wA, const float* __restrict__ wB,
                              float* __restrict__ oA, float* __restrict__ oB,
                              int n, int applyL){
  int gw = (int)(((long)blockIdx.x * blockDim.x + threadIdx.x) >> 6);
  int lane = threadIdx.x & 63;
  if (gw >= n) return;
  const _Float16* row = X + (size_t)gw * ld;
  float a = 0.f, b = 0.f;
  for (int c = lane*2; c < len; c += 128){
    half2 v = *(const half2*)(row + c);
    float f0 = (float)v[0], f1 = (float)v[1];
    if (applyL){ f0 = lrelu_f(f0); f1 = lrelu_f(f1); }
    a += f0 * wA[c] + f1 * wA[c+1];
    b += f0 * wB[c] + f1 * wB[c+1];
  }
  #pragma unroll
  for (int o = 32; o > 0; o >>= 1){
    a += __shfl_down(a, o);
    b += __shfl_down(b, o);
  }
  if (lane == 0){ oA[gw] = a; oB[gw] = b; }
}

// ---- merged line-graph (gat_r) chain: both graphs in one pass each ----
__global__ void k_lg_logit(const int* __restrict__ lgOut, const int* __restrict__ lgIn,
                           int ELG, int R, const float* __restrict__ sR_i,
                           const float* __restrict__ sR_j,
                           float* __restrict__ elog, unsigned* __restrict__ mEnc){
  int e = blockIdx.x * blockDim.x + threadIdx.x;
  if (e >= 2*ELG) return;
  int g = e >= ELG;
  int el = e - g*ELG;
  const int* lg = g ? lgIn : lgOut;
  int j = lg[el], i = lg[el + ELG];
  float v = lrelu_f(sR_j[j] + sR_i[i]);
  elog[e] = v;
  atomicMax(mEnc + g*R + j, encF(v));
}

__global__ void k_lg_exp(const int* __restrict__ lgOut, const int* __restrict__ lgIn,
                         int ELG, int R, float* __restrict__ elog,
                         const unsigned* __restrict__ mEnc, float* __restrict__ sumR){
  int e = blockIdx.x * blockDim.x + threadIdx.x;
  if (e >= 2*ELG) return;
  int g = e >= ELG;
  int el = e - g*ELG;
  const int* lg = g ? lgIn : lgOut;
  int j = lg[el];
  float ex = expf(elog[e] - decF(mEnc[g*R + j]));
  elog[e] = ex;
  atomAddF(sumR + g*R + j, ex);
}

__global__ void k_lg_scatter(const int* __restrict__ lgOut, const int* __restrict__ lgIn,
                             int ELG, int R, const float* __restrict__ ex,
                             const float* __restrict__ sumR,
                             const float* __restrict__ relEmb1, float* __restrict__ relEmb){
  int e = blockIdx.x;
  int g = e >= ELG;
  int el = e - g*ELG;
  const int* lg = g ? lgIn : lgOut;
  int j = lg[el], i = lg[el + ELG];
  float alpha = ex[e] / (sumR[g*R + j] + 1e-16f);
  const float* xj = relEmb1 + (size_t)j * 100;
  float* oi = relEmb + (size_t)(g*R + i) * 100;
  for (int c = threadIdx.x; c < 100; c += blockDim.x)
    atomAddF(oi + c, alpha * xj[c]);
}

extern "C" void kernel_launch(void* const* d_in, const int* in_sizes, int n_in,
                              void* d_out, int out_size, void* d_ws, size_t ws_size,
                              hipStream_t stream){
  const float* x_e     = (const float*)d_in[0];
  const int*   eiA     = (const int*)  d_in[3];   // edge_index_all [2,E]
  const int*   relAll  = (const int*)  d_in[4];
  const int*   lgOut   = (const int*)  d_in[5];
  const int*   lgIn    = (const int*)  d_in[7];
  const float* gcn1_w  = (const float*)d_in[9];
  const float* gcn2_w  = (const float*)d_in[10];
  const float* hw1_w   = (const float*)d_in[11];
  const float* hw1_b   = (const float*)d_in[12];
  const float* hw2_w   = (const float*)d_in[13];
  const float* hw2_b   = (const float*)d_in[14];
  const float* ww1     = (const float*)d_in[15];
  const float* gat_ai  = (const float*)d_in[16];
  const float* gat_aj  = (const float*)d_in[17];
  const float* gat_ar  = (const float*)d_in[18];
  const float* gatr_ai = (const float*)d_in[19];
  const float* gatr_aj = (const float*)d_in[20];
  const float* relEmb1 = (const float*)d_in[21];

  const int EH = 300, RH = 100;
  const int N   = in_sizes[0] / EH;
  const int E   = in_sizes[3] / 2;
  const int ELG = in_sizes[5] / 2;
  const int R   = in_sizes[21] / RH;
  const int Mtiles = (N + 127) / 128;
  const int Mpad = Mtiles * 128;

  // ---- workspace layout (16B-aligned f16 blocks first) ----
  char* base = (char*)d_ws;
  _Float16* xh0   = (_Float16*)base;  base += (size_t)Mpad * 320 * 2;   // x_e f16
  _Float16* xhA   = (_Float16*)base;  base += (size_t)Mpad * 320 * 2;   // x1 f16
  _Float16* A1f16 = (_Float16*)base;  base += (size_t)Mpad * 320 * 2;   // relu(agg) f16
  _Float16* xh2   = (_Float16*)base;  base += (size_t)N * 1024 * 2;     // x_wjq f16 mirror
  _Float16* BfAll = (_Float16*)base;  base += (size_t)4 * 102400 * 2;
  float* w = (float*)base;
  float* dis    = w; w += N;
  float* relEmb = w; w += (size_t)2 * R * RH;
  float* sxi    = w; w += N;
  float* sxj    = w; w += N;
  float* gxi    = w; w += N;
  float* gxj    = w; w += N;
  float* sR_i   = w; w += R;
  float* sR_j   = w; w += R;
  unsigned* mEncR = (unsigned*)w; w += 2 * R;   // mEncR (2R) then sumR (2R), contiguous
  float* sumR   = w; w += 2 * R;
  float* aRel   = w; w += 2 * R;
  float* srr    = w; w += 2 * R;
  float* eE     = w; w += E;
  int* degD   = (int*)w; w += N;
  int* degS   = (int*)w; w += N;
  int* curD   = (int*)w; w += N;
  int* curS   = (int*)w; w += N;
  int* offD   = (int*)w; w += N + 1;
  int* offS   = (int*)w; w += N + 1;
  int* permD  = (int*)w; w += E;
  int* permS  = (int*)w; w += E;

  _Float16* Bf_g1 = BfAll;
  _Float16* Bf_h1 = BfAll + 102400;
  _Float16* Bf_g2 = BfAll + 2 * 102400;
  _Float16* Bf_h2 = BfAll + 3 * 102400;

  float* out = (float*)d_out;
  const int* srcA = eiA;         // row0 (j in gcn/gat, i in wjq)
  const int* dstA = eiA + E;     // row1

  auto cdiv = [](int a, int b){ return (a + b - 1) / b; };

  // ---- fused CSR build (dst grouping + src grouping) ----
  hipMemsetAsync(degD, 0, (size_t)4 * N * 4, stream);   // degD,degS,curD,curS contiguous
  k_count2<<<cdiv(E,256),256,0,stream>>>(dstA, srcA, degD, degS, E);
  k_scan2<<<2,256,0,stream>>>(degD, offD, degS, offS, N);
  k_fill2<<<cdiv(E,256),256,0,stream>>>(dstA, srcA, offD, offS, curD, curS, permD, permS, E);
  k_inv_sqrt_int<<<cdiv(N,256),256,0,stream>>>(degD, dis, N);

  // ---- pack weights (one launch); convert x_e to f16 ----
  k_prep_B4<<<200,256,0,stream>>>(gcn1_w, hw1_w, gcn2_w, hw2_w, BfAll);
  k_conv_f16<<<Mpad,256,0,stream>>>(x_e, xh0, N);

  int NB = 5 * Mtiles;
  int GW = cdiv(N, 4);   // wave-per-node grids

  // layer 1: x1 = highway(x_e, gcn(x_e)) -> xhA (f16 mirror only)
  k_gcn_gather<<<GW,256,0,stream>>>(offD, permD, srcA, xh0, dis, A1f16, N);
  k_dual_mfma<<<NB,256,0,stream>>>(A1f16, xh0, Bf_g1, Bf_h1, hw1_b,
                                   nullptr, 0, xhA, 320, N);

  // layer 2: x2 = highway(x1, gcn(x1)) -> out cols 0:300 + xh2 cols 0:300
  k_gcn_gather<<<GW,256,0,stream>>>(offD, permD, srcA, xhA, dis, A1f16, N);
  k_dual_mfma<<<NB,256,0,stream>>>(A1f16, xhA, Bf_g2, Bf_h2, hw2_b,
                                   out, 2000, xh2, 1024, N);

  // gat_r -> relEmb [2R,100]  (merged out/in graphs, atomic path)
  k_dot2_small<<<cdiv(R,256),256,0,stream>>>(relEmb1, RH, RH, gatr_ai, gatr_aj, sR_i, sR_j, R, 0);
  hipMemsetAsync(relEmb, 0, (size_t)2*R*RH*4, stream);
  hipMemsetAsync(mEncR, 0, (size_t)4*R*4, stream);   // mEncR + sumR contiguous
  k_lg_logit<<<cdiv(2*ELG,256),256,0,stream>>>(lgOut, lgIn, ELG, R, sR_i, sR_j, eE, mEncR);
  k_lg_exp<<<cdiv(2*ELG,256),256,0,stream>>>(lgOut, lgIn, ELG, R, eE, mEncR, sumR);
  k_lg_scatter<<<2*ELG,128,0,stream>>>(lgOut, lgIn, ELG, R, eE, sumR, relEmb1, relEmb);

  // relu relEmb + aRel (ww1 mid) + srr (gat_ar) in one pass
  k_relu_dots<<<cdiv(2*R,256),256,0,stream>>>(relEmb, ww1 + EH, gat_ar, aRel, srr, 2*R);

  // wjq per-node logit dots over x2 (xh2 cols 0:300, lrelu applied)
  k_wave_dot2_h<<<cdiv(N,4),256,0,stream>>>(xh2, 1024, EH, ww1, ww1 + EH + RH, sxi, sxj, N, 1);

  // wjq: fused softmax + gather + head + gat-logit dots (gxi,gxj)
  k_wjq_gather<<<GW,256,0,stream>>>(offS, permS, dstA, relAll, sxi, sxj, aRel, relEmb,
                                    gat_ai, gat_aj, out, xh2, gxi, gxj, N);

  // gat: fused softmax + gather + relu, 2 waves/node
  k_gat_gather<<<cdiv(N,2),256,0,stream>>>(offD, permD, srcA, relAll, gxi, gxj, srr, xh2, out, N);
}

// Round 9
// 404.100 us; speedup vs baseline: 5.1760x; 1.1251x over previous
//
#include <hip/hip_runtime.h>
#include <math.h>

#define LSL 0.01f

typedef _Float16 half8 __attribute__((ext_vector_type(8)));
typedef _Float16 half2 __attribute__((ext_vector_type(2)));
typedef float floatx4 __attribute__((ext_vector_type(4)));

static __device__ __forceinline__ float lrelu_f(float x){ return x > 0.f ? x : LSL * x; }
static __device__ __forceinline__ void atomAddF(float* p, float v){ unsafeAtomicAdd(p, v); }

// monotone float <-> uint bijection so atomicMax(uint) == float max; 0 encodes < -inf
static __device__ __forceinline__ unsigned encF(float f){
  unsigned u = __float_as_uint(f);
  return (u & 0x80000000u) ? ~u : (u | 0x80000000u);
}
static __device__ __forceinline__ float decF(unsigned u){
  return (u & 0x80000000u) ? __uint_as_float(u & 0x7FFFFFFFu) : __uint_as_float(~u);
}

// ---------------- CSR build (fused) ----------------
__global__ void k_count2(const int* __restrict__ dstA, const int* __restrict__ srcA,
                         int* __restrict__ degD, int* __restrict__ degS, int E){
  int e = blockIdx.x * blockDim.x + threadIdx.x;
  if (e < E){ atomicAdd(degD + dstA[e], 1); atomicAdd(degS + srcA[e], 1); }
}

// two exclusive scans (block 0 -> D, block 1 -> S), 1024 threads, strip-per-thread
__global__ __launch_bounds__(1024)
void k_scan2(const int* __restrict__ cntD, int* __restrict__ offD,
             const int* __restrict__ cntS, int* __restrict__ offS, int n){
  const int* cnt = blockIdx.x ? cntS : cntD;
  int* off = blockIdx.x ? offS : offD;
  int t = threadIdx.x, lane = t & 63, wid = t >> 6;   // 16 waves
  int len = (n + 1023) >> 10;
  int lo = t * len, hi = min(lo + len, n);
  int s = 0;
  for (int k = lo; k < hi; k++) s += cnt[k];
  // block exclusive scan over 1024 thread sums
  int ws = s;
  #pragma unroll
  for (int o = 1; o < 64; o <<= 1){
    int u = __shfl_up(ws, o);
    if (lane >= o) ws += u;
  }
  __shared__ int wtot[16];
  if (lane == 63) wtot[wid] = ws;
  __syncthreads();
  int wpre = 0;
  #pragma unroll
  for (int k2 = 0; k2 < 16; k2++) wpre += (k2 < wid) ? wtot[k2] : 0;
  int run = wpre + ws - s;   // exclusive prefix for this thread's strip
  for (int k = lo; k < hi; k++){ off[k] = run; run += cnt[k]; }
  if (t == 0){
    int tot = 0;
    #pragma unroll
    for (int k2 = 0; k2 < 16; k2++) tot += wtot[k2];
    off[n] = tot;
  }
}

__global__ void k_fill2(const int* __restrict__ dstA, const int* __restrict__ srcA,
                        const int* __restrict__ offD, const int* __restrict__ offS,
                        int* __restrict__ curD, int* __restrict__ curS,
                        int* __restrict__ permD, int* __restrict__ permS, int E){
  int e = blockIdx.x * blockDim.x + threadIdx.x;
  if (e >= E) return;
  int i = dstA[e];
  permD[offD[i] + atomicAdd(curD + i, 1)] = e;
  int j = srcA[e];
  permS[offS[j] + atomicAdd(curS + j, 1)] = e;
}

__global__ void k_inv_sqrt_int(const int* __restrict__ deg, float* __restrict__ dis, int N){
  int v = blockIdx.x * blockDim.x + threadIdx.x;
  if (v < N){ int d = deg[v]; dis[v] = d > 0 ? rsqrtf((float)d) : 0.f; }
}

// x_e f32 [N][300] -> xh0 f16 [Mpad][320] zero-padded (cols 300:320, rows N:Mpad)
__global__ __launch_bounds__(256)
void k_conv_f16(const float* __restrict__ x, _Float16* __restrict__ xh, int N){
  int i = blockIdx.x, t = threadIdx.x;
  _Float16* o = xh + (size_t)i * 320;
  if (i < N){
    const float* r = x + (size_t)i * 300;
    o[t] = (_Float16)r[t];
    if (t < 44) o[t + 256] = (_Float16)r[t + 256];
    else if (t < 64) o[t + 256] = (_Float16)0.f;
  } else {
    o[t] = (_Float16)0.f;
    if (t < 64) o[t + 256] = (_Float16)0.f;
  }
}

// ---------------- CSR gathers: wave-per-node, register accumulate ----------------
// agg_f16[i][0:320] = relu(sum_e dis[i]*dis[j] * xh[j]); wave = node, lane<40 x half8
__global__ __launch_bounds__(256)
void k_gcn_gather(const int* __restrict__ off, const int* __restrict__ perm,
                  const int* __restrict__ src, const _Float16* __restrict__ x,
                  const float* __restrict__ dis, _Float16* __restrict__ agg, int N){
  int i = (int)(((long)blockIdx.x * blockDim.x + threadIdx.x) >> 6);
  int lane = threadIdx.x & 63;
  if (i >= N) return;
  int p0 = off[i], p1 = off[i+1];
  float di = dis[i];
  float acc[8] = {0.f,0.f,0.f,0.f,0.f,0.f,0.f,0.f};
  for (int base = p0; base < p1; base += 64){
    int m = min(64, p1 - base);
    int jj = 0; float wl = 0.f;
    if (base + lane < p1){
      int e = perm[base + lane];
      jj = src[e];
      wl = di * dis[jj];
    }
    int q = 0;
    for (; q + 1 < m; q += 2){
      int j0 = __shfl(jj, q),   j1 = __shfl(jj, q+1);
      float w0 = __shfl(wl, q), w1 = __shfl(wl, q+1);
      if (lane < 40){
        half8 v0 = *(const half8*)(x + (size_t)j0 * 320 + 8*lane);
        half8 v1 = *(const half8*)(x + (size_t)j1 * 320 + 8*lane);
        #pragma unroll
        for (int k = 0; k < 8; k++) acc[k] += w0 * (float)v0[k] + w1 * (float)v1[k];
      }
    }
    if (q < m){
      int j0 = __shfl(jj, q);
      float w0 = __shfl(wl, q);
      if (lane < 40){
        half8 v0 = *(const half8*)(x + (size_t)j0 * 320 + 8*lane);
        #pragma unroll
        for (int k = 0; k < 8; k++) acc[k] += w0 * (float)v0[k];
      }
    }
  }
  if (lane < 40){
    half8 o;
    #pragma unroll
    for (int k = 0; k < 8; k++) o[k] = (_Float16)fmaxf(acc[k], 0.f);
    *(half8*)(agg + (size_t)i * 320 + 8*lane) = o;
  }
}

// ---------------- MFMA dual-GEMM + highway ----------------
// pack 4 weights W [300x300] f32 into fragment-ready f16 (one launch)
__global__ void k_prep_B4(const float* __restrict__ W0, const float* __restrict__ W1,
                          const float* __restrict__ W2, const float* __restrict__ W3,
                          _Float16* __restrict__ BfAll){
  int idx = blockIdx.x * 256 + threadIdx.x;
  if (idx >= 4*12800) return;
  int wsel = idx / 12800;
  int rem2 = idx % 12800;
  const float* W = (wsel == 0) ? W0 : (wsel == 1) ? W1 : (wsel == 2) ? W2 : W3;
  int lane = rem2 & 63;
  int rem = rem2 >> 6;
  int nf = rem & 3; rem >>= 2;
  int nt = rem % 5;
  int ks = rem / 5;
  int n = nt*64 + nf*16 + (lane & 15);
  int kb = ks*32 + (lane >> 4) * 8;
  _Float16* o = BfAll + (size_t)wsel * 102400 + (size_t)rem2 * 8;
  #pragma unroll
  for (int e = 0; e < 8; e++){
    int k = kb + e;
    float v = (k < 300 && n < 300) ? W[(size_t)k * 300 + n] : 0.f;
    o[e] = (_Float16)v;
  }
}

// O = sig(X@Wh + b) * (A1@Wg) + (1-sig)*X ; A1, Xh f16 [Mpad][320]
// 16 rows/wave, 64-row panels (2x parallelism vs 128-row); 1-D grid, bijective
// XCD swizzle so the 5 column-tile blocks of one panel co-reside on one XCD.
__global__ __launch_bounds__(256)
void k_dual_mfma(const _Float16* __restrict__ A1, const _Float16* __restrict__ Xh,
                 const _Float16* __restrict__ Bf1, const _Float16* __restrict__ Bf2,
                 const float* __restrict__ bias, float* __restrict__ Of32, long ldo,
                 _Float16* __restrict__ Oh, long ldm, int M){
  int nb = gridDim.x;
  int q = nb >> 3, r = nb & 7;
  int xcd = blockIdx.x & 7, kk0 = blockIdx.x >> 3;
  int pseudo = (xcd < r ? xcd * (q + 1) : r * (q + 1) + (xcd - r) * q) + kk0;
  int nt = pseudo % 5;
  int panel = pseudo / 5;   // 64-row panel

  int tid = threadIdx.x;
  int w = tid >> 6, lane = tid & 63;
  int l15 = lane & 15, lg = lane >> 4;
  int rowBase = panel * 64 + w * 16;
  int colBase = nt * 64;

  floatx4 acc1[4], acc2[4];
  #pragma unroll
  for (int b = 0; b < 4; b++){
    acc1[b] = (floatx4){0.f,0.f,0.f,0.f};
    acc2[b] = (floatx4){0.f,0.f,0.f,0.f};
  }

  int row0 = rowBase + l15;
  const _Float16* a1p0 = A1 + (size_t)row0 * 320;
  const _Float16* a2p0 = Xh + (size_t)row0 * 320;

  for (int ks = 0; ks < 10; ks++){
    int kA = ks*32 + lg*8;
    half8 a1f0 = *(const half8*)(a1p0 + kA);
    half8 a2f0 = *(const half8*)(a2p0 + kA);
    const half8* b1p = (const half8*)Bf1 + ((size_t)(ks*5 + nt) * 4 * 64 + lane);
    const half8* b2p = (const half8*)Bf2 + ((size_t)(ks*5 + nt) * 4 * 64 + lane);
    #pragma unroll
    for (int nf = 0; nf < 4; nf++){
      half8 b1 = b1p[nf*64];
      half8 b2 = b2p[nf*64];
      acc1[nf] = __builtin_amdgcn_mfma_f32_16x16x32_f16(a1f0, b1, acc1[nf], 0,0,0);
      acc2[nf] = __builtin_amdgcn_mfma_f32_16x16x32_f16(a2f0, b2, acc2[nf], 0,0,0);
    }
  }

  #pragma unroll
  for (int nf = 0; nf < 4; nf++){
    int gn = colBase + nf*16 + l15;
    int gnc = min(gn, 299);
    float bv = bias[gnc];
    #pragma unroll
    for (int r2 = 0; r2 < 4; r2++){
      int gm = rowBase + lg*4 + r2;
      int gmc = min(gm, M-1);
      float xv = (float)Xh[(size_t)gmc * 320 + gnc];
      float g = 1.f / (1.f + expf(-(acc2[nf][r2] + bv)));
      float val = g * acc1[nf][r2] + (1.f - g) * xv;
      if (gm < M && gn < 300){
        if (Of32) Of32[(size_t)gm * ldo + gn] = val;
        if (Oh)   Oh[(size_t)gm * ldm + gn] = (_Float16)val;
      }
    }
  }
}

// wjq: wave-per-node (grouped by i=row0), fused softmax (single-pass logits for deg<=64)
// + gather + head + fused GAT logit dots gxi/gxj over the completed 1000-col row.
__global__ __launch_bounds__(256)
void k_wjq_gather(const int* __restrict__ off, const int* __restrict__ perm,
                  const int* __restrict__ dstA, const int* __restrict__ relI,
                  const float* __restrict__ sxi, const float* __restrict__ sxj,
                  const float* __restrict__ aRel, const float* __restrict__ relEmb,
                  const float* __restrict__ gat_ai, const float* __restrict__ gat_aj,
                  float* __restrict__ out, _Float16* __restrict__ xh2,
                  float* __restrict__ gxi, float* __restrict__ gxj, int N){
  int i = (int)(((long)blockIdx.x * blockDim.x + threadIdx.x) >> 6);
  int lane = threadIdx.x & 63;
  if (i >= N) return;
  int p0 = off[i], p1 = off[i+1];
  int deg = p1 - p0;
  float si = sxi[i];
  float accx[8] = {0.f,0.f,0.f,0.f,0.f,0.f,0.f,0.f};
  float accr[4] = {0.f,0.f,0.f,0.f};
  float sumA;

  if (deg <= 64){
    // single-pass: each lane owns one edge
    int jj = 0, rr = 0; float l = -3.4e38f;
    if (lane < deg){
      int e = perm[p0 + lane];
      jj = dstA[e]; rr = relI[e];
      l = si + sxj[jj] + aRel[rr];
    }
    float lm = l;
    #pragma unroll
    for (int o = 32; o > 0; o >>= 1) lm = fmaxf(lm, __shfl_xor(lm, o));
    float exl = (lane < deg) ? expf(l - lm) : 0.f;
    float ls = exl;
    #pragma unroll
    for (int o = 32; o > 0; o >>= 1) ls += __shfl_xor(ls, o);
    float inv = 1.f / (ls + 1e-16f);
    sumA = ls * inv;
    float wgt = exl * inv;
    int qe = 0;
    for (; qe + 1 < deg; qe += 2){
      int j0 = __shfl(jj, qe),  j1 = __shfl(jj, qe+1);
      int r0 = __shfl(rr, qe),  r1 = __shfl(rr, qe+1);
      float a0 = __shfl(wgt, qe), a1 = __shfl(wgt, qe+1);
      if (lane < 38){
        half8 v0 = *(const half8*)(xh2 + (size_t)j0 * 1024 + 8*lane);
        half8 v1 = *(const half8*)(xh2 + (size_t)j1 * 1024 + 8*lane);
        #pragma unroll
        for (int k = 0; k < 8; k++)
          accx[k] += a0 * lrelu_f((float)v0[k]) + a1 * lrelu_f((float)v1[k]);
      } else if (lane < 63){
        floatx4 v0 = *(const floatx4*)(relEmb + (size_t)r0 * 100 + 4*(lane - 38));
        floatx4 v1 = *(const floatx4*)(relEmb + (size_t)r1 * 100 + 4*(lane - 38));
        #pragma unroll
        for (int k = 0; k < 4; k++)
          accr[k] += a0 * lrelu_f(v0[k]) + a1 * lrelu_f(v1[k]);
      }
    }
    if (qe < deg){
      int j0 = __shfl(jj, qe);
      int r0 = __shfl(rr, qe);
      float a0 = __shfl(wgt, qe);
      if (lane < 38){
        half8 v0 = *(const half8*)(xh2 + (size_t)j0 * 1024 + 8*lane);
        #pragma unroll
        for (int k = 0; k < 8; k++) accx[k] += a0 * lrelu_f((float)v0[k]);
      } else if (lane < 63){
        floatx4 v0 = *(const floatx4*)(relEmb + (size_t)r0 * 100 + 4*(lane - 38));
        #pragma unroll
        for (int k = 0; k < 4; k++) accr[k] += a0 * lrelu_f(v0[k]);
      }
    }
  } else {
    // generic 3-pass path
    float lm = -3.4e38f;
    for (int p = p0 + lane; p < p1; p += 64){
      int e = perm[p];
      lm = fmaxf(lm, si + sxj[dstA[e]] + aRel[relI[e]]);
    }
    #pragma unroll
    for (int o = 32; o > 0; o >>= 1) lm = fmaxf(lm, __shfl_xor(lm, o));
    float ls = 0.f;
    for (int p = p0 + lane; p < p1; p += 64){
      int e = perm[p];
      ls += expf(si + sxj[dstA[e]] + aRel[relI[e]] - lm);
    }
    #pragma unroll
    for (int o = 32; o > 0; o >>= 1) ls += __shfl_xor(ls, o);
    float inv = 1.f / (ls + 1e-16f);
    sumA = ls * inv;
    for (int base = p0; base < p1; base += 64){
      int m = min(64, p1 - base);
      int jj = 0, rr = 0; float all = 0.f;
      if (base + lane < p1){
        int e = perm[base + lane];
        jj = dstA[e]; rr = relI[e];
        all = expf(si + sxj[jj] + aRel[rr] - lm) * inv;
      }
      for (int qe = 0; qe < m; qe++){
        int j = __shfl(jj, qe);
        int r = __shfl(rr, qe);
        float al = __shfl(all, qe);
        if (lane < 38){
          half8 v = *(const half8*)(xh2 + (size_t)j * 1024 + 8*lane);
          #pragma unroll
          for (int k = 0; k < 8; k++) accx[k] += al * lrelu_f((float)v[k]);
        } else if (lane < 63){
          floatx4 v = *(const floatx4*)(relEmb + (size_t)r * 100 + 4*(lane - 38));
          #pragma unroll
          for (int k = 0; k < 4; k++) accr[k] += al * lrelu_f(v[k]);
        }
      }
    }
  }

  // epilogue: write cols 600:1000, head 300:600; fused gxi/gxj dots over full row
  float* oi = out + (size_t)i * 2000;
  _Float16* hi = xh2 + (size_t)i * 1024;
  float dA = 0.f, dB = 0.f;
  if (lane < 38){
    #pragma unroll
    for (int k = 0; k < 8; k++){
      int c = 8*lane + k;
      if (c < 300){
        oi[700 + c] = accx[k]; hi[700 + c] = (_Float16)accx[k];
        dA += accx[k] * gat_ai[700 + c];
        dB += accx[k] * gat_aj[700 + c];
      }
    }
    half8 v = *(const half8*)(hi + 8*lane);   // x2 f16 (cols 0:300, written by dual_mfma)
    #pragma unroll
    for (int k = 0; k < 8; k++){
      int c = 8*lane + k;
      if (c < 300){
        float x2v = (float)v[k];
        float h = lrelu_f(x2v) * sumA;
        oi[300 + c] = h; hi[300 + c] = (_Float16)h;
        dA += x2v * gat_ai[c] + h * gat_ai[300 + c];
        dB += x2v * gat_aj[c] + h * gat_aj[300 + c];
      }
    }
  } else if (lane < 63){
    #pragma unroll
    for (int k = 0; k < 4; k++){
      int c = 4*(lane - 38) + k;
      oi[600 + c] = accr[k]; hi[600 + c] = (_Float16)accr[k];
      dA += accr[k] * gat_ai[600 + c];
      dB += accr[k] * gat_aj[600 + c];
    }
  }
  #pragma unroll
  for (int o = 32; o > 0; o >>= 1){
    dA += __shfl_xor(dA, o);
    dB += __shfl_xor(dB, o);
  }
  if (lane == 0){ gxi[i] = dA; gxj[i] = dB; }
}

// gat: TWO waves per node (512 cols each), fused softmax (single-pass for deg<=64) + gather + relu
__global__ __launch_bounds__(256)
void k_gat_gather(const int* __restrict__ off, const int* __restrict__ perm,
                  const int* __restrict__ srcA, const int* __restrict__ relI,
                  const float* __restrict__ gxi, const float* __restrict__ gxj,
                  const float* __restrict__ srr, const _Float16* __restrict__ xh2,
                  float* __restrict__ out, int N){
  long gw = ((long)blockIdx.x * blockDim.x + threadIdx.x) >> 6;
  int lane = threadIdx.x & 63;
  int i = (int)(gw >> 1), half = (int)(gw & 1);
  if (i >= N) return;
  int p0 = off[i], p1 = off[i+1];
  int deg = p1 - p0;
  float gi = gxi[i];
  int colBase = half * 512;
  int c0 = colBase + 8*lane;
  bool act = c0 < 1000;
  float acc[8] = {0.f,0.f,0.f,0.f,0.f,0.f,0.f,0.f};

  if (deg <= 64){
    int jj = 0; float l = -3.4e38f;
    if (lane < deg){
      int e = perm[p0 + lane];
      jj = srcA[e];
      l = lrelu_f(gi + gxj[jj] + srr[relI[e]]);
    }
    float lm = l;
    #pragma unroll
    for (int o = 32; o > 0; o >>= 1) lm = fmaxf(lm, __shfl_xor(lm, o));
    float exl = (lane < deg) ? expf(l - lm) : 0.f;
    float ls = exl;
    #pragma unroll
    for (int o = 32; o > 0; o >>= 1) ls += __shfl_xor(ls, o);
    float wgt = exl / (ls + 1e-16f);
    int qe = 0;
    for (; qe + 1 < deg; qe += 2){
      int j0 = __shfl(jj, qe),    j1 = __shfl(jj, qe+1);
      float a0 = __shfl(wgt, qe), a1 = __shfl(wgt, qe+1);
      if (act){
        half8 v0 = *(const half8*)(xh2 + (size_t)j0 * 1024 + c0);
        half8 v1 = *(const half8*)(xh2 + (size_t)j1 * 1024 + c0);
        #pragma unroll
        for (int k = 0; k < 8; k++) acc[k] += a0 * (float)v0[k] + a1 * (float)v1[k];
      }
    }
    if (qe < deg){
      int j0 = __shfl(jj, qe);
      float a0 = __shfl(wgt, qe);
      if (act){
        half8 v0 = *(const half8*)(xh2 + (size_t)j0 * 1024 + c0);
        #pragma unroll
        for (int k = 0; k < 8; k++) acc[k] += a0 * (float)v0[k];
      }
    }
  } else {
    float lm = -3.4e38f;
    for (int p = p0 + lane; p < p1; p += 64){
      int e = perm[p];
      lm = fmaxf(lm, lrelu_f(gi + gxj[srcA[e]] + srr[relI[e]]));
    }
    #pragma unroll
    for (int o = 32; o > 0; o >>= 1) lm = fmaxf(lm, __shfl_xor(lm, o));
    float ls = 0.f;
    for (int p = p0 + lane; p < p1; p += 64){
      int e = perm[p];
      ls += expf(lrelu_f(gi + gxj[srcA[e]] + srr[relI[e]]) - lm);
    }
    #pragma unroll
    for (int o = 32; o > 0; o >>= 1) ls += __shfl_xor(ls, o);
    float inv = 1.f / (ls + 1e-16f);
    for (int base = p0; base < p1; base += 64){
      int m = min(64, p1 - base);
      int jj = 0; float all = 0.f;
      if (base + lane < p1){
        int e = perm[base + lane];
        jj = srcA[e];
        all = expf(lrelu_f(gi + gxj[jj] + srr[relI[e]]) - lm) * inv;
      }
      for (int qe = 0; qe < m; qe++){
        int j = __shfl(jj, qe);
        float al = __shfl(all, qe);
        if (act){
          half8 v = *(const half8*)(xh2 + (size_t)j * 1024 + c0);
          #pragma unroll
          for (int k = 0; k < 8; k++) acc[k] += al * (float)v[k];
        }
      }
    }
  }

  if (act){
    float* oi = out + (size_t)i * 2000 + 1000 + c0;
    floatx4 s0, s1;
    #pragma unroll
    for (int k = 0; k < 4; k++){ s0[k] = fmaxf(acc[k], 0.f); s1[k] = fmaxf(acc[4+k], 0.f); }
    *(floatx4*)(oi) = s0;
    *(floatx4*)(oi + 4) = s1;
  }
}

// ---------------- small kernels ----------------
__global__ void k_dot2_small(const float* __restrict__ X, int ld, int len,
                             const float* __restrict__ wA, const float* __restrict__ wB,
                             float* __restrict__ oA, float* __restrict__ oB,
                             int n, int applyL){
  int v = blockIdx.x * blockDim.x + threadIdx.x;
  if (v >= n) return;
  const float* row = X + (size_t)v * ld;
  float a = 0.f, b = 0.f;
  for (int c = 0; c < len; c++){
    float f = row[c];
    if (applyL) f = lrelu_f(f);
    a += f * wA[c];
    if (wB) b += f * wB[c];
  }
  oA[v] = a;
  if (oB) oB[v] = b;
}

// relu relEmb in place + two dots (ww1 mid, gat_ar)
__global__ void k_relu_dots(float* __restrict__ relEmb, const float* __restrict__ wA,
                            const float* __restrict__ wB, float* __restrict__ aRel,
                            float* __restrict__ srr, int n){
  int v = blockIdx.x * blockDim.x + threadIdx.x;
  if (v >= n) return;
  float* row = relEmb + (size_t)v * 100;
  float a = 0.f, b = 0.f;
  for (int c = 0; c < 100; c++){
    float f = fmaxf(row[c], 0.f);
    row[c] = f;
    a += f * wA[c];
    b += f * wB[c];
  }
  aRel[v] = a;
  srr[v] = b;
}

// wave-per-row dual dot over f16 rows
__global__ void k_wave_dot2_h(const _Float16* __restrict__ X, long ld, int len,
                              const float* __restrict__ wA, const float* __restrict__ wB,
                              float* __restrict__ oA, float* __restrict__ oB,
                              int n, int applyL){
  int gw = (int)(((long)blockIdx.x * blockDim.x + threadIdx.x) >> 6);
  int lane = threadIdx.x & 63;
  if (gw >= n) return;
  const _Float16* row = X + (size_t)gw * ld;
  float a = 0.f, b = 0.f;
  for (int c = lane*2; c < len; c += 128){
    half2 v = *(const half2*)(row + c);
    float f0 = (float)v[0], f1 = (float)v[1];
    if (applyL){ f0 = lrelu_f(f0); f1 = lrelu_f(f1); }
    a += f0 * wA[c] + f1 * wA[c+1];
    b += f0 * wB[c] + f1 * wB[c+1];
  }
  #pragma unroll
  for (int o = 32; o > 0; o >>= 1){
    a += __shfl_down(a, o);
    b += __shfl_down(b, o);
  }
  if (lane == 0){ oA[gw] = a; oB[gw] = b; }
}

// ---- merged line-graph (gat_r) chain: both graphs in one pass each ----
__global__ void k_lg_logit(const int* __restrict__ lgOut, const int* __restrict__ lgIn,
                           int ELG, int R, const float* __restrict__ sR_i,
                           const float* __restrict__ sR_j,
                           float* __restrict__ elog, unsigned* __restrict__ mEnc){
  int e = blockIdx.x * blockDim.x + threadIdx.x;
  if (e >= 2*ELG) return;
  int g = e >= ELG;
  int el = e - g*ELG;
  const int* lg = g ? lgIn : lgOut;
  int j = lg[el], i = lg[el + ELG];
  float v = lrelu_f(sR_j[j] + sR_i[i]);
  elog[e] = v;
  atomicMax(mEnc + g*R + j, encF(v));
}

__global__ void k_lg_exp(const int* __restrict__ lgOut, const int* __restrict__ lgIn,
                         int ELG, int R, float* __restrict__ elog,
                         const unsigned* __restrict__ mEnc, float* __restrict__ sumR){
  int e = blockIdx.x * blockDim.x + threadIdx.x;
  if (e >= 2*ELG) return;
  int g = e >= ELG;
  int el = e - g*ELG;
  const int* lg = g ? lgIn : lgOut;
  int j = lg[el];
  float ex = expf(elog[e] - decF(mEnc[g*R + j]));
  elog[e] = ex;
  atomAddF(sumR + g*R + j, ex);
}

__global__ void k_lg_scatter(const int* __restrict__ lgOut, const int* __restrict__ lgIn,
                             int ELG, int R, const float* __restrict__ ex,
                             const float* __restrict__ sumR,
                             const float* __restrict__ relEmb1, float* __restrict__ relEmb){
  int e = blockIdx.x;
  int g = e >= ELG;
  int el = e - g*ELG;
  const int* lg = g ? lgIn : lgOut;
  int j = lg[el], i = lg[el + ELG];
  float alpha = ex[e] / (sumR[g*R + j] + 1e-16f);
  const float* xj = relEmb1 + (size_t)j * 100;
  float* oi = relEmb + (size_t)(g*R + i) * 100;
  for (int c = threadIdx.x; c < 100; c += blockDim.x)
    atomAddF(oi + c, alpha * xj[c]);
}

extern "C" void kernel_launch(void* const* d_in, const int* in_sizes, int n_in,
                              void* d_out, int out_size, void* d_ws, size_t ws_size,
                              hipStream_t stream){
  const float* x_e     = (const float*)d_in[0];
  const int*   eiA     = (const int*)  d_in[3];   // edge_index_all [2,E]
  const int*   relAll  = (const int*)  d_in[4];
  const int*   lgOut   = (const int*)  d_in[5];
  const int*   lgIn    = (const int*)  d_in[7];
  const float* gcn1_w  = (const float*)d_in[9];
  const float* gcn2_w  = (const float*)d_in[10];
  const float* hw1_w   = (const float*)d_in[11];
  const float* hw1_b   = (const float*)d_in[12];
  const float* hw2_w   = (const float*)d_in[13];
  const float* hw2_b   = (const float*)d_in[14];
  const float* ww1     = (const float*)d_in[15];
  const float* gat_ai  = (const float*)d_in[16];
  const float* gat_aj  = (const float*)d_in[17];
  const float* gat_ar  = (const float*)d_in[18];
  const float* gatr_ai = (const float*)d_in[19];
  const float* gatr_aj = (const float*)d_in[20];
  const float* relEmb1 = (const float*)d_in[21];

  const int EH = 300, RH = 100;
  const int N   = in_sizes[0] / EH;
  const int E   = in_sizes[3] / 2;
  const int ELG = in_sizes[5] / 2;
  const int R   = in_sizes[21] / RH;
  const int Mtiles = (N + 127) / 128;
  const int Mpad = Mtiles * 128;

  // ---- workspace layout (16B-aligned f16 blocks first) ----
  char* base = (char*)d_ws;
  _Float16* xh0   = (_Float16*)base;  base += (size_t)Mpad * 320 * 2;   // x_e f16
  _Float16* xhA   = (_Float16*)base;  base += (size_t)Mpad * 320 * 2;   // x1 f16
  _Float16* A1f16 = (_Float16*)base;  base += (size_t)Mpad * 320 * 2;   // relu(agg) f16
  _Float16* xh2   = (_Float16*)base;  base += (size_t)N * 1024 * 2;     // x_wjq f16 mirror
  _Float16* BfAll = (_Float16*)base;  base += (size_t)4 * 102400 * 2;
  float* w = (float*)base;
  float* dis    = w; w += N;
  float* relEmb = w; w += (size_t)2 * R * RH;
  float* sxi    = w; w += N;
  float* sxj    = w; w += N;
  float* gxi    = w; w += N;
  float* gxj    = w; w += N;
  float* sR_i   = w; w += R;
  float* sR_j   = w; w += R;
  unsigned* mEncR = (unsigned*)w; w += 2 * R;   // mEncR (2R) then sumR (2R), contiguous
  float* sumR   = w; w += 2 * R;
  float* aRel   = w; w += 2 * R;
  float* srr    = w; w += 2 * R;
  float* eE     = w; w += E;
  int* degD   = (int*)w; w += N;
  int* degS   = (int*)w; w += N;
  int* curD   = (int*)w; w += N;
  int* curS   = (int*)w; w += N;
  int* offD   = (int*)w; w += N + 1;
  int* offS   = (int*)w; w += N + 1;
  int* permD  = (int*)w; w += E;
  int* permS  = (int*)w; w += E;

  _Float16* Bf_g1 = BfAll;
  _Float16* Bf_h1 = BfAll + 102400;
  _Float16* Bf_g2 = BfAll + 2 * 102400;
  _Float16* Bf_h2 = BfAll + 3 * 102400;

  float* out = (float*)d_out;
  const int* srcA = eiA;         // row0 (j in gcn/gat, i in wjq)
  const int* dstA = eiA + E;     // row1

  auto cdiv = [](int a, int b){ return (a + b - 1) / b; };

  // ---- fused CSR build (dst grouping + src grouping) ----
  hipMemsetAsync(degD, 0, (size_t)4 * N * 4, stream);   // degD,degS,curD,curS contiguous
  k_count2<<<cdiv(E,256),256,0,stream>>>(dstA, srcA, degD, degS, E);
  k_scan2<<<2,1024,0,stream>>>(degD, offD, degS, offS, N);
  k_fill2<<<cdiv(E,256),256,0,stream>>>(dstA, srcA, offD, offS, curD, curS, permD, permS, E);
  k_inv_sqrt_int<<<cdiv(N,256),256,0,stream>>>(degD, dis, N);

  // ---- pack weights (one launch); convert x_e to f16 ----
  k_prep_B4<<<200,256,0,stream>>>(gcn1_w, hw1_w, gcn2_w, hw2_w, BfAll);
  k_conv_f16<<<Mpad,256,0,stream>>>(x_e, xh0, N);

  int NB = 5 * (Mpad / 64);   // 64-row panels
  int GW = cdiv(N, 4);        // wave-per-node grids

  // layer 1: x1 = highway(x_e, gcn(x_e)) -> xhA (f16 mirror only)
  k_gcn_gather<<<GW,256,0,stream>>>(offD, permD, srcA, xh0, dis, A1f16, N);
  k_dual_mfma<<<NB,256,0,stream>>>(A1f16, xh0, Bf_g1, Bf_h1, hw1_b,
                                   nullptr, 0, xhA, 320, N);

  // layer 2: x2 = highway(x1, gcn(x1)) -> out cols 0:300 + xh2 cols 0:300
  k_gcn_gather<<<GW,256,0,stream>>>(offD, permD, srcA, xhA, dis, A1f16, N);
  k_dual_mfma<<<NB,256,0,stream>>>(A1f16, xhA, Bf_g2, Bf_h2, hw2_b,
                                   out, 2000, xh2, 1024, N);

  // gat_r -> relEmb [2R,100]  (merged out/in graphs, atomic path)
  k_dot2_small<<<cdiv(R,256),256,0,stream>>>(relEmb1, RH, RH, gatr_ai, gatr_aj, sR_i, sR_j, R, 0);
  hipMemsetAsync(relEmb, 0, (size_t)2*R*RH*4, stream);
  hipMemsetAsync(mEncR, 0, (size_t)4*R*4, stream);   // mEncR + sumR contiguous
  k_lg_logit<<<cdiv(2*ELG,256),256,0,stream>>>(lgOut, lgIn, ELG, R, sR_i, sR_j, eE, mEncR);
  k_lg_exp<<<cdiv(2*ELG,256),256,0,stream>>>(lgOut, lgIn, ELG, R, eE, mEncR, sumR);
  k_lg_scatter<<<2*ELG,128,0,stream>>>(lgOut, lgIn, ELG, R, eE, sumR, relEmb1, relEmb);

  // relu relEmb + aRel (ww1 mid) + srr (gat_ar) in one pass
  k_relu_dots<<<cdiv(2*R,256),256,0,stream>>>(relEmb, ww1 + EH, gat_ar, aRel, srr, 2*R);

  // wjq per-node logit dots over x2 (xh2 cols 0:300, lrelu applied)
  k_wave_dot2_h<<<cdiv(N,4),256,0,stream>>>(xh2, 1024, EH, ww1, ww1 + EH + RH, sxi, sxj, N, 1);

  // wjq: fused softmax + gather + head + gat-logit dots (gxi,gxj)
  k_wjq_gather<<<GW,256,0,stream>>>(offS, permS, dstA, relAll, sxi, sxj, aRel, relEmb,
                                    gat_ai, gat_aj, out, xh2, gxi, gxj, N);

  // gat: fused softmax + gather + relu, 2 waves/node
  k_gat_gather<<<cdiv(N,2),256,0,stream>>>(offD, permD, srcA, relAll, gxi, gxj, srr, xh2, out, N);
}

// Round 10
// 392.439 us; speedup vs baseline: 5.3298x; 1.0297x over previous
//
#include <hip/hip_runtime.h>
#include <math.h>

#define LSL 0.01f

typedef _Float16 half8 __attribute__((ext_vector_type(8)));
typedef _Float16 half4 __attribute__((ext_vector_type(4)));
typedef float floatx4 __attribute__((ext_vector_type(4)));

static __device__ __forceinline__ float lrelu_f(float x){ return x > 0.f ? x : LSL * x; }
static __device__ __forceinline__ void atomAddF(float* p, float v){ unsafeAtomicAdd(p, v); }

// ---------------- CSR build (fused) ----------------
__global__ void k_count2(const int* __restrict__ dstA, const int* __restrict__ srcA,
                         int* __restrict__ degD, int* __restrict__ degS, int E){
  int e = blockIdx.x * blockDim.x + threadIdx.x;
  if (e < E){ atomicAdd(degD + dstA[e], 1); atomicAdd(degS + srcA[e], 1); }
}

// two exclusive scans (block 0 -> D, block 1 -> S), 1024 threads, strip-per-thread
__global__ __launch_bounds__(1024)
void k_scan2(const int* __restrict__ cntD, int* __restrict__ offD,
             const int* __restrict__ cntS, int* __restrict__ offS, int n){
  const int* cnt = blockIdx.x ? cntS : cntD;
  int* off = blockIdx.x ? offS : offD;
  int t = threadIdx.x, lane = t & 63, wid = t >> 6;   // 16 waves
  int len = (n + 1023) >> 10;
  int lo = t * len, hi = min(lo + len, n);
  int s = 0;
  for (int k = lo; k < hi; k++) s += cnt[k];
  int ws = s;
  #pragma unroll
  for (int o = 1; o < 64; o <<= 1){
    int u = __shfl_up(ws, o);
    if (lane >= o) ws += u;
  }
  __shared__ int wtot[16];
  if (lane == 63) wtot[wid] = ws;
  __syncthreads();
  int wpre = 0;
  #pragma unroll
  for (int k2 = 0; k2 < 16; k2++) wpre += (k2 < wid) ? wtot[k2] : 0;
  int run = wpre + ws - s;
  for (int k = lo; k < hi; k++){ off[k] = run; run += cnt[k]; }
  if (t == 0){
    int tot = 0;
    #pragma unroll
    for (int k2 = 0; k2 < 16; k2++) tot += wtot[k2];
    off[n] = tot;
  }
}

// fill both CSRs + inv-sqrt degree in one launch (FB fill blocks, then N-cover blocks)
__global__ void k_fill_inv(const int* __restrict__ dstA, const int* __restrict__ srcA,
                           const int* __restrict__ offD, const int* __restrict__ offS,
                           int* __restrict__ curD, int* __restrict__ curS,
                           int* __restrict__ permD, int* __restrict__ permS,
                           const int* __restrict__ degD, float* __restrict__ dis,
                           int E, int N, int FB){
  int b = blockIdx.x, t = threadIdx.x;
  if (b < FB){
    int e = b * 256 + t;
    if (e >= E) return;
    int i = dstA[e];
    permD[offD[i] + atomicAdd(curD + i, 1)] = e;
    int j = srcA[e];
    permS[offS[j] + atomicAdd(curS + j, 1)] = e;
  } else {
    int v = (b - FB) * 256 + t;
    if (v < N){ int d = degD[v]; dis[v] = d > 0 ? rsqrtf((float)d) : 0.f; }
  }
}

// x_e f32 [N][300] -> xh0 f16 [Mpad][320] zero-padded; also zero sxi/sxj
__global__ __launch_bounds__(256)
void k_conv_f16(const float* __restrict__ x, _Float16* __restrict__ xh,
                float* __restrict__ sxi, float* __restrict__ sxj, int N){
  int i = blockIdx.x, t = threadIdx.x;
  _Float16* o = xh + (size_t)i * 320;
  if (i < N){
    const float* r = x + (size_t)i * 300;
    o[t] = (_Float16)r[t];
    if (t < 44) o[t + 256] = (_Float16)r[t + 256];
    else if (t < 64) o[t + 256] = (_Float16)0.f;
    if (t == 0) sxi[i] = 0.f;
    if (t == 1) sxj[i] = 0.f;
  } else {
    o[t] = (_Float16)0.f;
    if (t < 64) o[t + 256] = (_Float16)0.f;
  }
}

// ---------------- CSR gathers: wave-per-node, register accumulate ----------------
__global__ __launch_bounds__(256)
void k_gcn_gather(const int* __restrict__ off, const int* __restrict__ perm,
                  const int* __restrict__ src, const _Float16* __restrict__ x,
                  const float* __restrict__ dis, _Float16* __restrict__ agg, int N){
  int i = (int)(((long)blockIdx.x * blockDim.x + threadIdx.x) >> 6);
  int lane = threadIdx.x & 63;
  if (i >= N) return;
  int p0 = off[i], p1 = off[i+1];
  float di = dis[i];
  float acc[8] = {0.f,0.f,0.f,0.f,0.f,0.f,0.f,0.f};
  for (int base = p0; base < p1; base += 64){
    int m = min(64, p1 - base);
    int jj = 0; float wl = 0.f;
    if (base + lane < p1){
      int e = perm[base + lane];
      jj = src[e];
      wl = di * dis[jj];
    }
    int q = 0;
    for (; q + 1 < m; q += 2){
      int j0 = __shfl(jj, q),   j1 = __shfl(jj, q+1);
      float w0 = __shfl(wl, q), w1 = __shfl(wl, q+1);
      if (lane < 40){
        half8 v0 = *(const half8*)(x + (size_t)j0 * 320 + 8*lane);
        half8 v1 = *(const half8*)(x + (size_t)j1 * 320 + 8*lane);
        #pragma unroll
        for (int k = 0; k < 8; k++) acc[k] += w0 * (float)v0[k] + w1 * (float)v1[k];
      }
    }
    if (q < m){
      int j0 = __shfl(jj, q);
      float w0 = __shfl(wl, q);
      if (lane < 40){
        half8 v0 = *(const half8*)(x + (size_t)j0 * 320 + 8*lane);
        #pragma unroll
        for (int k = 0; k < 8; k++) acc[k] += w0 * (float)v0[k];
      }
    }
  }
  if (lane < 40){
    half8 o;
    #pragma unroll
    for (int k = 0; k < 8; k++) o[k] = (_Float16)fmaxf(acc[k], 0.f);
    *(half8*)(agg + (size_t)i * 320 + 8*lane) = o;
  }
}

// ---------------- MFMA dual-GEMM + highway ----------------
__global__ void k_prep_B4(const float* __restrict__ W0, const float* __restrict__ W1,
                          const float* __restrict__ W2, const float* __restrict__ W3,
                          _Float16* __restrict__ BfAll){
  int idx = blockIdx.x * 256 + threadIdx.x;
  if (idx >= 4*12800) return;
  int wsel = idx / 12800;
  int rem2 = idx % 12800;
  const float* W = (wsel == 0) ? W0 : (wsel == 1) ? W1 : (wsel == 2) ? W2 : W3;
  int lane = rem2 & 63;
  int rem = rem2 >> 6;
  int nf = rem & 3; rem >>= 2;
  int nt = rem % 5;
  int ks = rem / 5;
  int n = nt*64 + nf*16 + (lane & 15);
  int kb = ks*32 + (lane >> 4) * 8;
  _Float16* o = BfAll + (size_t)wsel * 102400 + (size_t)rem2 * 8;
  #pragma unroll
  for (int e = 0; e < 8; e++){
    int k = kb + e;
    float v = (k < 300 && n < 300) ? W[(size_t)k * 300 + n] : 0.f;
    o[e] = (_Float16)v;
  }
}

// O = sig(X@Wh + b) * (A1@Wg) + (1-sig)*X ; 16 rows/wave, 64-row panels, XCD swizzle.
// Optional fused per-row dots: sxi += lrelu(val)*ww[gn], sxj += lrelu(val)*ww[400+gn].
__global__ __launch_bounds__(256)
void k_dual_mfma(const _Float16* __restrict__ A1, const _Float16* __restrict__ Xh,
                 const _Float16* __restrict__ Bf1, const _Float16* __restrict__ Bf2,
                 const float* __restrict__ bias, float* __restrict__ Of32, long ldo,
                 _Float16* __restrict__ Oh, long ldm, int M,
                 const float* __restrict__ ww, float* __restrict__ sxi,
                 float* __restrict__ sxj){
  int nb = gridDim.x;
  int q = nb >> 3, r = nb & 7;
  int xcd = blockIdx.x & 7, kk0 = blockIdx.x >> 3;
  int pseudo = (xcd < r ? xcd * (q + 1) : r * (q + 1) + (xcd - r) * q) + kk0;
  int nt = pseudo % 5;
  int panel = pseudo / 5;

  int tid = threadIdx.x;
  int w = tid >> 6, lane = tid & 63;
  int l15 = lane & 15, lg = lane >> 4;
  int rowBase = panel * 64 + w * 16;
  int colBase = nt * 64;

  floatx4 acc1[4], acc2[4];
  #pragma unroll
  for (int b = 0; b < 4; b++){
    acc1[b] = (floatx4){0.f,0.f,0.f,0.f};
    acc2[b] = (floatx4){0.f,0.f,0.f,0.f};
  }

  int row0 = rowBase + l15;
  const _Float16* a1p0 = A1 + (size_t)row0 * 320;
  const _Float16* a2p0 = Xh + (size_t)row0 * 320;

  for (int ks = 0; ks < 10; ks++){
    int kA = ks*32 + lg*8;
    half8 a1f0 = *(const half8*)(a1p0 + kA);
    half8 a2f0 = *(const half8*)(a2p0 + kA);
    const half8* b1p = (const half8*)Bf1 + ((size_t)(ks*5 + nt) * 4 * 64 + lane);
    const half8* b2p = (const half8*)Bf2 + ((size_t)(ks*5 + nt) * 4 * 64 + lane);
    #pragma unroll
    for (int nf = 0; nf < 4; nf++){
      half8 b1 = b1p[nf*64];
      half8 b2 = b2p[nf*64];
      acc1[nf] = __builtin_amdgcn_mfma_f32_16x16x32_f16(a1f0, b1, acc1[nf], 0,0,0);
      acc2[nf] = __builtin_amdgcn_mfma_f32_16x16x32_f16(a2f0, b2, acc2[nf], 0,0,0);
    }
  }

  bool doSX = (sxi != nullptr);
  float dA[4] = {0.f,0.f,0.f,0.f}, dB[4] = {0.f,0.f,0.f,0.f};
  #pragma unroll
  for (int nf = 0; nf < 4; nf++){
    int gn = colBase + nf*16 + l15;
    int gnc = min(gn, 299);
    float bv = bias[gnc];
    float wA = doSX ? ww[gnc] : 0.f;
    float wB = doSX ? ww[400 + gnc] : 0.f;
    #pragma unroll
    for (int r2 = 0; r2 < 4; r2++){
      int gm = rowBase + lg*4 + r2;
      int gmc = min(gm, M-1);
      float xv = (float)Xh[(size_t)gmc * 320 + gnc];
      float g = 1.f / (1.f + expf(-(acc2[nf][r2] + bv)));
      float val = g * acc1[nf][r2] + (1.f - g) * xv;
      if (gm < M && gn < 300){
        if (Of32) Of32[(size_t)gm * ldo + gn] = val;
        if (Oh)   Oh[(size_t)gm * ldm + gn] = (_Float16)val;
        float f = lrelu_f(val);
        dA[r2] += f * wA;
        dB[r2] += f * wB;
      }
    }
  }
  if (doSX){
    #pragma unroll
    for (int r2 = 0; r2 < 4; r2++){
      float a = dA[r2], b = dB[r2];
      #pragma unroll
      for (int o = 1; o < 16; o <<= 1){
        a += __shfl_xor(a, o);
        b += __shfl_xor(b, o);
      }
      int gm = rowBase + lg*4 + r2;
      if (l15 == 0 && gm < M){
        atomAddF(sxi + gm, a);
        atomAddF(sxj + gm, b);
      }
    }
  }
}

// wjq: wave-per-node (grouped by i=row0), fused softmax + gather + head
// + fused GAT logit dots gxi/gxj; stores sumA -> sAl. relEmb read as f16.
__global__ __launch_bounds__(256)
void k_wjq_gather(const int* __restrict__ off, const int* __restrict__ perm,
                  const int* __restrict__ dstA, const int* __restrict__ relI,
                  const float* __restrict__ sxi, const float* __restrict__ sxj,
                  const float* __restrict__ aRel, const _Float16* __restrict__ relEmbH,
                  const float* __restrict__ gat_ai, const float* __restrict__ gat_aj,
                  float* __restrict__ out, _Float16* __restrict__ xh2,
                  float* __restrict__ gxi, float* __restrict__ gxj,
                  float* __restrict__ sAl, int N){
  int i = (int)(((long)blockIdx.x * blockDim.x + threadIdx.x) >> 6);
  int lane = threadIdx.x & 63;
  if (i >= N) return;
  int p0 = off[i], p1 = off[i+1];
  int deg = p1 - p0;
  float si = sxi[i];
  float accx[8] = {0.f,0.f,0.f,0.f,0.f,0.f,0.f,0.f};
  float accr[4] = {0.f,0.f,0.f,0.f};
  float sumA;

  if (deg <= 64){
    int jj = 0, rr = 0; float l = -3.4e38f;
    if (lane < deg){
      int e = perm[p0 + lane];
      jj = dstA[e]; rr = relI[e];
      l = si + sxj[jj] + aRel[rr];
    }
    float lm = l;
    #pragma unroll
    for (int o = 32; o > 0; o >>= 1) lm = fmaxf(lm, __shfl_xor(lm, o));
    float exl = (lane < deg) ? expf(l - lm) : 0.f;
    float ls = exl;
    #pragma unroll
    for (int o = 32; o > 0; o >>= 1) ls += __shfl_xor(ls, o);
    float inv = 1.f / (ls + 1e-16f);
    sumA = ls * inv;
    float wgt = exl * inv;
    int qe = 0;
    for (; qe + 1 < deg; qe += 2){
      int j0 = __shfl(jj, qe),  j1 = __shfl(jj, qe+1);
      int r0 = __shfl(rr, qe),  r1 = __shfl(rr, qe+1);
      float a0 = __shfl(wgt, qe), a1 = __shfl(wgt, qe+1);
      if (lane < 38){
        half8 v0 = *(const half8*)(xh2 + (size_t)j0 * 1024 + 8*lane);
        half8 v1 = *(const half8*)(xh2 + (size_t)j1 * 1024 + 8*lane);
        #pragma unroll
        for (int k = 0; k < 8; k++)
          accx[k] += a0 * lrelu_f((float)v0[k]) + a1 * lrelu_f((float)v1[k]);
      } else if (lane < 63){
        half4 v0 = *(const half4*)(relEmbH + (size_t)r0 * 100 + 4*(lane - 38));
        half4 v1 = *(const half4*)(relEmbH + (size_t)r1 * 100 + 4*(lane - 38));
        #pragma unroll
        for (int k = 0; k < 4; k++)
          accr[k] += a0 * (float)v0[k] + a1 * (float)v1[k];   // relEmb >= 0: lrelu no-op
      }
    }
    if (qe < deg){
      int j0 = __shfl(jj, qe);
      int r0 = __shfl(rr, qe);
      float a0 = __shfl(wgt, qe);
      if (lane < 38){
        half8 v0 = *(const half8*)(xh2 + (size_t)j0 * 1024 + 8*lane);
        #pragma unroll
        for (int k = 0; k < 8; k++) accx[k] += a0 * lrelu_f((float)v0[k]);
      } else if (lane < 63){
        half4 v0 = *(const half4*)(relEmbH + (size_t)r0 * 100 + 4*(lane - 38));
        #pragma unroll
        for (int k = 0; k < 4; k++) accr[k] += a0 * (float)v0[k];
      }
    }
  } else {
    float lm = -3.4e38f;
    for (int p = p0 + lane; p < p1; p += 64){
      int e = perm[p];
      lm = fmaxf(lm, si + sxj[dstA[e]] + aRel[relI[e]]);
    }
    #pragma unroll
    for (int o = 32; o > 0; o >>= 1) lm = fmaxf(lm, __shfl_xor(lm, o));
    float ls = 0.f;
    for (int p = p0 + lane; p < p1; p += 64){
      int e = perm[p];
      ls += expf(si + sxj[dstA[e]] + aRel[relI[e]] - lm);
    }
    #pragma unroll
    for (int o = 32; o > 0; o >>= 1) ls += __shfl_xor(ls, o);
    float inv = 1.f / (ls + 1e-16f);
    sumA = ls * inv;
    for (int base = p0; base < p1; base += 64){
      int m = min(64, p1 - base);
      int jj = 0, rr = 0; float all = 0.f;
      if (base + lane < p1){
        int e = perm[base + lane];
        jj = dstA[e]; rr = relI[e];
        all = expf(si + sxj[jj] + aRel[rr] - lm) * inv;
      }
      for (int qe = 0; qe < m; qe++){
        int j = __shfl(jj, qe);
        int r = __shfl(rr, qe);
        float al = __shfl(all, qe);
        if (lane < 38){
          half8 v = *(const half8*)(xh2 + (size_t)j * 1024 + 8*lane);
          #pragma unroll
          for (int k = 0; k < 8; k++) accx[k] += al * lrelu_f((float)v[k]);
        } else if (lane < 63){
          half4 v = *(const half4*)(relEmbH + (size_t)r * 100 + 4*(lane - 38));
          #pragma unroll
          for (int k = 0; k < 4; k++) accr[k] += al * (float)v[k];
        }
      }
    }
  }

  // epilogue: write cols 600:1000 (f32 + f16 mirror), head 300:600 (f32 only);
  // fused gxi/gxj dots over the full 1000-col row
  float* oi = out + (size_t)i * 2000;
  _Float16* hi = xh2 + (size_t)i * 1024;
  float dA = 0.f, dB = 0.f;
  if (lane < 38){
    #pragma unroll
    for (int k = 0; k < 8; k++){
      int c = 8*lane + k;
      if (c < 300){
        oi[700 + c] = accx[k]; hi[700 + c] = (_Float16)accx[k];
        dA += accx[k] * gat_ai[700 + c];
        dB += accx[k] * gat_aj[700 + c];
      }
    }
    half8 v = *(const half8*)(hi + 8*lane);   // x2 f16 (cols 0:300)
    #pragma unroll
    for (int k = 0; k < 8; k++){
      int c = 8*lane + k;
      if (c < 300){
        float x2v = (float)v[k];
        float h = lrelu_f(x2v) * sumA;
        oi[300 + c] = h;                      // f16 mirror of 300:600 no longer needed
        dA += x2v * gat_ai[c] + h * gat_ai[300 + c];
        dB += x2v * gat_aj[c] + h * gat_aj[300 + c];
      }
    }
  } else if (lane < 63){
    #pragma unroll
    for (int k = 0; k < 4; k++){
      int c = 4*(lane - 38) + k;
      oi[600 + c] = accr[k]; hi[600 + c] = (_Float16)accr[k];
      dA += accr[k] * gat_ai[600 + c];
      dB += accr[k] * gat_aj[600 + c];
    }
  }
  #pragma unroll
  for (int o = 32; o > 0; o >>= 1){
    dA += __shfl_xor(dA, o);
    dB += __shfl_xor(dB, o);
  }
  if (lane == 0){ gxi[i] = dA; gxj[i] = dB; sAl[i] = sumA; }
}

// gat: TWO waves per node. half 0: out cols 0:600 derived from x2 (cols 0:300) + sAl[j];
// half 1: out cols 600:1000 from xh2 cols 600:1000. Fused softmax per half.
__global__ __launch_bounds__(256)
void k_gat_gather(const int* __restrict__ off, const int* __restrict__ perm,
                  const int* __restrict__ srcA, const int* __restrict__ relI,
                  const float* __restrict__ gxi, const float* __restrict__ gxj,
                  const float* __restrict__ srr, const float* __restrict__ sAl,
                  const _Float16* __restrict__ xh2, float* __restrict__ out, int N){
  long gw = ((long)blockIdx.x * blockDim.x + threadIdx.x) >> 6;
  int lane = threadIdx.x & 63;
  int i = (int)(gw >> 1), half = (int)(gw & 1);
  if (i >= N) return;
  int p0 = off[i], p1 = off[i+1];
  int deg = p1 - p0;
  float gi = gxi[i];
  float acc_a[8] = {0.f,0.f,0.f,0.f,0.f,0.f,0.f,0.f};
  float acc_b[8] = {0.f,0.f,0.f,0.f,0.f,0.f,0.f,0.f};

  if (deg <= 64){
    int jj = 0; float l = -3.4e38f, saj = 0.f;
    if (lane < deg){
      int e = perm[p0 + lane];
      jj = srcA[e];
      l = lrelu_f(gi + gxj[jj] + srr[relI[e]]);
      if (half == 0) saj = sAl[jj];
    }
    float lm = l;
    #pragma unroll
    for (int o = 32; o > 0; o >>= 1) lm = fmaxf(lm, __shfl_xor(lm, o));
    float exl = (lane < deg) ? expf(l - lm) : 0.f;
    float ls = exl;
    #pragma unroll
    for (int o = 32; o > 0; o >>= 1) ls += __shfl_xor(ls, o);
    float wgt = exl / (ls + 1e-16f);
    if (half == 0){
      int qe = 0;
      for (; qe + 1 < deg; qe += 2){
        int j0 = __shfl(jj, qe),    j1 = __shfl(jj, qe+1);
        float a0 = __shfl(wgt, qe), a1 = __shfl(wgt, qe+1);
        float s0 = __shfl(saj, qe) * a0, s1 = __shfl(saj, qe+1) * a1;
        if (lane < 38){
          half8 v0 = *(const half8*)(xh2 + (size_t)j0 * 1024 + 8*lane);
          half8 v1 = *(const half8*)(xh2 + (size_t)j1 * 1024 + 8*lane);
          #pragma unroll
          for (int k = 0; k < 8; k++){
            float x0 = (float)v0[k], x1 = (float)v1[k];
            acc_a[k] += a0 * x0 + a1 * x1;
            acc_b[k] += s0 * lrelu_f(x0) + s1 * lrelu_f(x1);
          }
        }
      }
      if (qe < deg){
        int j0 = __shfl(jj, qe);
        float a0 = __shfl(wgt, qe);
        float s0 = __shfl(saj, qe) * a0;
        if (lane < 38){
          half8 v0 = *(const half8*)(xh2 + (size_t)j0 * 1024 + 8*lane);
          #pragma unroll
          for (int k = 0; k < 8; k++){
            float x0 = (float)v0[k];
            acc_a[k] += a0 * x0;
            acc_b[k] += s0 * lrelu_f(x0);
          }
        }
      }
    } else {
      int qe = 0;
      for (; qe + 1 < deg; qe += 2){
        int j0 = __shfl(jj, qe),    j1 = __shfl(jj, qe+1);
        float a0 = __shfl(wgt, qe), a1 = __shfl(wgt, qe+1);
        if (lane < 50){
          half8 v0 = *(const half8*)(xh2 + (size_t)j0 * 1024 + 600 + 8*lane);
          half8 v1 = *(const half8*)(xh2 + (size_t)j1 * 1024 + 600 + 8*lane);
          #pragma unroll
          for (int k = 0; k < 8; k++) acc_a[k] += a0 * (float)v0[k] + a1 * (float)v1[k];
        }
      }
      if (qe < deg){
        int j0 = __shfl(jj, qe);
        float a0 = __shfl(wgt, qe);
        if (lane < 50){
          half8 v0 = *(const half8*)(xh2 + (size_t)j0 * 1024 + 600 + 8*lane);
          #pragma unroll
          for (int k = 0; k < 8; k++) acc_a[k] += a0 * (float)v0[k];
        }
      }
    }
  } else {
    // generic path
    float lm = -3.4e38f;
    for (int p = p0 + lane; p < p1; p += 64){
      int e = perm[p];
      lm = fmaxf(lm, lrelu_f(gi + gxj[srcA[e]] + srr[relI[e]]));
    }
    #pragma unroll
    for (int o = 32; o > 0; o >>= 1) lm = fmaxf(lm, __shfl_xor(lm, o));
    float ls = 0.f;
    for (int p = p0 + lane; p < p1; p += 64){
      int e = perm[p];
      ls += expf(lrelu_f(gi + gxj[srcA[e]] + srr[relI[e]]) - lm);
    }
    #pragma unroll
    for (int o = 32; o > 0; o >>= 1) ls += __shfl_xor(ls, o);
    float inv = 1.f / (ls + 1e-16f);
    for (int base = p0; base < p1; base += 64){
      int m = min(64, p1 - base);
      int jj = 0; float all = 0.f, saj = 0.f;
      if (base + lane < p1){
        int e = perm[base + lane];
        jj = srcA[e];
        all = expf(lrelu_f(gi + gxj[jj] + srr[relI[e]]) - lm) * inv;
        if (half == 0) saj = sAl[jj];
      }
      for (int qe = 0; qe < m; qe++){
        int j = __shfl(jj, qe);
        float al = __shfl(all, qe);
        if (half == 0){
          float sa = __shfl(saj, qe) * al;
          if (lane < 38){
            half8 v = *(const half8*)(xh2 + (size_t)j * 1024 + 8*lane);
            #pragma unroll
            for (int k = 0; k < 8; k++){
              float x0 = (float)v[k];
              acc_a[k] += al * x0;
              acc_b[k] += sa * lrelu_f(x0);
            }
          }
        } else {
          if (lane < 50){
            half8 v = *(const half8*)(xh2 + (size_t)j * 1024 + 600 + 8*lane);
            #pragma unroll
            for (int k = 0; k < 8; k++) acc_a[k] += al * (float)v[k];
          }
        }
      }
    }
  }

  float* ob = out + (size_t)i * 2000 + 1000;
  if (half == 0){
    if (lane < 37){
      floatx4 s0, s1, t0, t1;
      #pragma unroll
      for (int k = 0; k < 4; k++){
        s0[k] = fmaxf(acc_a[k], 0.f);   s1[k] = fmaxf(acc_a[4+k], 0.f);
        t0[k] = fmaxf(acc_b[k], 0.f);   t1[k] = fmaxf(acc_b[4+k], 0.f);
      }
      *(floatx4*)(ob + 8*lane) = s0;
      *(floatx4*)(ob + 8*lane + 4) = s1;
      *(floatx4*)(ob + 300 + 8*lane) = t0;
      *(floatx4*)(ob + 300 + 8*lane + 4) = t1;
    } else if (lane == 37){
      #pragma unroll
      for (int k = 0; k < 4; k++){       // cols 296..299
        ob[296 + k] = fmaxf(acc_a[k], 0.f);
        ob[596 + k] = fmaxf(acc_b[k], 0.f);
      }
    }
  } else {
    if (lane < 50){
      floatx4 s0, s1;
      #pragma unroll
      for (int k = 0; k < 4; k++){ s0[k] = fmaxf(acc_a[k], 0.f); s1[k] = fmaxf(acc_a[4+k], 0.f); }
      *(floatx4*)(ob + 600 + 8*lane) = s0;
      *(floatx4*)(ob + 600 + 8*lane + 4) = s1;
    }
  }
}

// ---------------- small kernels ----------------
__global__ void k_dot2_small(const float* __restrict__ X, int ld, int len,
                             const float* __restrict__ wA, const float* __restrict__ wB,
                             float* __restrict__ oA, float* __restrict__ oB,
                             int n, int applyL){
  int v = blockIdx.x * blockDim.x + threadIdx.x;
  if (v >= n) return;
  const float* row = X + (size_t)v * ld;
  float a = 0.f, b = 0.f;
  for (int c = 0; c < len; c++){
    float f = row[c];
    if (applyL) f = lrelu_f(f);
    a += f * wA[c];
    if (wB) b += f * wB[c];
  }
  oA[v] = a;
  if (oB) oB[v] = b;
}

// relu relEmb in place + f16 mirror + two dots (ww1 mid, gat_ar)
__global__ void k_relu_dots(float* __restrict__ relEmb, _Float16* __restrict__ relEmbH,
                            const float* __restrict__ wA, const float* __restrict__ wB,
                            float* __restrict__ aRel, float* __restrict__ srr, int n){
  int v = blockIdx.x * blockDim.x + threadIdx.x;
  if (v >= n) return;
  float* row = relEmb + (size_t)v * 100;
  _Float16* rowH = relEmbH + (size_t)v * 100;
  float a = 0.f, b = 0.f;
  for (int c = 0; c < 100; c++){
    float f = fmaxf(row[c], 0.f);
    row[c] = f;
    rowH[c] = (_Float16)f;
    a += f * wA[c];
    b += f * wB[c];
  }
  aRel[v] = a;
  srr[v] = b;
}

// ---- merged line-graph (gat_r) chain: logit+exp in one pass (softmax shift-invariant,
// logits are O(0.05) so exp without max subtraction is numerically safe) ----
__global__ void k_lg_le(const int* __restrict__ lgOut, const int* __restrict__ lgIn,
                        int ELG, int R, const float* __restrict__ sR_i,
                        const float* __restrict__ sR_j,
                        float* __restrict__ elog, float* __restrict__ sumR){
  int e = blockIdx.x * blockDim.x + threadIdx.x;
  if (e >= 2*ELG) return;
  int g = e >= ELG;
  int el = e - g*ELG;
  const int* lg = g ? lgIn : lgOut;
  int j = lg[el], i = lg[el + ELG];
  float ex = expf(lrelu_f(sR_j[j] + sR_i[i]));
  elog[e] = ex;
  atomAddF(sumR + g*R + j, ex);
}

__global__ void k_lg_scatter(const int* __restrict__ lgOut, const int* __restrict__ lgIn,
                             int ELG, int R, const float* __restrict__ ex,
                             const float* __restrict__ sumR,
                             const float* __restrict__ relEmb1, float* __restrict__ relEmb){
  int e = blockIdx.x;
  int g = e >= ELG;
  int el = e - g*ELG;
  const int* lg = g ? lgIn : lgOut;
  int j = lg[el], i = lg[el + ELG];
  float alpha = ex[e] / (sumR[g*R + j] + 1e-16f);
  const float* xj = relEmb1 + (size_t)j * 100;
  float* oi = relEmb + (size_t)(g*R + i) * 100;
  for (int c = threadIdx.x; c < 100; c += blockDim.x)
    atomAddF(oi + c, alpha * xj[c]);
}

extern "C" void kernel_launch(void* const* d_in, const int* in_sizes, int n_in,
                              void* d_out, int out_size, void* d_ws, size_t ws_size,
                              hipStream_t stream){
  const float* x_e     = (const float*)d_in[0];
  const int*   eiA     = (const int*)  d_in[3];   // edge_index_all [2,E]
  const int*   relAll  = (const int*)  d_in[4];
  const int*   lgOut   = (const int*)  d_in[5];
  const int*   lgIn    = (const int*)  d_in[7];
  const float* gcn1_w  = (const float*)d_in[9];
  const float* gcn2_w  = (const float*)d_in[10];
  const float* hw1_w   = (const float*)d_in[11];
  const float* hw1_b   = (const float*)d_in[12];
  const float* hw2_w   = (const float*)d_in[13];
  const float* hw2_b   = (const float*)d_in[14];
  const float* ww1     = (const float*)d_in[15];
  const float* gat_ai  = (const float*)d_in[16];
  const float* gat_aj  = (const float*)d_in[17];
  const float* gat_ar  = (const float*)d_in[18];
  const float* gatr_ai = (const float*)d_in[19];
  const float* gatr_aj = (const float*)d_in[20];
  const float* relEmb1 = (const float*)d_in[21];

  const int EH = 300, RH = 100;
  const int N   = in_sizes[0] / EH;
  const int E   = in_sizes[3] / 2;
  const int ELG = in_sizes[5] / 2;
  const int R   = in_sizes[21] / RH;
  const int Mtiles = (N + 127) / 128;
  const int Mpad = Mtiles * 128;

  // ---- workspace layout (16B-aligned f16 blocks first) ----
  char* base = (char*)d_ws;
  _Float16* xh0   = (_Float16*)base;  base += (size_t)Mpad * 320 * 2;   // x_e f16
  _Float16* xhA   = (_Float16*)base;  base += (size_t)Mpad * 320 * 2;   // x1 f16
  _Float16* A1f16 = (_Float16*)base;  base += (size_t)Mpad * 320 * 2;   // relu(agg) f16
  _Float16* xh2   = (_Float16*)base;  base += (size_t)N * 1024 * 2;     // x_wjq f16 mirror
  _Float16* BfAll = (_Float16*)base;  base += (size_t)4 * 102400 * 2;
  _Float16* relEmbH = (_Float16*)base; base += (size_t)2 * R * RH * 2;  // relEmb f16
  float* w = (float*)base;
  float* dis    = w; w += N;
  float* relEmb = w; w += (size_t)2 * R * RH;   // relEmb then sumR contiguous (one memset)
  float* sumR   = w; w += 2 * R;
  float* sxi    = w; w += N;
  float* sxj    = w; w += N;
  float* gxi    = w; w += N;
  float* gxj    = w; w += N;
  float* sAl    = w; w += N;
  float* sR_i   = w; w += R;
  float* sR_j   = w; w += R;
  float* aRel   = w; w += 2 * R;
  float* srr    = w; w += 2 * R;
  float* eE     = w; w += E;
  int* degD   = (int*)w; w += N;
  int* degS   = (int*)w; w += N;
  int* curD   = (int*)w; w += N;
  int* curS   = (int*)w; w += N;
  int* offD   = (int*)w; w += N + 1;
  int* offS   = (int*)w; w += N + 1;
  int* permD  = (int*)w; w += E;
  int* permS  = (int*)w; w += E;

  _Float16* Bf_g1 = BfAll;
  _Float16* Bf_h1 = BfAll + 102400;
  _Float16* Bf_g2 = BfAll + 2 * 102400;
  _Float16* Bf_h2 = BfAll + 3 * 102400;

  float* out = (float*)d_out;
  const int* srcA = eiA;         // row0 (j in gcn/gat, i in wjq)
  const int* dstA = eiA + E;     // row1

  auto cdiv = [](int a, int b){ return (a + b - 1) / b; };

  // ---- fused CSR build (dst grouping + src grouping) ----
  hipMemsetAsync(degD, 0, (size_t)4 * N * 4, stream);   // degD,degS,curD,curS contiguous
  k_count2<<<cdiv(E,256),256,0,stream>>>(dstA, srcA, degD, degS, E);
  k_scan2<<<2,1024,0,stream>>>(degD, offD, degS, offS, N);
  int FB = cdiv(E,256);
  k_fill_inv<<<FB + cdiv(N,256),256,0,stream>>>(dstA, srcA, offD, offS, curD, curS,
                                                permD, permS, degD, dis, E, N, FB);

  // ---- pack weights (one launch); convert x_e to f16 (+zero sxi/sxj) ----
  k_prep_B4<<<200,256,0,stream>>>(gcn1_w, hw1_w, gcn2_w, hw2_w, BfAll);
  k_conv_f16<<<Mpad,256,0,stream>>>(x_e, xh0, sxi, sxj, N);

  int NB = 5 * (Mpad / 64);   // 64-row panels
  int GW = cdiv(N, 4);        // wave-per-node grids

  // layer 1: x1 = highway(x_e, gcn(x_e)) -> xhA (f16 mirror only)
  k_gcn_gather<<<GW,256,0,stream>>>(offD, permD, srcA, xh0, dis, A1f16, N);
  k_dual_mfma<<<NB,256,0,stream>>>(A1f16, xh0, Bf_g1, Bf_h1, hw1_b,
                                   nullptr, 0, xhA, 320, N, nullptr, nullptr, nullptr);

  // layer 2: x2 = highway(x1, gcn(x1)) -> out cols 0:300 + xh2 cols 0:300 + sxi/sxj dots
  k_gcn_gather<<<GW,256,0,stream>>>(offD, permD, srcA, xhA, dis, A1f16, N);
  k_dual_mfma<<<NB,256,0,stream>>>(A1f16, xhA, Bf_g2, Bf_h2, hw2_b,
                                   out, 2000, xh2, 1024, N, ww1, sxi, sxj);

  // gat_r -> relEmb [2R,100]  (merged out/in graphs, atomic path, no max pass)
  k_dot2_small<<<cdiv(R,256),256,0,stream>>>(relEmb1, RH, RH, gatr_ai, gatr_aj, sR_i, sR_j, R, 0);
  hipMemsetAsync(relEmb, 0, ((size_t)2*R*RH + 2*R) * 4, stream);   // relEmb + sumR
  k_lg_le<<<cdiv(2*ELG,256),256,0,stream>>>(lgOut, lgIn, ELG, R, sR_i, sR_j, eE, sumR);
  k_lg_scatter<<<2*ELG,128,0,stream>>>(lgOut, lgIn, ELG, R, eE, sumR, relEmb1, relEmb);

  // relu relEmb + f16 mirror + aRel (ww1 mid) + srr (gat_ar) in one pass
  k_relu_dots<<<cdiv(2*R,256),256,0,stream>>>(relEmb, relEmbH, ww1 + EH, gat_ar, aRel, srr, 2*R);

  // wjq: fused softmax + gather + head + gat-logit dots (gxi,gxj) + sAl
  k_wjq_gather<<<GW,256,0,stream>>>(offS, permS, dstA, relAll, sxi, sxj, aRel, relEmbH,
                                    gat_ai, gat_aj, out, xh2, gxi, gxj, sAl, N);

  // gat: fused softmax + gather + relu; half0 derives cols 300:600 from x2 + sAl
  k_gat_gather<<<cdiv(N,2),256,0,stream>>>(offD, permD, srcA, relAll, gxi, gxj, srr,
                                           sAl, xh2, out, N);
}

// Round 11
// 373.638 us; speedup vs baseline: 5.5980x; 1.0503x over previous
//
#include <hip/hip_runtime.h>
#include <math.h>

#define LSL 0.01f

typedef _Float16 half8 __attribute__((ext_vector_type(8)));
typedef _Float16 half4 __attribute__((ext_vector_type(4)));
typedef float floatx4 __attribute__((ext_vector_type(4)));

static __device__ __forceinline__ float lrelu_f(float x){ return x > 0.f ? x : LSL * x; }
static __device__ __forceinline__ void atomAddF(float* p, float v){ unsafeAtomicAdd(p, v); }

// ---------------- fused setup: count2 | prep_B4 | conv_f16 | sR dots ----------------
__global__ __launch_bounds__(256)
void k_setup(const int* __restrict__ dstA, const int* __restrict__ srcA,
             int* __restrict__ degD, int* __restrict__ degS, int E,
             const float* __restrict__ W0, const float* __restrict__ W1,
             const float* __restrict__ W2, const float* __restrict__ W3,
             _Float16* __restrict__ BfAll,
             const float* __restrict__ x_e, _Float16* __restrict__ xh0,
             float* __restrict__ sxi, float* __restrict__ sxj, int N,
             const float* __restrict__ relEmb1, const float* __restrict__ gatr_ai,
             const float* __restrict__ gatr_aj, float* __restrict__ sR_i,
             float* __restrict__ sR_j, int R, int B0, int B1, int B2){
  int b = blockIdx.x, t = threadIdx.x;
  if (b < B0){
    // edge degree count (both groupings)
    int e = b * 256 + t;
    if (e < E){ atomicAdd(degD + dstA[e], 1); atomicAdd(degS + srcA[e], 1); }
  } else if (b < B0 + B1){
    // pack 4 weight matrices into MFMA fragment layout
    int idx = (b - B0) * 256 + t;
    if (idx >= 4*12800) return;
    int wsel = idx / 12800;
    int rem2 = idx % 12800;
    const float* W = (wsel == 0) ? W0 : (wsel == 1) ? W1 : (wsel == 2) ? W2 : W3;
    int lane = rem2 & 63;
    int rem = rem2 >> 6;
    int nf = rem & 3; rem >>= 2;
    int nt = rem % 5;
    int ks = rem / 5;
    int n = nt*64 + nf*16 + (lane & 15);
    int kb = ks*32 + (lane >> 4) * 8;
    _Float16* o = BfAll + (size_t)wsel * 102400 + (size_t)rem2 * 8;
    #pragma unroll
    for (int e = 0; e < 8; e++){
      int k = kb + e;
      float v = (k < 300 && n < 300) ? W[(size_t)k * 300 + n] : 0.f;
      o[e] = (_Float16)v;
    }
  } else if (b < B0 + B1 + B2){
    // x_e f32 -> xh0 f16 [Mpad][320] zero-padded; zero sxi/sxj
    int i = b - B0 - B1;
    _Float16* o = xh0 + (size_t)i * 320;
    if (i < N){
      const float* r = x_e + (size_t)i * 300;
      o[t] = (_Float16)r[t];
      if (t < 44) o[t + 256] = (_Float16)r[t + 256];
      else if (t < 64) o[t + 256] = (_Float16)0.f;
      if (t == 0) sxi[i] = 0.f;
      if (t == 1) sxj[i] = 0.f;
    } else {
      o[t] = (_Float16)0.f;
      if (t < 64) o[t + 256] = (_Float16)0.f;
    }
  } else {
    // sR_i / sR_j dots over relEmb1 rows
    int v = (b - B0 - B1 - B2) * 256 + t;
    if (v >= R) return;
    const float* row = relEmb1 + (size_t)v * 100;
    float a = 0.f, c = 0.f;
    for (int k = 0; k < 100; k++){
      float f = row[k];
      a += f * gatr_ai[k];
      c += f * gatr_aj[k];
    }
    sR_i[v] = a;
    sR_j[v] = c;
  }
}

// two exclusive scans (block 0 -> D, block 1 -> S), 1024 threads, strip-per-thread
__global__ __launch_bounds__(1024)
void k_scan2(const int* __restrict__ cntD, int* __restrict__ offD,
             const int* __restrict__ cntS, int* __restrict__ offS, int n){
  const int* cnt = blockIdx.x ? cntS : cntD;
  int* off = blockIdx.x ? offS : offD;
  int t = threadIdx.x, lane = t & 63, wid = t >> 6;   // 16 waves
  int len = (n + 1023) >> 10;
  int lo = t * len, hi = min(lo + len, n);
  int s = 0;
  for (int k = lo; k < hi; k++) s += cnt[k];
  int ws = s;
  #pragma unroll
  for (int o = 1; o < 64; o <<= 1){
    int u = __shfl_up(ws, o);
    if (lane >= o) ws += u;
  }
  __shared__ int wtot[16];
  if (lane == 63) wtot[wid] = ws;
  __syncthreads();
  int wpre = 0;
  #pragma unroll
  for (int k2 = 0; k2 < 16; k2++) wpre += (k2 < wid) ? wtot[k2] : 0;
  int run = wpre + ws - s;
  for (int k = lo; k < hi; k++){ off[k] = run; run += cnt[k]; }
  if (t == 0){
    int tot = 0;
    #pragma unroll
    for (int k2 = 0; k2 < 16; k2++) tot += wtot[k2];
    off[n] = tot;
  }
}

// fill both CSRs + inv-sqrt degree in one launch (FB fill blocks, then N-cover blocks)
__global__ void k_fill_inv(const int* __restrict__ dstA, const int* __restrict__ srcA,
                           const int* __restrict__ offD, const int* __restrict__ offS,
                           int* __restrict__ curD, int* __restrict__ curS,
                           int* __restrict__ permD, int* __restrict__ permS,
                           const int* __restrict__ degD, float* __restrict__ dis,
                           int E, int N, int FB){
  int b = blockIdx.x, t = threadIdx.x;
  if (b < FB){
    int e = b * 256 + t;
    if (e >= E) return;
    int i = dstA[e];
    permD[offD[i] + atomicAdd(curD + i, 1)] = e;
    int j = srcA[e];
    permS[offS[j] + atomicAdd(curS + j, 1)] = e;
  } else {
    int v = (b - FB) * 256 + t;
    if (v < N){ int d = degD[v]; dis[v] = d > 0 ? rsqrtf((float)d) : 0.f; }
  }
}

// ---------------- CSR gathers: wave-per-node, register accumulate ----------------
__global__ __launch_bounds__(256)
void k_gcn_gather(const int* __restrict__ off, const int* __restrict__ perm,
                  const int* __restrict__ src, const _Float16* __restrict__ x,
                  const float* __restrict__ dis, _Float16* __restrict__ agg, int N){
  int i = (int)(((long)blockIdx.x * blockDim.x + threadIdx.x) >> 6);
  int lane = threadIdx.x & 63;
  if (i >= N) return;
  int p0 = off[i], p1 = off[i+1];
  float di = dis[i];
  float acc[8] = {0.f,0.f,0.f,0.f,0.f,0.f,0.f,0.f};
  for (int base = p0; base < p1; base += 64){
    int m = min(64, p1 - base);
    int jj = 0; float wl = 0.f;
    if (base + lane < p1){
      int e = perm[base + lane];
      jj = src[e];
      wl = di * dis[jj];
    }
    int q = 0;
    for (; q + 1 < m; q += 2){
      int j0 = __shfl(jj, q),   j1 = __shfl(jj, q+1);
      float w0 = __shfl(wl, q), w1 = __shfl(wl, q+1);
      if (lane < 40){
        half8 v0 = *(const half8*)(x + (size_t)j0 * 320 + 8*lane);
        half8 v1 = *(const half8*)(x + (size_t)j1 * 320 + 8*lane);
        #pragma unroll
        for (int k = 0; k < 8; k++) acc[k] += w0 * (float)v0[k] + w1 * (float)v1[k];
      }
    }
    if (q < m){
      int j0 = __shfl(jj, q);
      float w0 = __shfl(wl, q);
      if (lane < 40){
        half8 v0 = *(const half8*)(x + (size_t)j0 * 320 + 8*lane);
        #pragma unroll
        for (int k = 0; k < 8; k++) acc[k] += w0 * (float)v0[k];
      }
    }
  }
  if (lane < 40){
    half8 o;
    #pragma unroll
    for (int k = 0; k < 8; k++) o[k] = (_Float16)fmaxf(acc[k], 0.f);
    *(half8*)(agg + (size_t)i * 320 + 8*lane) = o;
  }
}

// ---------------- MFMA dual-GEMM + highway ----------------
// O = sig(X@Wh + b) * (A1@Wg) + (1-sig)*X ; 16 rows/wave, 64-row panels, XCD swizzle.
__global__ __launch_bounds__(256)
void k_dual_mfma(const _Float16* __restrict__ A1, const _Float16* __restrict__ Xh,
                 const _Float16* __restrict__ Bf1, const _Float16* __restrict__ Bf2,
                 const float* __restrict__ bias, float* __restrict__ Of32, long ldo,
                 _Float16* __restrict__ Oh, long ldm, int M,
                 const float* __restrict__ ww, float* __restrict__ sxi,
                 float* __restrict__ sxj){
  int nb = gridDim.x;
  int q = nb >> 3, r = nb & 7;
  int xcd = blockIdx.x & 7, kk0 = blockIdx.x >> 3;
  int pseudo = (xcd < r ? xcd * (q + 1) : r * (q + 1) + (xcd - r) * q) + kk0;
  int nt = pseudo % 5;
  int panel = pseudo / 5;

  int tid = threadIdx.x;
  int w = tid >> 6, lane = tid & 63;
  int l15 = lane & 15, lg = lane >> 4;
  int rowBase = panel * 64 + w * 16;
  int colBase = nt * 64;

  floatx4 acc1[4], acc2[4];
  #pragma unroll
  for (int b = 0; b < 4; b++){
    acc1[b] = (floatx4){0.f,0.f,0.f,0.f};
    acc2[b] = (floatx4){0.f,0.f,0.f,0.f};
  }

  int row0 = rowBase + l15;
  const _Float16* a1p0 = A1 + (size_t)row0 * 320;
  const _Float16* a2p0 = Xh + (size_t)row0 * 320;

  for (int ks = 0; ks < 10; ks++){
    int kA = ks*32 + lg*8;
    half8 a1f0 = *(const half8*)(a1p0 + kA);
    half8 a2f0 = *(const half8*)(a2p0 + kA);
    const half8* b1p = (const half8*)Bf1 + ((size_t)(ks*5 + nt) * 4 * 64 + lane);
    const half8* b2p = (const half8*)Bf2 + ((size_t)(ks*5 + nt) * 4 * 64 + lane);
    #pragma unroll
    for (int nf = 0; nf < 4; nf++){
      half8 b1 = b1p[nf*64];
      half8 b2 = b2p[nf*64];
      acc1[nf] = __builtin_amdgcn_mfma_f32_16x16x32_f16(a1f0, b1, acc1[nf], 0,0,0);
      acc2[nf] = __builtin_amdgcn_mfma_f32_16x16x32_f16(a2f0, b2, acc2[nf], 0,0,0);
    }
  }

  bool doSX = (sxi != nullptr);
  float dA[4] = {0.f,0.f,0.f,0.f}, dB[4] = {0.f,0.f,0.f,0.f};
  #pragma unroll
  for (int nf = 0; nf < 4; nf++){
    int gn = colBase + nf*16 + l15;
    int gnc = min(gn, 299);
    float bv = bias[gnc];
    float wA = doSX ? ww[gnc] : 0.f;
    float wB = doSX ? ww[400 + gnc] : 0.f;
    #pragma unroll
    for (int r2 = 0; r2 < 4; r2++){
      int gm = rowBase + lg*4 + r2;
      int gmc = min(gm, M-1);
      float xv = (float)Xh[(size_t)gmc * 320 + gnc];
      float g = 1.f / (1.f + expf(-(acc2[nf][r2] + bv)));
      float val = g * acc1[nf][r2] + (1.f - g) * xv;
      if (gm < M && gn < 300){
        if (Of32) Of32[(size_t)gm * ldo + gn] = val;
        if (Oh)   Oh[(size_t)gm * ldm + gn] = (_Float16)val;
        float f = lrelu_f(val);
        dA[r2] += f * wA;
        dB[r2] += f * wB;
      }
    }
  }
  if (doSX){
    #pragma unroll
    for (int r2 = 0; r2 < 4; r2++){
      float a = dA[r2], b = dB[r2];
      #pragma unroll
      for (int o = 1; o < 16; o <<= 1){
        a += __shfl_xor(a, o);
        b += __shfl_xor(b, o);
      }
      int gm = rowBase + lg*4 + r2;
      if (l15 == 0 && gm < M){
        atomAddF(sxi + gm, a);
        atomAddF(sxj + gm, b);
      }
    }
  }
}

// wjq: wave-per-node (grouped by i=row0), fused softmax + gather + head
// + fused GAT logit dots gxi/gxj; stores sumA -> sAl. relEmb read as f16.
__global__ __launch_bounds__(256)
void k_wjq_gather(const int* __restrict__ off, const int* __restrict__ perm,
                  const int* __restrict__ dstA, const int* __restrict__ relI,
                  const float* __restrict__ sxi, const float* __restrict__ sxj,
                  const float* __restrict__ aRel, const _Float16* __restrict__ relEmbH,
                  const float* __restrict__ gat_ai, const float* __restrict__ gat_aj,
                  float* __restrict__ out, _Float16* __restrict__ xh2,
                  float* __restrict__ gxi, float* __restrict__ gxj,
                  float* __restrict__ sAl, int N){
  int i = (int)(((long)blockIdx.x * blockDim.x + threadIdx.x) >> 6);
  int lane = threadIdx.x & 63;
  if (i >= N) return;
  int p0 = off[i], p1 = off[i+1];
  int deg = p1 - p0;
  float si = sxi[i];
  float accx[8] = {0.f,0.f,0.f,0.f,0.f,0.f,0.f,0.f};
  float accr[4] = {0.f,0.f,0.f,0.f};
  float sumA;

  if (deg <= 64){
    int jj = 0, rr = 0; float l = -3.4e38f;
    if (lane < deg){
      int e = perm[p0 + lane];
      jj = dstA[e]; rr = relI[e];
      l = si + sxj[jj] + aRel[rr];
    }
    float lm = l;
    #pragma unroll
    for (int o = 32; o > 0; o >>= 1) lm = fmaxf(lm, __shfl_xor(lm, o));
    float exl = (lane < deg) ? expf(l - lm) : 0.f;
    float ls = exl;
    #pragma unroll
    for (int o = 32; o > 0; o >>= 1) ls += __shfl_xor(ls, o);
    float inv = 1.f / (ls + 1e-16f);
    sumA = ls * inv;
    float wgt = exl * inv;
    int qe = 0;
    for (; qe + 1 < deg; qe += 2){
      int j0 = __shfl(jj, qe),  j1 = __shfl(jj, qe+1);
      int r0 = __shfl(rr, qe),  r1 = __shfl(rr, qe+1);
      float a0 = __shfl(wgt, qe), a1 = __shfl(wgt, qe+1);
      if (lane < 38){
        half8 v0 = *(const half8*)(xh2 + (size_t)j0 * 1024 + 8*lane);
        half8 v1 = *(const half8*)(xh2 + (size_t)j1 * 1024 + 8*lane);
        #pragma unroll
        for (int k = 0; k < 8; k++)
          accx[k] += a0 * lrelu_f((float)v0[k]) + a1 * lrelu_f((float)v1[k]);
      } else if (lane < 63){
        half4 v0 = *(const half4*)(relEmbH + (size_t)r0 * 100 + 4*(lane - 38));
        half4 v1 = *(const half4*)(relEmbH + (size_t)r1 * 100 + 4*(lane - 38));
        #pragma unroll
        for (int k = 0; k < 4; k++)
          accr[k] += a0 * (float)v0[k] + a1 * (float)v1[k];   // relEmb >= 0: lrelu no-op
      }
    }
    if (qe < deg){
      int j0 = __shfl(jj, qe);
      int r0 = __shfl(rr, qe);
      float a0 = __shfl(wgt, qe);
      if (lane < 38){
        half8 v0 = *(const half8*)(xh2 + (size_t)j0 * 1024 + 8*lane);
        #pragma unroll
        for (int k = 0; k < 8; k++) accx[k] += a0 * lrelu_f((float)v0[k]);
      } else if (lane < 63){
        half4 v0 = *(const half4*)(relEmbH + (size_t)r0 * 100 + 4*(lane - 38));
        #pragma unroll
        for (int k = 0; k < 4; k++) accr[k] += a0 * (float)v0[k];
      }
    }
  } else {
    float lm = -3.4e38f;
    for (int p = p0 + lane; p < p1; p += 64){
      int e = perm[p];
      lm = fmaxf(lm, si + sxj[dstA[e]] + aRel[relI[e]]);
    }
    #pragma unroll
    for (int o = 32; o > 0; o >>= 1) lm = fmaxf(lm, __shfl_xor(lm, o));
    float ls = 0.f;
    for (int p = p0 + lane; p < p1; p += 64){
      int e = perm[p];
      ls += expf(si + sxj[dstA[e]] + aRel[relI[e]] - lm);
    }
    #pragma unroll
    for (int o = 32; o > 0; o >>= 1) ls += __shfl_xor(ls, o);
    float inv = 1.f / (ls + 1e-16f);
    sumA = ls * inv;
    for (int base = p0; base < p1; base += 64){
      int m = min(64, p1 - base);
      int jj = 0, rr = 0; float all = 0.f;
      if (base + lane < p1){
        int e = perm[base + lane];
        jj = dstA[e]; rr = relI[e];
        all = expf(si + sxj[jj] + aRel[rr] - lm) * inv;
      }
      for (int qe = 0; qe < m; qe++){
        int j = __shfl(jj, qe);
        int r = __shfl(rr, qe);
        float al = __shfl(all, qe);
        if (lane < 38){
          half8 v = *(const half8*)(xh2 + (size_t)j * 1024 + 8*lane);
          #pragma unroll
          for (int k = 0; k < 8; k++) accx[k] += al * lrelu_f((float)v[k]);
        } else if (lane < 63){
          half4 v = *(const half4*)(relEmbH + (size_t)r * 100 + 4*(lane - 38));
          #pragma unroll
          for (int k = 0; k < 4; k++) accr[k] += al * (float)v[k];
        }
      }
    }
  }

  float* oi = out + (size_t)i * 2000;
  _Float16* hi = xh2 + (size_t)i * 1024;
  float dA = 0.f, dB = 0.f;
  if (lane < 38){
    #pragma unroll
    for (int k = 0; k < 8; k++){
      int c = 8*lane + k;
      if (c < 300){
        oi[700 + c] = accx[k]; hi[700 + c] = (_Float16)accx[k];
        dA += accx[k] * gat_ai[700 + c];
        dB += accx[k] * gat_aj[700 + c];
      }
    }
    half8 v = *(const half8*)(hi + 8*lane);   // x2 f16 (cols 0:300)
    #pragma unroll
    for (int k = 0; k < 8; k++){
      int c = 8*lane + k;
      if (c < 300){
        float x2v = (float)v[k];
        float h = lrelu_f(x2v) * sumA;
        oi[300 + c] = h;
        dA += x2v * gat_ai[c] + h * gat_ai[300 + c];
        dB += x2v * gat_aj[c] + h * gat_aj[300 + c];
      }
    }
  } else if (lane < 63){
    #pragma unroll
    for (int k = 0; k < 4; k++){
      int c = 4*(lane - 38) + k;
      oi[600 + c] = accr[k]; hi[600 + c] = (_Float16)accr[k];
      dA += accr[k] * gat_ai[600 + c];
      dB += accr[k] * gat_aj[600 + c];
    }
  }
  #pragma unroll
  for (int o = 32; o > 0; o >>= 1){
    dA += __shfl_xor(dA, o);
    dB += __shfl_xor(dB, o);
  }
  if (lane == 0){ gxi[i] = dA; gxj[i] = dB; sAl[i] = sumA; }
}

// gat: THREE waves per node. part0: cols 0:300 gather -> out 0:600 (derived via sAl);
// part1: cols 600:800; part2: cols 800:1000. Fused softmax per wave.
__global__ __launch_bounds__(256)
void k_gat_gather(const int* __restrict__ off, const int* __restrict__ perm,
                  const int* __restrict__ srcA, const int* __restrict__ relI,
                  const float* __restrict__ gxi, const float* __restrict__ gxj,
                  const float* __restrict__ srr, const float* __restrict__ sAl,
                  const _Float16* __restrict__ xh2, float* __restrict__ out, int N){
  long gw = ((long)blockIdx.x * blockDim.x + threadIdx.x) >> 6;
  int lane = threadIdx.x & 63;
  int i = (int)(gw / 3), part = (int)(gw % 3);
  if (i >= N) return;
  int p0 = off[i], p1 = off[i+1];
  int deg = p1 - p0;
  float gi = gxi[i];
  int cbase = (part == 0) ? 0 : (400 + part * 200);   // 0 / 600 / 800
  int c0 = cbase + 8*lane;
  bool act = (part == 0) ? (lane < 38) : (lane < 25);
  float acc_a[8] = {0.f,0.f,0.f,0.f,0.f,0.f,0.f,0.f};
  float acc_b[8] = {0.f,0.f,0.f,0.f,0.f,0.f,0.f,0.f};

  if (deg <= 64){
    int jj = 0; float l = -3.4e38f, saj = 0.f;
    if (lane < deg){
      int e = perm[p0 + lane];
      jj = srcA[e];
      l = lrelu_f(gi + gxj[jj] + srr[relI[e]]);
      if (part == 0) saj = sAl[jj];
    }
    float lm = l;
    #pragma unroll
    for (int o = 32; o > 0; o >>= 1) lm = fmaxf(lm, __shfl_xor(lm, o));
    float exl = (lane < deg) ? expf(l - lm) : 0.f;
    float ls = exl;
    #pragma unroll
    for (int o = 32; o > 0; o >>= 1) ls += __shfl_xor(ls, o);
    float wgt = exl / (ls + 1e-16f);
    if (part == 0){
      int qe = 0;
      for (; qe + 1 < deg; qe += 2){
        int j0 = __shfl(jj, qe),    j1 = __shfl(jj, qe+1);
        float a0 = __shfl(wgt, qe), a1 = __shfl(wgt, qe+1);
        float s0 = __shfl(saj, qe) * a0, s1 = __shfl(saj, qe+1) * a1;
        if (act){
          half8 v0 = *(const half8*)(xh2 + (size_t)j0 * 1024 + 8*lane);
          half8 v1 = *(const half8*)(xh2 + (size_t)j1 * 1024 + 8*lane);
          #pragma unroll
          for (int k = 0; k < 8; k++){
            float x0 = (float)v0[k], x1 = (float)v1[k];
            acc_a[k] += a0 * x0 + a1 * x1;
            acc_b[k] += s0 * lrelu_f(x0) + s1 * lrelu_f(x1);
          }
        }
      }
      if (qe < deg){
        int j0 = __shfl(jj, qe);
        float a0 = __shfl(wgt, qe);
        float s0 = __shfl(saj, qe) * a0;
        if (act){
          half8 v0 = *(const half8*)(xh2 + (size_t)j0 * 1024 + 8*lane);
          #pragma unroll
          for (int k = 0; k < 8; k++){
            float x0 = (float)v0[k];
            acc_a[k] += a0 * x0;
            acc_b[k] += s0 * lrelu_f(x0);
          }
        }
      }
    } else {
      int qe = 0;
      for (; qe + 1 < deg; qe += 2){
        int j0 = __shfl(jj, qe),    j1 = __shfl(jj, qe+1);
        float a0 = __shfl(wgt, qe), a1 = __shfl(wgt, qe+1);
        if (act){
          half8 v0 = *(const half8*)(xh2 + (size_t)j0 * 1024 + c0);
          half8 v1 = *(const half8*)(xh2 + (size_t)j1 * 1024 + c0);
          #pragma unroll
          for (int k = 0; k < 8; k++) acc_a[k] += a0 * (float)v0[k] + a1 * (float)v1[k];
        }
      }
      if (qe < deg){
        int j0 = __shfl(jj, qe);
        float a0 = __shfl(wgt, qe);
        if (act){
          half8 v0 = *(const half8*)(xh2 + (size_t)j0 * 1024 + c0);
          #pragma unroll
          for (int k = 0; k < 8; k++) acc_a[k] += a0 * (float)v0[k];
        }
      }
    }
  } else {
    float lm = -3.4e38f;
    for (int p = p0 + lane; p < p1; p += 64){
      int e = perm[p];
      lm = fmaxf(lm, lrelu_f(gi + gxj[srcA[e]] + srr[relI[e]]));
    }
    #pragma unroll
    for (int o = 32; o > 0; o >>= 1) lm = fmaxf(lm, __shfl_xor(lm, o));
    float ls = 0.f;
    for (int p = p0 + lane; p < p1; p += 64){
      int e = perm[p];
      ls += expf(lrelu_f(gi + gxj[srcA[e]] + srr[relI[e]]) - lm);
    }
    #pragma unroll
    for (int o = 32; o > 0; o >>= 1) ls += __shfl_xor(ls, o);
    float inv = 1.f / (ls + 1e-16f);
    for (int base = p0; base < p1; base += 64){
      int m = min(64, p1 - base);
      int jj = 0; float all = 0.f, saj = 0.f;
      if (base + lane < p1){
        int e = perm[base + lane];
        jj = srcA[e];
        all = expf(lrelu_f(gi + gxj[jj] + srr[relI[e]]) - lm) * inv;
        if (part == 0) saj = sAl[jj];
      }
      for (int qe = 0; qe < m; qe++){
        int j = __shfl(jj, qe);
        float al = __shfl(all, qe);
        if (part == 0){
          float sa = __shfl(saj, qe) * al;
          if (act){
            half8 v = *(const half8*)(xh2 + (size_t)j * 1024 + 8*lane);
            #pragma unroll
            for (int k = 0; k < 8; k++){
              float x0 = (float)v[k];
              acc_a[k] += al * x0;
              acc_b[k] += sa * lrelu_f(x0);
            }
          }
        } else {
          if (act){
            half8 v = *(const half8*)(xh2 + (size_t)j * 1024 + c0);
            #pragma unroll
            for (int k = 0; k < 8; k++) acc_a[k] += al * (float)v[k];
          }
        }
      }
    }
  }

  float* ob = out + (size_t)i * 2000 + 1000;
  if (part == 0){
    if (lane < 37){
      floatx4 s0, s1, t0, t1;
      #pragma unroll
      for (int k = 0; k < 4; k++){
        s0[k] = fmaxf(acc_a[k], 0.f);   s1[k] = fmaxf(acc_a[4+k], 0.f);
        t0[k] = fmaxf(acc_b[k], 0.f);   t1[k] = fmaxf(acc_b[4+k], 0.f);
      }
      *(floatx4*)(ob + 8*lane) = s0;
      *(floatx4*)(ob + 8*lane + 4) = s1;
      *(floatx4*)(ob + 300 + 8*lane) = t0;
      *(floatx4*)(ob + 300 + 8*lane + 4) = t1;
    } else if (lane == 37){
      #pragma unroll
      for (int k = 0; k < 4; k++){       // cols 296..299
        ob[296 + k] = fmaxf(acc_a[k], 0.f);
        ob[596 + k] = fmaxf(acc_b[k], 0.f);
      }
    }
  } else {
    if (lane < 25){
      floatx4 s0, s1;
      #pragma unroll
      for (int k = 0; k < 4; k++){ s0[k] = fmaxf(acc_a[k], 0.f); s1[k] = fmaxf(acc_a[4+k], 0.f); }
      *(floatx4*)(ob + c0) = s0;
      *(floatx4*)(ob + c0 + 4) = s1;
    }
  }
}

// relu relEmb in place + f16 mirror + two dots (ww1 mid, gat_ar)
__global__ void k_relu_dots(float* __restrict__ relEmb, _Float16* __restrict__ relEmbH,
                            const float* __restrict__ wA, const float* __restrict__ wB,
                            float* __restrict__ aRel, float* __restrict__ srr, int n){
  int v = blockIdx.x * blockDim.x + threadIdx.x;
  if (v >= n) return;
  float* row = relEmb + (size_t)v * 100;
  _Float16* rowH = relEmbH + (size_t)v * 100;
  float a = 0.f, b = 0.f;
  for (int c = 0; c < 100; c++){
    float f = fmaxf(row[c], 0.f);
    row[c] = f;
    rowH[c] = (_Float16)f;
    a += f * wA[c];
    b += f * wB[c];
  }
  aRel[v] = a;
  srr[v] = b;
}

// ---- merged line-graph (gat_r) chain: logit+exp in one pass (softmax shift-invariant,
// logits are O(0.05) so exp without max subtraction is numerically safe) ----
__global__ void k_lg_le(const int* __restrict__ lgOut, const int* __restrict__ lgIn,
                        int ELG, int R, const float* __restrict__ sR_i,
                        const float* __restrict__ sR_j,
                        float* __restrict__ elog, float* __restrict__ sumR){
  int e = blockIdx.x * blockDim.x + threadIdx.x;
  if (e >= 2*ELG) return;
  int g = e >= ELG;
  int el = e - g*ELG;
  const int* lg = g ? lgIn : lgOut;
  int j = lg[el], i = lg[el + ELG];
  float ex = expf(lrelu_f(sR_j[j] + sR_i[i]));
  elog[e] = ex;
  atomAddF(sumR + g*R + j, ex);
}

__global__ void k_lg_scatter(const int* __restrict__ lgOut, const int* __restrict__ lgIn,
                             int ELG, int R, const float* __restrict__ ex,
                             const float* __restrict__ sumR,
                             const float* __restrict__ relEmb1, float* __restrict__ relEmb){
  int e = blockIdx.x;
  int g = e >= ELG;
  int el = e - g*ELG;
  const int* lg = g ? lgIn : lgOut;
  int j = lg[el], i = lg[el + ELG];
  float alpha = ex[e] / (sumR[g*R + j] + 1e-16f);
  const float* xj = relEmb1 + (size_t)j * 100;
  float* oi = relEmb + (size_t)(g*R + i) * 100;
  for (int c = threadIdx.x; c < 100; c += blockDim.x)
    atomAddF(oi + c, alpha * xj[c]);
}

extern "C" void kernel_launch(void* const* d_in, const int* in_sizes, int n_in,
                              void* d_out, int out_size, void* d_ws, size_t ws_size,
                              hipStream_t stream){
  const float* x_e     = (const float*)d_in[0];
  const int*   eiA     = (const int*)  d_in[3];   // edge_index_all [2,E]
  const int*   relAll  = (const int*)  d_in[4];
  const int*   lgOut   = (const int*)  d_in[5];
  const int*   lgIn    = (const int*)  d_in[7];
  const float* gcn1_w  = (const float*)d_in[9];
  const float* gcn2_w  = (const float*)d_in[10];
  const float* hw1_w   = (const float*)d_in[11];
  const float* hw1_b   = (const float*)d_in[12];
  const float* hw2_w   = (const float*)d_in[13];
  const float* hw2_b   = (const float*)d_in[14];
  const float* ww1     = (const float*)d_in[15];
  const float* gat_ai  = (const float*)d_in[16];
  const float* gat_aj  = (const float*)d_in[17];
  const float* gat_ar  = (const float*)d_in[18];
  const float* gatr_ai = (const float*)d_in[19];
  const float* gatr_aj = (const float*)d_in[20];
  const float* relEmb1 = (const float*)d_in[21];

  const int EH = 300, RH = 100;
  const int N   = in_sizes[0] / EH;
  const int E   = in_sizes[3] / 2;
  const int ELG = in_sizes[5] / 2;
  const int R   = in_sizes[21] / RH;
  const int Mtiles = (N + 127) / 128;
  const int Mpad = Mtiles * 128;

  // ---- workspace layout (16B-aligned f16 blocks first) ----
  char* base = (char*)d_ws;
  _Float16* xh0   = (_Float16*)base;  base += (size_t)Mpad * 320 * 2;   // x_e f16
  _Float16* xhA   = (_Float16*)base;  base += (size_t)Mpad * 320 * 2;   // x1 f16
  _Float16* A1f16 = (_Float16*)base;  base += (size_t)Mpad * 320 * 2;   // relu(agg) f16
  _Float16* xh2   = (_Float16*)base;  base += (size_t)N * 1024 * 2;     // x_wjq f16 mirror
  _Float16* BfAll = (_Float16*)base;  base += (size_t)4 * 102400 * 2;
  _Float16* relEmbH = (_Float16*)base; base += (size_t)2 * R * RH * 2;  // relEmb f16
  float* w = (float*)base;
  float* dis    = w; w += N;
  float* relEmb = w; w += (size_t)2 * R * RH;   // relEmb then sumR contiguous (one memset)
  float* sumR   = w; w += 2 * R;
  float* sxi    = w; w += N;
  float* sxj    = w; w += N;
  float* gxi    = w; w += N;
  float* gxj    = w; w += N;
  float* sAl    = w; w += N;
  float* sR_i   = w; w += R;
  float* sR_j   = w; w += R;
  float* aRel   = w; w += 2 * R;
  float* srr    = w; w += 2 * R;
  float* eE     = w; w += E;
  int* degD   = (int*)w; w += N;
  int* degS   = (int*)w; w += N;
  int* curD   = (int*)w; w += N;
  int* curS   = (int*)w; w += N;
  int* offD   = (int*)w; w += N + 1;
  int* offS   = (int*)w; w += N + 1;
  int* permD  = (int*)w; w += E;
  int* permS  = (int*)w; w += E;

  _Float16* Bf_g1 = BfAll;
  _Float16* Bf_h1 = BfAll + 102400;
  _Float16* Bf_g2 = BfAll + 2 * 102400;
  _Float16* Bf_h2 = BfAll + 3 * 102400;

  float* out = (float*)d_out;
  const int* srcA = eiA;         // row0 (j in gcn/gat, i in wjq)
  const int* dstA = eiA + E;     // row1

  auto cdiv = [](int a, int b){ return (a + b - 1) / b; };

  // ---- fused setup: degree count + weight pack + f16 convert + sR dots ----
  hipMemsetAsync(degD, 0, (size_t)4 * N * 4, stream);   // degD,degS,curD,curS contiguous
  int B0 = cdiv(E,256), B1 = 200, B2 = Mpad, B3 = cdiv(R,256);
  k_setup<<<B0+B1+B2+B3,256,0,stream>>>(dstA, srcA, degD, degS, E,
                                        gcn1_w, hw1_w, gcn2_w, hw2_w, BfAll,
                                        x_e, xh0, sxi, sxj, N,
                                        relEmb1, gatr_ai, gatr_aj, sR_i, sR_j, R,
                                        B0, B1, B2);
  k_scan2<<<2,1024,0,stream>>>(degD, offD, degS, offS, N);
  int FB = cdiv(E,256);
  k_fill_inv<<<FB + cdiv(N,256),256,0,stream>>>(dstA, srcA, offD, offS, curD, curS,
                                                permD, permS, degD, dis, E, N, FB);

  int NB = 5 * (Mpad / 64);   // 64-row panels
  int GW = cdiv(N, 4);        // wave-per-node grids

  // layer 1: x1 = highway(x_e, gcn(x_e)) -> xhA (f16 mirror only)
  k_gcn_gather<<<GW,256,0,stream>>>(offD, permD, srcA, xh0, dis, A1f16, N);
  k_dual_mfma<<<NB,256,0,stream>>>(A1f16, xh0, Bf_g1, Bf_h1, hw1_b,
                                   nullptr, 0, xhA, 320, N, nullptr, nullptr, nullptr);

  // layer 2: x2 = highway(x1, gcn(x1)) -> out cols 0:300 + xh2 cols 0:300 + sxi/sxj dots
  k_gcn_gather<<<GW,256,0,stream>>>(offD, permD, srcA, xhA, dis, A1f16, N);
  k_dual_mfma<<<NB,256,0,stream>>>(A1f16, xhA, Bf_g2, Bf_h2, hw2_b,
                                   out, 2000, xh2, 1024, N, ww1, sxi, sxj);

  // gat_r -> relEmb [2R,100]  (merged out/in graphs, atomic path, no max pass)
  hipMemsetAsync(relEmb, 0, ((size_t)2*R*RH + 2*R) * 4, stream);   // relEmb + sumR
  k_lg_le<<<cdiv(2*ELG,256),256,0,stream>>>(lgOut, lgIn, ELG, R, sR_i, sR_j, eE, sumR);
  k_lg_scatter<<<2*ELG,128,0,stream>>>(lgOut, lgIn, ELG, R, eE, sumR, relEmb1, relEmb);

  // relu relEmb + f16 mirror + aRel (ww1 mid) + srr (gat_ar) in one pass
  k_relu_dots<<<cdiv(2*R,256),256,0,stream>>>(relEmb, relEmbH, ww1 + EH, gat_ar, aRel, srr, 2*R);

  // wjq: fused softmax + gather + head + gat-logit dots (gxi,gxj) + sAl
  k_wjq_gather<<<GW,256,0,stream>>>(offS, permS, dstA, relAll, sxi, sxj, aRel, relEmbH,
                                    gat_ai, gat_aj, out, xh2, gxi, gxj, sAl, N);

  // gat: fused softmax + gather + relu, 3 waves/node
  k_gat_gather<<<cdiv(3*N,4),256,0,stream>>>(offD, permD, srcA, relAll, gxi, gxj, srr,
                                             sAl, xh2, out, N);
}

// Round 12
// 361.885 us; speedup vs baseline: 5.7798x; 1.0325x over previous
//
#include <hip/hip_runtime.h>
#include <math.h>

#define LSL 0.01f

typedef _Float16 half8 __attribute__((ext_vector_type(8)));
typedef _Float16 half4 __attribute__((ext_vector_type(4)));
typedef float floatx4 __attribute__((ext_vector_type(4)));

static __device__ __forceinline__ float lrelu_f(float x){ return x > 0.f ? x : LSL * x; }
static __device__ __forceinline__ void atomAddF(float* p, float v){ unsafeAtomicAdd(p, v); }

// ---------------- fused setup: count2 | prep_B4 | conv_f16 | sR dots ----------------
__global__ __launch_bounds__(256)
void k_setup(const int* __restrict__ dstA, const int* __restrict__ srcA,
             int* __restrict__ degD, int* __restrict__ degS, int E,
             const float* __restrict__ W0, const float* __restrict__ W1,
             const float* __restrict__ W2, const float* __restrict__ W3,
             _Float16* __restrict__ BfAll,
             const float* __restrict__ x_e, _Float16* __restrict__ xh0,
             float* __restrict__ sxi, float* __restrict__ sxj, int N,
             const float* __restrict__ relEmb1, const float* __restrict__ gatr_ai,
             const float* __restrict__ gatr_aj, float* __restrict__ sR_i,
             float* __restrict__ sR_j, int R, int B0, int B1, int B2){
  int b = blockIdx.x, t = threadIdx.x;
  if (b < B0){
    int e = b * 256 + t;
    if (e < E){ atomicAdd(degD + dstA[e], 1); atomicAdd(degS + srcA[e], 1); }
  } else if (b < B0 + B1){
    int idx = (b - B0) * 256 + t;
    if (idx >= 4*12800) return;
    int wsel = idx / 12800;
    int rem2 = idx % 12800;
    const float* W = (wsel == 0) ? W0 : (wsel == 1) ? W1 : (wsel == 2) ? W2 : W3;
    int lane = rem2 & 63;
    int rem = rem2 >> 6;
    int nf = rem & 3; rem >>= 2;
    int nt = rem % 5;
    int ks = rem / 5;
    int n = nt*64 + nf*16 + (lane & 15);
    int kb = ks*32 + (lane >> 4) * 8;
    _Float16* o = BfAll + (size_t)wsel * 102400 + (size_t)rem2 * 8;
    #pragma unroll
    for (int e = 0; e < 8; e++){
      int k = kb + e;
      float v = (k < 300 && n < 300) ? W[(size_t)k * 300 + n] : 0.f;
      o[e] = (_Float16)v;
    }
  } else if (b < B0 + B1 + B2){
    int i = b - B0 - B1;
    _Float16* o = xh0 + (size_t)i * 320;
    if (i < N){
      const float* r = x_e + (size_t)i * 300;
      o[t] = (_Float16)r[t];
      if (t < 44) o[t + 256] = (_Float16)r[t + 256];
      else if (t < 64) o[t + 256] = (_Float16)0.f;
      if (t == 0) sxi[i] = 0.f;
      if (t == 1) sxj[i] = 0.f;
    } else {
      o[t] = (_Float16)0.f;
      if (t < 64) o[t + 256] = (_Float16)0.f;
    }
  } else {
    int v = (b - B0 - B1 - B2) * 256 + t;
    if (v >= R) return;
    const float* row = relEmb1 + (size_t)v * 100;
    float a = 0.f, c = 0.f;
    for (int k = 0; k < 100; k++){
      float f = row[k];
      a += f * gatr_ai[k];
      c += f * gatr_aj[k];
    }
    sR_i[v] = a;
    sR_j[v] = c;
  }
}

// two exclusive scans (block 0 -> D, block 1 -> S), 1024 threads, strip-per-thread
__global__ __launch_bounds__(1024)
void k_scan2(const int* __restrict__ cntD, int* __restrict__ offD,
             const int* __restrict__ cntS, int* __restrict__ offS, int n){
  const int* cnt = blockIdx.x ? cntS : cntD;
  int* off = blockIdx.x ? offS : offD;
  int t = threadIdx.x, lane = t & 63, wid = t >> 6;   // 16 waves
  int len = (n + 1023) >> 10;
  int lo = t * len, hi = min(lo + len, n);
  int s = 0;
  for (int k = lo; k < hi; k++) s += cnt[k];
  int ws = s;
  #pragma unroll
  for (int o = 1; o < 64; o <<= 1){
    int u = __shfl_up(ws, o);
    if (lane >= o) ws += u;
  }
  __shared__ int wtot[16];
  if (lane == 63) wtot[wid] = ws;
  __syncthreads();
  int wpre = 0;
  #pragma unroll
  for (int k2 = 0; k2 < 16; k2++) wpre += (k2 < wid) ? wtot[k2] : 0;
  int run = wpre + ws - s;
  for (int k = lo; k < hi; k++){ off[k] = run; run += cnt[k]; }
  if (t == 0){
    int tot = 0;
    #pragma unroll
    for (int k2 = 0; k2 < 16; k2++) tot += wtot[k2];
    off[n] = tot;
  }
}

// fill both CSRs + inv-sqrt degree in one launch (FB fill blocks, then N-cover blocks)
__global__ void k_fill_inv(const int* __restrict__ dstA, const int* __restrict__ srcA,
                           const int* __restrict__ offD, const int* __restrict__ offS,
                           int* __restrict__ curD, int* __restrict__ curS,
                           int* __restrict__ permD, int* __restrict__ permS,
                           const int* __restrict__ degD, float* __restrict__ dis,
                           int E, int N, int FB){
  int b = blockIdx.x, t = threadIdx.x;
  if (b < FB){
    int e = b * 256 + t;
    if (e >= E) return;
    int i = dstA[e];
    permD[offD[i] + atomicAdd(curD + i, 1)] = e;
    int j = srcA[e];
    permS[offS[j] + atomicAdd(curS + j, 1)] = e;
  } else {
    int v = (b - FB) * 256 + t;
    if (v < N){ int d = degD[v]; dis[v] = d > 0 ? rsqrtf((float)d) : 0.f; }
  }
}

// ---------------- CSR gather (gcn) + fused small work in trailing blocks ----------------
// mode 1: lg_le (line-graph logit+exp); mode 2: relu_dots (relEmb relu + f16 + dots)
__global__ __launch_bounds__(256)
void k_gcn_gather(const int* __restrict__ off, const int* __restrict__ perm,
                  const int* __restrict__ src, const _Float16* __restrict__ x,
                  const float* __restrict__ dis, _Float16* __restrict__ agg, int N,
                  int GWB, int mode,
                  const int* __restrict__ lgOut, const int* __restrict__ lgIn,
                  int ELG, int R, const float* __restrict__ sR_i,
                  const float* __restrict__ sR_j, float* __restrict__ eE,
                  float* __restrict__ sumR,
                  float* __restrict__ relEmb, _Float16* __restrict__ relEmbH,
                  const float* __restrict__ wA, const float* __restrict__ wB,
                  float* __restrict__ aRel, float* __restrict__ srr){
  if (blockIdx.x >= GWB){
    int idx = (blockIdx.x - GWB) * 256 + threadIdx.x;
    if (mode == 1){
      if (idx >= 2*ELG) return;
      int g = idx >= ELG;
      int el = idx - g*ELG;
      const int* lg = g ? lgIn : lgOut;
      int j = lg[el], i2 = lg[el + ELG];
      float ex = expf(lrelu_f(sR_j[j] + sR_i[i2]));
      eE[idx] = ex;
      atomAddF(sumR + g*R + j, ex);
    } else {
      if (idx >= 2*R) return;
      float* row = relEmb + (size_t)idx * 100;
      _Float16* rowH = relEmbH + (size_t)idx * 100;
      float a = 0.f, b2 = 0.f;
      for (int c = 0; c < 100; c++){
        float f = fmaxf(row[c], 0.f);
        row[c] = f;
        rowH[c] = (_Float16)f;
        a += f * wA[c];
        b2 += f * wB[c];
      }
      aRel[idx] = a;
      srr[idx] = b2;
    }
    return;
  }
  int i = (int)(((long)blockIdx.x * blockDim.x + threadIdx.x) >> 6);
  int lane = threadIdx.x & 63;
  if (i >= N) return;
  int p0 = off[i], p1 = off[i+1];
  float di = dis[i];
  float acc[8] = {0.f,0.f,0.f,0.f,0.f,0.f,0.f,0.f};
  for (int base = p0; base < p1; base += 64){
    int m = min(64, p1 - base);
    int jj = 0; float wl = 0.f;
    if (base + lane < p1){
      int e = perm[base + lane];
      jj = src[e];
      wl = di * dis[jj];
    }
    int q = 0;
    for (; q + 1 < m; q += 2){
      int j0 = __shfl(jj, q),   j1 = __shfl(jj, q+1);
      float w0 = __shfl(wl, q), w1 = __shfl(wl, q+1);
      if (lane < 38){      // cols 0:304 only — A1 cols >=300 multiply zero-packed B rows
        half8 v0 = *(const half8*)(x + (size_t)j0 * 320 + 8*lane);
        half8 v1 = *(const half8*)(x + (size_t)j1 * 320 + 8*lane);
        #pragma unroll
        for (int k = 0; k < 8; k++) acc[k] += w0 * (float)v0[k] + w1 * (float)v1[k];
      }
    }
    if (q < m){
      int j0 = __shfl(jj, q);
      float w0 = __shfl(wl, q);
      if (lane < 38){
        half8 v0 = *(const half8*)(x + (size_t)j0 * 320 + 8*lane);
        #pragma unroll
        for (int k = 0; k < 8; k++) acc[k] += w0 * (float)v0[k];
      }
    }
  }
  if (lane < 38){
    half8 o;
    #pragma unroll
    for (int k = 0; k < 8; k++) o[k] = (_Float16)fmaxf(acc[k], 0.f);
    *(half8*)(agg + (size_t)i * 320 + 8*lane) = o;
  }
}

// ---------------- MFMA dual-GEMM + highway (+optional fused lg_scatter blocks) ----------------
__global__ __launch_bounds__(256)
void k_dual_mfma(const _Float16* __restrict__ A1, const _Float16* __restrict__ Xh,
                 const _Float16* __restrict__ Bf1, const _Float16* __restrict__ Bf2,
                 const float* __restrict__ bias, float* __restrict__ Of32, long ldo,
                 _Float16* __restrict__ Oh, long ldm, int M,
                 const float* __restrict__ ww, float* __restrict__ sxi,
                 float* __restrict__ sxj, int NBm,
                 const int* __restrict__ lgOut, const int* __restrict__ lgIn,
                 int ELG, int R, const float* __restrict__ eE,
                 const float* __restrict__ sumR, const float* __restrict__ relEmb1,
                 float* __restrict__ relEmbO){
  if (blockIdx.x >= NBm){
    // fused line-graph scatter: 2 edges per 256-thread block
    int t = threadIdx.x;
    int e = (blockIdx.x - NBm) * 2 + (t >> 7);
    if (e >= 2*ELG) return;
    int g = e >= ELG;
    int el = e - g*ELG;
    const int* lg = g ? lgIn : lgOut;
    int j = lg[el], i2 = lg[el + ELG];
    float alpha = eE[e] / (sumR[g*R + j] + 1e-16f);
    int tt = t & 127;
    if (tt < 100)
      atomAddF(relEmbO + (size_t)(g*R + i2) * 100 + tt,
               alpha * relEmb1[(size_t)j * 100 + tt]);
    return;
  }
  int nb = NBm;
  int q = nb >> 3, r = nb & 7;
  int xcd = blockIdx.x & 7, kk0 = blockIdx.x >> 3;
  int pseudo = (xcd < r ? xcd * (q + 1) : r * (q + 1) + (xcd - r) * q) + kk0;
  int nt = pseudo % 5;
  int panel = pseudo / 5;

  int tid = threadIdx.x;
  int w = tid >> 6, lane = tid & 63;
  int l15 = lane & 15, lg2 = lane >> 4;
  int rowBase = panel * 64 + w * 16;
  int colBase = nt * 64;

  floatx4 acc1[4], acc2[4];
  #pragma unroll
  for (int b = 0; b < 4; b++){
    acc1[b] = (floatx4){0.f,0.f,0.f,0.f};
    acc2[b] = (floatx4){0.f,0.f,0.f,0.f};
  }

  int row0 = rowBase + l15;
  const _Float16* a1p0 = A1 + (size_t)row0 * 320;
  const _Float16* a2p0 = Xh + (size_t)row0 * 320;

  for (int ks = 0; ks < 10; ks++){
    int kA = ks*32 + lg2*8;
    half8 a1f0 = *(const half8*)(a1p0 + kA);
    half8 a2f0 = *(const half8*)(a2p0 + kA);
    const half8* b1p = (const half8*)Bf1 + ((size_t)(ks*5 + nt) * 4 * 64 + lane);
    const half8* b2p = (const half8*)Bf2 + ((size_t)(ks*5 + nt) * 4 * 64 + lane);
    #pragma unroll
    for (int nf = 0; nf < 4; nf++){
      half8 b1 = b1p[nf*64];
      half8 b2 = b2p[nf*64];
      acc1[nf] = __builtin_amdgcn_mfma_f32_16x16x32_f16(a1f0, b1, acc1[nf], 0,0,0);
      acc2[nf] = __builtin_amdgcn_mfma_f32_16x16x32_f16(a2f0, b2, acc2[nf], 0,0,0);
    }
  }

  bool doSX = (sxi != nullptr);
  float dA[4] = {0.f,0.f,0.f,0.f}, dB[4] = {0.f,0.f,0.f,0.f};
  #pragma unroll
  for (int nf = 0; nf < 4; nf++){
    int gn = colBase + nf*16 + l15;
    int gnc = min(gn, 299);
    float bv = bias[gnc];
    float wA = doSX ? ww[gnc] : 0.f;
    float wB = doSX ? ww[400 + gnc] : 0.f;
    #pragma unroll
    for (int r2 = 0; r2 < 4; r2++){
      int gm = rowBase + lg2*4 + r2;
      int gmc = min(gm, M-1);
      float xv = (float)Xh[(size_t)gmc * 320 + gnc];
      float g = 1.f / (1.f + expf(-(acc2[nf][r2] + bv)));
      float val = g * acc1[nf][r2] + (1.f - g) * xv;
      if (gm < M && gn < 300){
        if (Of32) Of32[(size_t)gm * ldo + gn] = val;
        if (Oh)   Oh[(size_t)gm * ldm + gn] = (_Float16)val;
        float f = lrelu_f(val);
        dA[r2] += f * wA;
        dB[r2] += f * wB;
      }
    }
  }
  if (doSX){
    #pragma unroll
    for (int r2 = 0; r2 < 4; r2++){
      float a = dA[r2], b = dB[r2];
      #pragma unroll
      for (int o = 1; o < 16; o <<= 1){
        a += __shfl_xor(a, o);
        b += __shfl_xor(b, o);
      }
      int gm = rowBase + lg2*4 + r2;
      if (l15 == 0 && gm < M){
        atomAddF(sxi + gm, a);
        atomAddF(sxj + gm, b);
      }
    }
  }
}

// wjq: wave-per-node (grouped by i=row0), fused softmax + gather + head
// + fused GAT logit dots gxi/gxj; stores sumA -> sAl. relEmb read as f16.
__global__ __launch_bounds__(256)
void k_wjq_gather(const int* __restrict__ off, const int* __restrict__ perm,
                  const int* __restrict__ dstA, const int* __restrict__ relI,
                  const float* __restrict__ sxi, const float* __restrict__ sxj,
                  const float* __restrict__ aRel, const _Float16* __restrict__ relEmbH,
                  const float* __restrict__ gat_ai, const float* __restrict__ gat_aj,
                  float* __restrict__ out, _Float16* __restrict__ xh2,
                  float* __restrict__ gxi, float* __restrict__ gxj,
                  float* __restrict__ sAl, int N){
  int i = (int)(((long)blockIdx.x * blockDim.x + threadIdx.x) >> 6);
  int lane = threadIdx.x & 63;
  if (i >= N) return;
  int p0 = off[i], p1 = off[i+1];
  int deg = p1 - p0;
  float si = sxi[i];
  float accx[8] = {0.f,0.f,0.f,0.f,0.f,0.f,0.f,0.f};
  float accr[4] = {0.f,0.f,0.f,0.f};
  float sumA;

  if (deg <= 64){
    int jj = 0, rr = 0; float l = -3.4e38f;
    if (lane < deg){
      int e = perm[p0 + lane];
      jj = dstA[e]; rr = relI[e];
      l = si + sxj[jj] + aRel[rr];
    }
    float lm = l;
    #pragma unroll
    for (int o = 32; o > 0; o >>= 1) lm = fmaxf(lm, __shfl_xor(lm, o));
    float exl = (lane < deg) ? expf(l - lm) : 0.f;
    float ls = exl;
    #pragma unroll
    for (int o = 32; o > 0; o >>= 1) ls += __shfl_xor(ls, o);
    float inv = 1.f / (ls + 1e-16f);
    sumA = ls * inv;
    float wgt = exl * inv;
    int qe = 0;
    for (; qe + 1 < deg; qe += 2){
      int j0 = __shfl(jj, qe),  j1 = __shfl(jj, qe+1);
      int r0 = __shfl(rr, qe),  r1 = __shfl(rr, qe+1);
      float a0 = __shfl(wgt, qe), a1 = __shfl(wgt, qe+1);
      if (lane < 38){
        half8 v0 = *(const half8*)(xh2 + (size_t)j0 * 1024 + 8*lane);
        half8 v1 = *(const half8*)(xh2 + (size_t)j1 * 1024 + 8*lane);
        #pragma unroll
        for (int k = 0; k < 8; k++)
          accx[k] += a0 * lrelu_f((float)v0[k]) + a1 * lrelu_f((float)v1[k]);
      } else if (lane < 63){
        half4 v0 = *(const half4*)(relEmbH + (size_t)r0 * 100 + 4*(lane - 38));
        half4 v1 = *(const half4*)(relEmbH + (size_t)r1 * 100 + 4*(lane - 38));
        #pragma unroll
        for (int k = 0; k < 4; k++)
          accr[k] += a0 * (float)v0[k] + a1 * (float)v1[k];   // relEmb >= 0: lrelu no-op
      }
    }
    if (qe < deg){
      int j0 = __shfl(jj, qe);
      int r0 = __shfl(rr, qe);
      float a0 = __shfl(wgt, qe);
      if (lane < 38){
        half8 v0 = *(const half8*)(xh2 + (size_t)j0 * 1024 + 8*lane);
        #pragma unroll
        for (int k = 0; k < 8; k++) accx[k] += a0 * lrelu_f((float)v0[k]);
      } else if (lane < 63){
        half4 v0 = *(const half4*)(relEmbH + (size_t)r0 * 100 + 4*(lane - 38));
        #pragma unroll
        for (int k = 0; k < 4; k++) accr[k] += a0 * (float)v0[k];
      }
    }
  } else {
    float lm = -3.4e38f;
    for (int p = p0 + lane; p < p1; p += 64){
      int e = perm[p];
      lm = fmaxf(lm, si + sxj[dstA[e]] + aRel[relI[e]]);
    }
    #pragma unroll
    for (int o = 32; o > 0; o >>= 1) lm = fmaxf(lm, __shfl_xor(lm, o));
    float ls = 0.f;
    for (int p = p0 + lane; p < p1; p += 64){
      int e = perm[p];
      ls += expf(si + sxj[dstA[e]] + aRel[relI[e]] - lm);
    }
    #pragma unroll
    for (int o = 32; o > 0; o >>= 1) ls += __shfl_xor(ls, o);
    float inv = 1.f / (ls + 1e-16f);
    sumA = ls * inv;
    for (int base = p0; base < p1; base += 64){
      int m = min(64, p1 - base);
      int jj = 0, rr = 0; float all = 0.f;
      if (base + lane < p1){
        int e = perm[base + lane];
        jj = dstA[e]; rr = relI[e];
        all = expf(si + sxj[jj] + aRel[rr] - lm) * inv;
      }
      for (int qe = 0; qe < m; qe++){
        int j = __shfl(jj, qe);
        int r = __shfl(rr, qe);
        float al = __shfl(all, qe);
        if (lane < 38){
          half8 v = *(const half8*)(xh2 + (size_t)j * 1024 + 8*lane);
          #pragma unroll
          for (int k = 0; k < 8; k++) accx[k] += al * lrelu_f((float)v[k]);
        } else if (lane < 63){
          half4 v = *(const half4*)(relEmbH + (size_t)r * 100 + 4*(lane - 38));
          #pragma unroll
          for (int k = 0; k < 4; k++) accr[k] += al * (float)v[k];
        }
      }
    }
  }

  float* oi = out + (size_t)i * 2000;
  _Float16* hi = xh2 + (size_t)i * 1024;
  float dA = 0.f, dB = 0.f;
  if (lane < 38){
    #pragma unroll
    for (int k = 0; k < 8; k++){
      int c = 8*lane + k;
      if (c < 300){
        oi[700 + c] = accx[k]; hi[700 + c] = (_Float16)accx[k];
        dA += accx[k] * gat_ai[700 + c];
        dB += accx[k] * gat_aj[700 + c];
      }
    }
    half8 v = *(const half8*)(hi + 8*lane);   // x2 f16 (cols 0:300)
    #pragma unroll
    for (int k = 0; k < 8; k++){
      int c = 8*lane + k;
      if (c < 300){
        float x2v = (float)v[k];
        float h = lrelu_f(x2v) * sumA;
        oi[300 + c] = h;
        dA += x2v * gat_ai[c] + h * gat_ai[300 + c];
        dB += x2v * gat_aj[c] + h * gat_aj[300 + c];
      }
    }
  } else if (lane < 63){
    #pragma unroll
    for (int k = 0; k < 4; k++){
      int c = 4*(lane - 38) + k;
      oi[600 + c] = accr[k]; hi[600 + c] = (_Float16)accr[k];
      dA += accr[k] * gat_ai[600 + c];
      dB += accr[k] * gat_aj[600 + c];
    }
  }
  #pragma unroll
  for (int o = 32; o > 0; o >>= 1){
    dA += __shfl_xor(dA, o);
    dB += __shfl_xor(dB, o);
  }
  if (lane == 0){ gxi[i] = dA; gxj[i] = dB; sAl[i] = sumA; }
}

// gat: THREE waves per node. part0: cols 0:300 gather -> out 0:600 (derived via sAl);
// part1: cols 600:800; part2: cols 800:1000. Fused softmax per wave.
__global__ __launch_bounds__(256)
void k_gat_gather(const int* __restrict__ off, const int* __restrict__ perm,
                  const int* __restrict__ srcA, const int* __restrict__ relI,
                  const float* __restrict__ gxi, const float* __restrict__ gxj,
                  const float* __restrict__ srr, const float* __restrict__ sAl,
                  const _Float16* __restrict__ xh2, float* __restrict__ out, int N){
  long gw = ((long)blockIdx.x * blockDim.x + threadIdx.x) >> 6;
  int lane = threadIdx.x & 63;
  int i = (int)(gw / 3), part = (int)(gw % 3);
  if (i >= N) return;
  int p0 = off[i], p1 = off[i+1];
  int deg = p1 - p0;
  float gi = gxi[i];
  int cbase = (part == 0) ? 0 : (400 + part * 200);   // 0 / 600 / 800
  int c0 = cbase + 8*lane;
  bool act = (part == 0) ? (lane < 38) : (lane < 25);
  float acc_a[8] = {0.f,0.f,0.f,0.f,0.f,0.f,0.f,0.f};
  float acc_b[8] = {0.f,0.f,0.f,0.f,0.f,0.f,0.f,0.f};

  if (deg <= 64){
    int jj = 0; float l = -3.4e38f, saj = 0.f;
    if (lane < deg){
      int e = perm[p0 + lane];
      jj = srcA[e];
      l = lrelu_f(gi + gxj[jj] + srr[relI[e]]);
      if (part == 0) saj = sAl[jj];
    }
    float lm = l;
    #pragma unroll
    for (int o = 32; o > 0; o >>= 1) lm = fmaxf(lm, __shfl_xor(lm, o));
    float exl = (lane < deg) ? expf(l - lm) : 0.f;
    float ls = exl;
    #pragma unroll
    for (int o = 32; o > 0; o >>= 1) ls += __shfl_xor(ls, o);
    float wgt = exl / (ls + 1e-16f);
    if (part == 0){
      int qe = 0;
      for (; qe + 1 < deg; qe += 2){
        int j0 = __shfl(jj, qe),    j1 = __shfl(jj, qe+1);
        float a0 = __shfl(wgt, qe), a1 = __shfl(wgt, qe+1);
        float s0 = __shfl(saj, qe) * a0, s1 = __shfl(saj, qe+1) * a1;
        if (act){
          half8 v0 = *(const half8*)(xh2 + (size_t)j0 * 1024 + 8*lane);
          half8 v1 = *(const half8*)(xh2 + (size_t)j1 * 1024 + 8*lane);
          #pragma unroll
          for (int k = 0; k < 8; k++){
            float x0 = (float)v0[k], x1 = (float)v1[k];
            acc_a[k] += a0 * x0 + a1 * x1;
            acc_b[k] += s0 * lrelu_f(x0) + s1 * lrelu_f(x1);
          }
        }
      }
      if (qe < deg){
        int j0 = __shfl(jj, qe);
        float a0 = __shfl(wgt, qe);
        float s0 = __shfl(saj, qe) * a0;
        if (act){
          half8 v0 = *(const half8*)(xh2 + (size_t)j0 * 1024 + 8*lane);
          #pragma unroll
          for (int k = 0; k < 8; k++){
            float x0 = (float)v0[k];
            acc_a[k] += a0 * x0;
            acc_b[k] += s0 * lrelu_f(x0);
          }
        }
      }
    } else {
      int qe = 0;
      for (; qe + 1 < deg; qe += 2){
        int j0 = __shfl(jj, qe),    j1 = __shfl(jj, qe+1);
        float a0 = __shfl(wgt, qe), a1 = __shfl(wgt, qe+1);
        if (act){
          half8 v0 = *(const half8*)(xh2 + (size_t)j0 * 1024 + c0);
          half8 v1 = *(const half8*)(xh2 + (size_t)j1 * 1024 + c0);
          #pragma unroll
          for (int k = 0; k < 8; k++) acc_a[k] += a0 * (float)v0[k] + a1 * (float)v1[k];
        }
      }
      if (qe < deg){
        int j0 = __shfl(jj, qe);
        float a0 = __shfl(wgt, qe);
        if (act){
          half8 v0 = *(const half8*)(xh2 + (size_t)j0 * 1024 + c0);
          #pragma unroll
          for (int k = 0; k < 8; k++) acc_a[k] += a0 * (float)v0[k];
        }
      }
    }
  } else {
    float lm = -3.4e38f;
    for (int p = p0 + lane; p < p1; p += 64){
      int e = perm[p];
      lm = fmaxf(lm, lrelu_f(gi + gxj[srcA[e]] + srr[relI[e]]));
    }
    #pragma unroll
    for (int o = 32; o > 0; o >>= 1) lm = fmaxf(lm, __shfl_xor(lm, o));
    float ls = 0.f;
    for (int p = p0 + lane; p < p1; p += 64){
      int e = perm[p];
      ls += expf(lrelu_f(gi + gxj[srcA[e]] + srr[relI[e]]) - lm);
    }
    #pragma unroll
    for (int o = 32; o > 0; o >>= 1) ls += __shfl_xor(ls, o);
    float inv = 1.f / (ls + 1e-16f);
    for (int base = p0; base < p1; base += 64){
      int m = min(64, p1 - base);
      int jj = 0; float all = 0.f, saj = 0.f;
      if (base + lane < p1){
        int e = perm[base + lane];
        jj = srcA[e];
        all = expf(lrelu_f(gi + gxj[jj] + srr[relI[e]]) - lm) * inv;
        if (part == 0) saj = sAl[jj];
      }
      for (int qe = 0; qe < m; qe++){
        int j = __shfl(jj, qe);
        float al = __shfl(all, qe);
        if (part == 0){
          float sa = __shfl(saj, qe) * al;
          if (act){
            half8 v = *(const half8*)(xh2 + (size_t)j * 1024 + 8*lane);
            #pragma unroll
            for (int k = 0; k < 8; k++){
              float x0 = (float)v[k];
              acc_a[k] += al * x0;
              acc_b[k] += sa * lrelu_f(x0);
            }
          }
        } else {
          if (act){
            half8 v = *(const half8*)(xh2 + (size_t)j * 1024 + c0);
            #pragma unroll
            for (int k = 0; k < 8; k++) acc_a[k] += al * (float)v[k];
          }
        }
      }
    }
  }

  float* ob = out + (size_t)i * 2000 + 1000;
  if (part == 0){
    if (lane < 37){
      floatx4 s0, s1, t0, t1;
      #pragma unroll
      for (int k = 0; k < 4; k++){
        s0[k] = fmaxf(acc_a[k], 0.f);   s1[k] = fmaxf(acc_a[4+k], 0.f);
        t0[k] = fmaxf(acc_b[k], 0.f);   t1[k] = fmaxf(acc_b[4+k], 0.f);
      }
      *(floatx4*)(ob + 8*lane) = s0;
      *(floatx4*)(ob + 8*lane + 4) = s1;
      *(floatx4*)(ob + 300 + 8*lane) = t0;
      *(floatx4*)(ob + 300 + 8*lane + 4) = t1;
    } else if (lane == 37){
      #pragma unroll
      for (int k = 0; k < 4; k++){       // cols 296..299
        ob[296 + k] = fmaxf(acc_a[k], 0.f);
        ob[596 + k] = fmaxf(acc_b[k], 0.f);
      }
    }
  } else {
    if (lane < 25){
      floatx4 s0, s1;
      #pragma unroll
      for (int k = 0; k < 4; k++){ s0[k] = fmaxf(acc_a[k], 0.f); s1[k] = fmaxf(acc_a[4+k], 0.f); }
      *(floatx4*)(ob + c0) = s0;
      *(floatx4*)(ob + c0 + 4) = s1;
    }
  }
}

extern "C" void kernel_launch(void* const* d_in, const int* in_sizes, int n_in,
                              void* d_out, int out_size, void* d_ws, size_t ws_size,
                              hipStream_t stream){
  const float* x_e     = (const float*)d_in[0];
  const int*   eiA     = (const int*)  d_in[3];   // edge_index_all [2,E]
  const int*   relAll  = (const int*)  d_in[4];
  const int*   lgOut   = (const int*)  d_in[5];
  const int*   lgIn    = (const int*)  d_in[7];
  const float* gcn1_w  = (const float*)d_in[9];
  const float* gcn2_w  = (const float*)d_in[10];
  const float* hw1_w   = (const float*)d_in[11];
  const float* hw1_b   = (const float*)d_in[12];
  const float* hw2_w   = (const float*)d_in[13];
  const float* hw2_b   = (const float*)d_in[14];
  const float* ww1     = (const float*)d_in[15];
  const float* gat_ai  = (const float*)d_in[16];
  const float* gat_aj  = (const float*)d_in[17];
  const float* gat_ar  = (const float*)d_in[18];
  const float* gatr_ai = (const float*)d_in[19];
  const float* gatr_aj = (const float*)d_in[20];
  const float* relEmb1 = (const float*)d_in[21];

  const int EH = 300, RH = 100;
  const int N   = in_sizes[0] / EH;
  const int E   = in_sizes[3] / 2;
  const int ELG = in_sizes[5] / 2;
  const int R   = in_sizes[21] / RH;
  const int Mtiles = (N + 127) / 128;
  const int Mpad = Mtiles * 128;

  // ---- workspace layout (16B-aligned f16 blocks first) ----
  char* base = (char*)d_ws;
  _Float16* xh0   = (_Float16*)base;  base += (size_t)Mpad * 320 * 2;   // x_e f16
  _Float16* xhA   = (_Float16*)base;  base += (size_t)Mpad * 320 * 2;   // x1 f16
  _Float16* A1f16 = (_Float16*)base;  base += (size_t)Mpad * 320 * 2;   // relu(agg) f16
  _Float16* xh2   = (_Float16*)base;  base += (size_t)N * 1024 * 2;     // x_wjq f16 mirror
  _Float16* BfAll = (_Float16*)base;  base += (size_t)4 * 102400 * 2;
  _Float16* relEmbH = (_Float16*)base; base += (size_t)2 * R * RH * 2;  // relEmb f16
  float* w = (float*)base;
  float* dis    = w; w += N;
  float* relEmb = w; w += (size_t)2 * R * RH;   // relEmb then sumR contiguous (one memset)
  float* sumR   = w; w += 2 * R;
  float* sxi    = w; w += N;
  float* sxj    = w; w += N;
  float* gxi    = w; w += N;
  float* gxj    = w; w += N;
  float* sAl    = w; w += N;
  float* sR_i   = w; w += R;
  float* sR_j   = w; w += R;
  float* aRel   = w; w += 2 * R;
  float* srr    = w; w += 2 * R;
  float* eE     = w; w += E;
  int* degD   = (int*)w; w += N;
  int* degS   = (int*)w; w += N;
  int* curD   = (int*)w; w += N;
  int* curS   = (int*)w; w += N;
  int* offD   = (int*)w; w += N + 1;
  int* offS   = (int*)w; w += N + 1;
  int* permD  = (int*)w; w += E;
  int* permS  = (int*)w; w += E;

  _Float16* Bf_g1 = BfAll;
  _Float16* Bf_h1 = BfAll + 102400;
  _Float16* Bf_g2 = BfAll + 2 * 102400;
  _Float16* Bf_h2 = BfAll + 3 * 102400;

  float* out = (float*)d_out;
  const int* srcA = eiA;         // row0 (j in gcn/gat, i in wjq)
  const int* dstA = eiA + E;     // row1

  auto cdiv = [](int a, int b){ return (a + b - 1) / b; };

  // ---- fused setup: degree count + weight pack + f16 convert + sR dots ----
  hipMemsetAsync(degD, 0, (size_t)4 * N * 4, stream);   // degD,degS,curD,curS contiguous
  hipMemsetAsync(relEmb, 0, ((size_t)2*R*RH + 2*R) * 4, stream);   // relEmb + sumR
  int B0 = cdiv(E,256), B1 = 200, B2 = Mpad, B3 = cdiv(R,256);
  k_setup<<<B0+B1+B2+B3,256,0,stream>>>(dstA, srcA, degD, degS, E,
                                        gcn1_w, hw1_w, gcn2_w, hw2_w, BfAll,
                                        x_e, xh0, sxi, sxj, N,
                                        relEmb1, gatr_ai, gatr_aj, sR_i, sR_j, R,
                                        B0, B1, B2);
  k_scan2<<<2,1024,0,stream>>>(degD, offD, degS, offS, N);
  int FB = cdiv(E,256);
  k_fill_inv<<<FB + cdiv(N,256),256,0,stream>>>(dstA, srcA, offD, offS, curD, curS,
                                                permD, permS, degD, dis, E, N, FB);

  int NB = 5 * (Mpad / 64);   // 64-row panels
  int GW = cdiv(N, 4);        // wave-per-node grids
  int EXT1 = cdiv(2*ELG, 256);
  int EXT2 = cdiv(2*R, 256);

  // layer 1 gather (+ fused line-graph logit/exp)
  k_gcn_gather<<<GW+EXT1,256,0,stream>>>(offD, permD, srcA, xh0, dis, A1f16, N,
                                         GW, 1, lgOut, lgIn, ELG, R, sR_i, sR_j, eE, sumR,
                                         nullptr, nullptr, nullptr, nullptr, nullptr, nullptr);
  // layer 1 GEMM (+ fused line-graph scatter: ELG blocks x 2 edges)
  k_dual_mfma<<<NB+ELG,256,0,stream>>>(A1f16, xh0, Bf_g1, Bf_h1, hw1_b,
                                       nullptr, 0, xhA, 320, N, nullptr, nullptr, nullptr,
                                       NB, lgOut, lgIn, ELG, R, eE, sumR, relEmb1, relEmb);
  // layer 2 gather (+ fused relEmb relu/f16/dots)
  k_gcn_gather<<<GW+EXT2,256,0,stream>>>(offD, permD, srcA, xhA, dis, A1f16, N,
                                         GW, 2, nullptr, nullptr, ELG, R, nullptr, nullptr,
                                         nullptr, nullptr,
                                         relEmb, relEmbH, ww1 + EH, gat_ar, aRel, srr);
  // layer 2 GEMM (+ fused sxi/sxj logit dots)
  k_dual_mfma<<<NB,256,0,stream>>>(A1f16, xhA, Bf_g2, Bf_h2, hw2_b,
                                   out, 2000, xh2, 1024, N, ww1, sxi, sxj,
                                   NB, nullptr, nullptr, ELG, R, nullptr, nullptr,
                                   nullptr, nullptr);

  // wjq: fused softmax + gather + head + gat-logit dots (gxi,gxj) + sAl
  k_wjq_gather<<<GW,256,0,stream>>>(offS, permS, dstA, relAll, sxi, sxj, aRel, relEmbH,
                                    gat_ai, gat_aj, out, xh2, gxi, gxj, sAl, N);

  // gat: fused softmax + gather + relu, 3 waves/node
  k_gat_gather<<<cdiv(3*N,4),256,0,stream>>>(offD, permD, srcA, relAll, gxi, gxj, srr,
                                             sAl, xh2, out, N);
}